// Round 1
// baseline (366.854 us; speedup 1.0000x reference)
//
#include <hip/hip_runtime.h>
#include <hip/hip_bf16.h>
#include <hip/hip_fp16.h>

#define B_SZ   16
#define L_SZ   8192
#define DM     64
#define DI     128
#define NCH    128      // scan chunks
#define CLEN   64       // L_SZ / NCH
#define CH     64       // frontend tokens per block
#define RT     80       // padded rows (5 mtiles of 16; 67 used)
#define PA     72       // LDS pitch (u16) for 64-wide acts: 144B
#define PU     136      // LDS pitch (u16) for 128-wide acts: 272B
#define PC     132      // LDS pitch (u16) for conv input: 264B
#define LN_EPS 1e-3f

typedef float  f4 __attribute__((ext_vector_type(4)));
typedef short  s8 __attribute__((ext_vector_type(8)));
typedef unsigned short u16;
typedef unsigned int   u32;
#define MFMA16 __builtin_amdgcn_mfma_f32_16x16x32_bf16

__device__ __forceinline__ u16 f2bfu(float f) {
    u32 u = __float_as_uint(f);
    return (u16)((u + 0x7FFFu + ((u >> 16) & 1u)) >> 16);
}
__device__ __forceinline__ u32 pk2bf(float a, float b) {
    return (u32)f2bfu(a) | ((u32)f2bfu(b) << 16);
}
__device__ __forceinline__ float bflo(u32 u) { return __uint_as_float(u << 16); }
__device__ __forceinline__ float bfhi(u32 u) { return __uint_as_float(u & 0xFFFF0000u); }
__device__ __forceinline__ float bfu2f(u16 h) { return __uint_as_float((u32)h << 16); }
__device__ __forceinline__ float h2f(u32 lo16) {
    return __half2float(__ushort_as_half((u16)(lo16 & 0xFFFFu)));
}
__device__ __forceinline__ float fsig(float v) {
    return __builtin_amdgcn_rcpf(1.f + __expf(-v));
}
__device__ __forceinline__ float fsp(float v) {   // softplus
    return fmaxf(v, 0.f) + __logf(1.f + __expf(-fabsf(v)));
}

// ---------------- Weight prep: fragment-linear bf16 granules ----------------
__global__ __launch_bounds__(256) void k_prep(
    const float* __restrict__ W_in, const float* __restrict__ in_proj,
    const float* __restrict__ x_proj, const float* __restrict__ Wout,
    u16* __restrict__ Wf1, u16* __restrict__ Wf2,
    u16* __restrict__ Wf3, u16* __restrict__ Wf4)
{
    const int tid = threadIdx.x;
    for (int g = tid; g < 512; g += 256) {          // W_in: 4 nt x 2 ks
        int lane = g & 63, ks = (g >> 6) & 1, nt = g >> 7;
        int n = nt * 16 + (lane & 15), kb = ks * 32 + (lane >> 4) * 8;
        for (int j = 0; j < 8; j++) Wf1[g * 8 + j] = f2bfu(W_in[(kb + j) * 64 + n]);
    }
    for (int g = tid; g < 2048; g += 256) {         // in_proj: 16 nt x 2 ks
        int lane = g & 63, ks = (g >> 6) & 1, nt = g >> 7;
        int n = nt * 16 + (lane & 15), kb = ks * 32 + (lane >> 4) * 8;
        for (int j = 0; j < 8; j++) Wf2[g * 8 + j] = f2bfu(in_proj[(kb + j) * 256 + n]);
    }
    for (int g = tid; g < 768; g += 256) {          // x_proj (pad N 36->48): 3 nt x 4 ks
        int lane = g & 63, ks = (g >> 6) & 3, nt = g >> 8;
        int n = nt * 16 + (lane & 15), kb = ks * 32 + (lane >> 4) * 8;
        for (int j = 0; j < 8; j++)
            Wf3[g * 8 + j] = f2bfu(n < 36 ? x_proj[(kb + j) * 36 + n] : 0.f);
    }
    for (int g = tid; g < 1024; g += 256) {         // out_proj: 4 nt x 4 ks
        int lane = g & 63, ks = (g >> 6) & 3, nt = g >> 8;
        int n = nt * 16 + (lane & 15), kb = ks * 32 + (lane >> 4) * 8;
        for (int j = 0; j < 8; j++) Wf4[g * 8 + j] = f2bfu(Wout[(kb + j) * 64 + n]);
    }
}

// ---------------- Frontend ----------------
__global__ __launch_bounds__(256) void k_frontend(
    const float* __restrict__ x, const float* __restrict__ b_in,
    const float* __restrict__ conv_w, const float* __restrict__ conv_b,
    const float* __restrict__ dt_w, const float* __restrict__ dt_b,
    const u16* __restrict__ Wf1, const u16* __restrict__ Wf2, const u16* __restrict__ Wf3,
    float* __restrict__ xin_g, u32* __restrict__ dtu_g,
    float* __restrict__ B_g, float* __restrict__ C_g, u16* __restrict__ sz_g)
{
    __shared__ __align__(16) char sm[41088];
    u16*   smA   = (u16*)sm;              // [80][72] x (bf16)
    u16*   smB   = (u16*)(sm + 11520);    // [80][72] xin
    u16*   smU   = (u16*)sm;              // [64][136] u (reuses smA/smB)
    float* smDtr = (float*)(sm + 17408);  // [64][4]
    u16*   smC   = (u16*)(sm + 23040);    // [67][132] xc

    const int tid = threadIdx.x;
    const int w = tid >> 6, lane = tid & 63;
    const int n16 = lane & 15, quad = lane >> 4;
    const int b = blockIdx.y, c0 = blockIdx.x * CH;
    const long long tokbase = (long long)b * L_SZ + c0;

    // P0: stage x rows (bf16), float4-vectorized
    for (int idx = tid; idx < RT * 16; idx += 256) {
        int r = idx >> 4, c4 = idx & 15;
        int l = c0 - 3 + r;
        float4 v = make_float4(0.f, 0.f, 0.f, 0.f);
        if (r < 67 && l >= 0)
            v = *(const float4*)(x + ((long long)b * L_SZ + l) * 64 + c4 * 4);
        *(uint2*)((char*)smA + r * 144 + c4 * 8) = make_uint2(pk2bf(v.x, v.y), pk2bf(v.z, v.w));
    }
    __syncthreads();

    // GEMM1: xin = x @ W_in + b_in
    {
        s8 b0 = *(const s8*)(Wf1 + ((w * 2 + 0) * 64 + lane) * 8);
        s8 b1 = *(const s8*)(Wf1 + ((w * 2 + 1) * 64 + lane) * 8);
        float bias = b_in[w * 16 + n16];
        for (int m = 0; m < 5; m++) {
            int ar = m * 16 + n16;
            s8 a0 = *(const s8*)(smA + ar * PA + quad * 8);
            s8 a1 = *(const s8*)(smA + ar * PA + 32 + quad * 8);
            f4 acc = {0.f, 0.f, 0.f, 0.f};
            acc = MFMA16(a0, b0, acc, 0, 0, 0);
            acc = MFMA16(a1, b1, acc, 0, 0, 0);
#pragma unroll
            for (int reg = 0; reg < 4; reg++) {
                int rr = m * 16 + quad * 4 + reg;
                float v = acc[reg] + bias;
                smB[rr * PA + w * 16 + n16] = f2bfu(v);
                if (rr >= 3 && rr < 67)
                    xin_g[(tokbase + rr - 3) * 64 + w * 16 + n16] = v;
            }
        }
    }
    __syncthreads();

    // GEMM2: xz = xin @ in_proj (waves 0-1 -> xc, waves 2-3 -> silu(z))
    {
        s8 bf[4][2];
#pragma unroll
        for (int i = 0; i < 4; i++)
#pragma unroll
            for (int ks = 0; ks < 2; ks++)
                bf[i][ks] = *(const s8*)(Wf2 + (((w * 4 + i) * 2 + ks) * 64 + lane) * 8);
        for (int m = 0; m < 5; m++) {
            int ar = m * 16 + n16;
            s8 a0 = *(const s8*)(smB + ar * PA + quad * 8);
            s8 a1 = *(const s8*)(smB + ar * PA + 32 + quad * 8);
#pragma unroll
            for (int i = 0; i < 4; i++) {
                f4 acc = {0.f, 0.f, 0.f, 0.f};
                acc = MFMA16(a0, bf[i][0], acc, 0, 0, 0);
                acc = MFMA16(a1, bf[i][1], acc, 0, 0, 0);
                int cg = (w * 4 + i) * 16 + n16;
#pragma unroll
                for (int reg = 0; reg < 4; reg++) {
                    int rr = m * 16 + quad * 4 + reg;
                    float v = acc[reg];
                    if (cg < 128) {                     // wave-uniform branch
                        if (rr < 67) {
                            int l = c0 - 3 + rr;
                            smC[rr * PC + cg] = f2bfu(l >= 0 ? v : 0.f);
                        }
                    } else if (rr >= 3 && rr < 67) {
                        sz_g[(tokbase + rr - 3) * 128 + (cg - 128)] = f2bfu(v * fsig(v));
                    }
                }
            }
        }
    }
    __syncthreads();

    // conv(4) + silu -> u (LDS only; global u rides packed with dt below)
    {
        const int d2 = lane * 2, ctb = w * 16;
        float4 cw0 = ((const float4*)conv_w)[d2];
        float4 cw1 = ((const float4*)conv_w)[d2 + 1];
        float cb0 = conv_b[d2], cb1 = conv_b[d2 + 1];
        u32 r0 = *(const u32*)((char*)smC + (ctb + 0) * 264 + lane * 4);
        u32 r1 = *(const u32*)((char*)smC + (ctb + 1) * 264 + lane * 4);
        u32 r2 = *(const u32*)((char*)smC + (ctb + 2) * 264 + lane * 4);
#pragma unroll 4
        for (int j = 0; j < 16; j++) {
            int ct = ctb + j;
            u32 r3 = *(const u32*)((char*)smC + (ct + 3) * 264 + lane * 4);
            float v0 = cb0 + bflo(r0) * cw0.x + bflo(r1) * cw0.y + bflo(r2) * cw0.z + bflo(r3) * cw0.w;
            float v1 = cb1 + bfhi(r0) * cw1.x + bfhi(r1) * cw1.y + bfhi(r2) * cw1.z + bfhi(r3) * cw1.w;
            u32 pk = pk2bf(v0 * fsig(v0), v1 * fsig(v1));
            *(u32*)(smU + ct * PU + d2) = pk;
            r0 = r1; r1 = r2; r2 = r3;
        }
    }
    __syncthreads();

    // GEMM3: dbc = u @ x_proj  (M=64, N=48(36), K=128); wave w -> mtile w
    {
        s8 bf3[3][4];
#pragma unroll
        for (int nt = 0; nt < 3; nt++)
#pragma unroll
            for (int ks = 0; ks < 4; ks++)
                bf3[nt][ks] = *(const s8*)(Wf3 + ((nt * 4 + ks) * 64 + lane) * 8);
        f4 acc[3] = {{0.f,0.f,0.f,0.f},{0.f,0.f,0.f,0.f},{0.f,0.f,0.f,0.f}};
        int ar = w * 16 + n16;
#pragma unroll
        for (int ks = 0; ks < 4; ks++) {
            s8 a = *(const s8*)(smU + ar * PU + ks * 32 + quad * 8);
#pragma unroll
            for (int nt = 0; nt < 3; nt++) acc[nt] = MFMA16(a, bf3[nt][ks], acc[nt], 0, 0, 0);
        }
#pragma unroll
        for (int nt = 0; nt < 3; nt++) {
            int c = nt * 16 + n16;
#pragma unroll
            for (int reg = 0; reg < 4; reg++) {
                int rr = w * 16 + quad * 4 + reg;
                float v = acc[nt][reg];
                long long t = tokbase + rr;
                if (c < 4)       smDtr[rr * 4 + c] = v;
                else if (c < 20) B_g[t * 16 + (c - 4)] = v;
                else if (c < 36) C_g[t * 16 + (c - 20)] = v;
            }
        }
    }
    __syncthreads();

    // dt = softplus(dtr @ dt_proj_w + dt_proj_b); pack (dt fp16 | u bf16) per channel
    {
        const int o2 = lane * 2, grp = w;
        float w00 = dt_w[o2],       w01 = dt_w[o2 + 1];
        float w10 = dt_w[128 + o2], w11 = dt_w[128 + o2 + 1];
        float w20 = dt_w[256 + o2], w21 = dt_w[256 + o2 + 1];
        float w30 = dt_w[384 + o2], w31 = dt_w[384 + o2 + 1];
        float b0 = dt_b[o2], b1 = dt_b[o2 + 1];
#pragma unroll 4
        for (int j = 0; j < 16; j++) {
            int ct = grp * 16 + j;
            float4 q = *(const float4*)(smDtr + ct * 4);
            float v0 = b0 + q.x * w00 + q.y * w10 + q.z * w20 + q.w * w30;
            float v1 = b1 + q.x * w01 + q.y * w11 + q.z * w21 + q.w * w31;
            u32 upk = *(const u32*)(smU + ct * PU + o2);
            u32 pk0 = (u32)__half_as_ushort(__float2half_rn(fsp(v0))) | (upk << 16);
            u32 pk1 = (u32)__half_as_ushort(__float2half_rn(fsp(v1))) | (upk & 0xFFFF0000u);
            *(uint2*)(dtu_g + (tokbase + ct) * 128 + o2) = make_uint2(pk0, pk1);
        }
    }
}

// ---------------- Scan phase 1: per-chunk local states (state-split 2x) ----------------
__global__ __launch_bounds__(256, 8) void k_scan1(
    const u32* __restrict__ dtu_g, const float* __restrict__ B_g,
    const float* __restrict__ A_log,
    float* __restrict__ hl_ws, float* __restrict__ sdt_ws)
{
    const int tid = threadIdx.x;
    const int d = tid >> 1, sh = tid & 1, s0 = sh * 8;
    const int c = blockIdx.x, b = blockIdx.y;
    const float A0g = -__expf(A_log[d * 16]);
    float A[8];
#pragma unroll
    for (int s = 0; s < 8; s++) A[s] = -__expf(A_log[d * 16 + s0 + s]);
    bool chl = true;
#pragma unroll
    for (int s = 0; s < 8; s++)
        chl = chl && (fabsf(A[s] - (float)(s0 + s + 1) * A0g) <= 1e-4f * fabsf(A[s]));
    const bool chain = __all(chl);   // wave-uniform (shuffle-safe branches)

    float h[8];
#pragma unroll
    for (int s = 0; s < 8; s++) h[s] = 0.f;
    float sdt = 0.f;
    const long long tok0 = (long long)b * L_SZ + (long long)c * CLEN;

    u32 pk = dtu_g[tok0 * 128 + d];
    float4 Bq0 = *(const float4*)(B_g + tok0 * 16 + s0);
    float4 Bq1 = *(const float4*)(B_g + tok0 * 16 + s0 + 4);

    if (chain) {
#pragma unroll 2
        for (int i = 0; i < CLEN; i++) {
            const long long t = tok0 + i;
            u32 pkc = pk; float4 b0 = Bq0, b1 = Bq1;
            if (i + 1 < CLEN) {
                pk  = dtu_g[(t + 1) * 128 + d];
                Bq0 = *(const float4*)(B_g + (t + 1) * 16 + s0);
                Bq1 = *(const float4*)(B_g + (t + 1) * 16 + s0 + 4);
            }
            float dtv = h2f(pkc);
            float uv  = bfhi(pkc);
            float du  = dtv * uv;  sdt += dtv;
            float p  = __expf(dtv * A0g);
            float p2 = p * p, p4 = p2 * p2;
            float dA = sh ? p4 * p4 * p : p;          // p^9 or p^1
            h[0] = dA * h[0] + du * b0.x;
            dA *= p; h[1] = dA * h[1] + du * b0.y;
            dA *= p; h[2] = dA * h[2] + du * b0.z;
            dA *= p; h[3] = dA * h[3] + du * b0.w;
            dA *= p; h[4] = dA * h[4] + du * b1.x;
            dA *= p; h[5] = dA * h[5] + du * b1.y;
            dA *= p; h[6] = dA * h[6] + du * b1.z;
            dA *= p; h[7] = dA * h[7] + du * b1.w;
        }
    } else {
#pragma unroll 2
        for (int i = 0; i < CLEN; i++) {
            const long long t = tok0 + i;
            u32 pkc = pk; float4 b0 = Bq0, b1 = Bq1;
            if (i + 1 < CLEN) {
                pk  = dtu_g[(t + 1) * 128 + d];
                Bq0 = *(const float4*)(B_g + (t + 1) * 16 + s0);
                Bq1 = *(const float4*)(B_g + (t + 1) * 16 + s0 + 4);
            }
            float dtv = h2f(pkc);
            float uv  = bfhi(pkc);
            float du  = dtv * uv;  sdt += dtv;
            float Bv[8] = { b0.x, b0.y, b0.z, b0.w, b1.x, b1.y, b1.z, b1.w };
#pragma unroll
            for (int s = 0; s < 8; s++) h[s] = __expf(dtv * A[s]) * h[s] + du * Bv[s];
        }
    }

    float4* hp4 = (float4*)(hl_ws + (((long long)b * NCH + c) * 128 + d) * 16 + s0);
    hp4[0] = make_float4(h[0], h[1], h[2], h[3]);
    hp4[1] = make_float4(h[4], h[5], h[6], h[7]);
    if (sh == 0) sdt_ws[((long long)b * NCH + c) * 128 + d] = sdt;
}

// ---------------- Chunk-boundary combine ----------------
__global__ __launch_bounds__(256) void k_combine(
    const float* __restrict__ A_log, const float* __restrict__ hl_ws,
    const float* __restrict__ sdt_ws, float* __restrict__ hin_ws)
{
    int gid = blockIdx.x * 256 + threadIdx.x;   // 0..32767
    int b = gid >> 11;
    int rem = gid & 2047;     // d*16+s
    int d = rem >> 4;
    float A = -__expf(A_log[rem]);
    float h = 0.f;
    for (int c = 0; c < NCH; c++) {
        long long o = ((long long)b * NCH + c) * 2048 + rem;
        hin_ws[o] = h;
        float sdt = sdt_ws[((long long)b * NCH + c) * 128 + d];
        h = __expf(A * sdt) * h + hl_ws[o];
    }
}

// ---------------- Scan phase 3: final states + y (state-split 2x) ----------------
__global__ __launch_bounds__(256, 8) void k_scan3(
    const u32* __restrict__ dtu_g, const float* __restrict__ B_g,
    const float* __restrict__ C_g, const u16* __restrict__ sz_g,
    const float* __restrict__ A_log, const float* __restrict__ D_skip,
    const float* __restrict__ hin_ws, u16* __restrict__ y_g)
{
    const int tid = threadIdx.x;
    const int d = tid >> 1, sh = tid & 1, s0 = sh * 8;
    const int c = blockIdx.x, b = blockIdx.y;
    const float A0g = -__expf(A_log[d * 16]);
    float A[8];
#pragma unroll
    for (int s = 0; s < 8; s++) A[s] = -__expf(A_log[d * 16 + s0 + s]);
    bool chl = true;
#pragma unroll
    for (int s = 0; s < 8; s++)
        chl = chl && (fabsf(A[s] - (float)(s0 + s + 1) * A0g) <= 1e-4f * fabsf(A[s]));
    const bool chain = __all(chl);

    float h[8];
    {
        const float4* hp = (const float4*)(hin_ws + (((long long)b * NCH + c) * 128 + d) * 16 + s0);
        float4 h0 = hp[0], h1 = hp[1];
        h[0]=h0.x; h[1]=h0.y; h[2]=h0.z; h[3]=h0.w;
        h[4]=h1.x; h[5]=h1.y; h[6]=h1.z; h[7]=h1.w;
    }
    const float Dv = D_skip[d];
    const long long tok0 = (long long)b * L_SZ + (long long)c * CLEN;

    u32 pk = dtu_g[tok0 * 128 + d];
    float4 Bq0 = *(const float4*)(B_g + tok0 * 16 + s0);
    float4 Bq1 = *(const float4*)(B_g + tok0 * 16 + s0 + 4);

    if (chain) {
#pragma unroll 2
        for (int i = 0; i < CLEN; i++) {
            const long long t = tok0 + i;
            u32 pkc = pk; float4 b0 = Bq0, b1 = Bq1;
            float4 c0 = *(const float4*)(C_g + t * 16 + s0);
            float4 c1 = *(const float4*)(C_g + t * 16 + s0 + 4);
            u16 szu = sz_g[t * 128 + d];
            if (i + 1 < CLEN) {
                pk  = dtu_g[(t + 1) * 128 + d];
                Bq0 = *(const float4*)(B_g + (t + 1) * 16 + s0);
                Bq1 = *(const float4*)(B_g + (t + 1) * 16 + s0 + 4);
            }
            float dtv = h2f(pkc);
            float uv  = bfhi(pkc);
            float du  = dtv * uv;
            float p  = __expf(dtv * A0g);
            float p2 = p * p, p4 = p2 * p2;
            float dA = sh ? p4 * p4 * p : p;          // p^9 or p^1
            h[0] = dA * h[0] + du * b0.x; float ys = h[0] * c0.x;
            dA *= p; h[1] = dA * h[1] + du * b0.y; ys += h[1] * c0.y;
            dA *= p; h[2] = dA * h[2] + du * b0.z; ys += h[2] * c0.z;
            dA *= p; h[3] = dA * h[3] + du * b0.w; ys += h[3] * c0.w;
            dA *= p; h[4] = dA * h[4] + du * b1.x; ys += h[4] * c1.x;
            dA *= p; h[5] = dA * h[5] + du * b1.y; ys += h[5] * c1.y;
            dA *= p; h[6] = dA * h[6] + du * b1.z; ys += h[6] * c1.z;
            dA *= p; h[7] = dA * h[7] + du * b1.w; ys += h[7] * c1.w;
            ys += __shfl_xor(ys, 1, 64);
            if (sh == 0)
                y_g[t * 128 + d] = f2bfu((ys + uv * Dv) * bfu2f(szu));
        }
    } else {
#pragma unroll 2
        for (int i = 0; i < CLEN; i++) {
            const long long t = tok0 + i;
            u32 pkc = pk; float4 b0 = Bq0, b1 = Bq1;
            float4 c0 = *(const float4*)(C_g + t * 16 + s0);
            float4 c1 = *(const float4*)(C_g + t * 16 + s0 + 4);
            u16 szu = sz_g[t * 128 + d];
            if (i + 1 < CLEN) {
                pk  = dtu_g[(t + 1) * 128 + d];
                Bq0 = *(const float4*)(B_g + (t + 1) * 16 + s0);
                Bq1 = *(const float4*)(B_g + (t + 1) * 16 + s0 + 4);
            }
            float dtv = h2f(pkc);
            float uv  = bfhi(pkc);
            float du  = dtv * uv;
            float Bv[8] = { b0.x, b0.y, b0.z, b0.w, b1.x, b1.y, b1.z, b1.w };
            float Cv[8] = { c0.x, c0.y, c0.z, c0.w, c1.x, c1.y, c1.z, c1.w };
            float ys = 0.f;
#pragma unroll
            for (int s = 0; s < 8; s++) {
                h[s] = __expf(dtv * A[s]) * h[s] + du * Bv[s];
                ys += h[s] * Cv[s];
            }
            ys += __shfl_xor(ys, 1, 64);
            if (sh == 0)
                y_g[t * 128 + d] = f2bfu((ys + uv * Dv) * bfu2f(szu));
        }
    }
}

// ---------------- Epilogue: out = LN(y @ out_proj + xin) ----------------
__global__ __launch_bounds__(256) void k_epilogue(
    const u16* __restrict__ y_g, const float* __restrict__ xin_g,
    const u16* __restrict__ Wf4, const float* __restrict__ gamma,
    const float* __restrict__ beta, float* __restrict__ out)
{
    __shared__ __align__(16) char sm[34048];
    u16*   yA  = (u16*)sm;            // [64][136]
    float* smR = (float*)(sm + 17408);// [64][65]

    const int tid = threadIdx.x;
    const int w = tid >> 6, lane = tid & 63;
    const int n16 = lane & 15, quad = lane >> 4;
    const long long t0 = (long long)blockIdx.x * 64;

    for (int idx = tid; idx < 64 * 64; idx += 256) {
        int r = idx >> 6, cp = idx & 63;
        u32 v = ((const u32*)y_g)[(t0 + r) * 64 + cp];
        *(u32*)((char*)yA + r * 272 + cp * 4) = v;
    }
    __syncthreads();

    {
        s8 bf[4];
#pragma unroll
        for (int ks = 0; ks < 4; ks++)
            bf[ks] = *(const s8*)(Wf4 + ((w * 4 + ks) * 64 + lane) * 8);
#pragma unroll
        for (int m = 0; m < 4; m++) {
            int ar = m * 16 + n16;
            f4 acc = {0.f, 0.f, 0.f, 0.f};
#pragma unroll
            for (int ks = 0; ks < 4; ks++) {
                s8 a = *(const s8*)(yA + ar * PU + ks * 32 + quad * 8);
                acc = MFMA16(a, bf[ks], acc, 0, 0, 0);
            }
#pragma unroll
            for (int reg = 0; reg < 4; reg++) {
                int rr = m * 16 + quad * 4 + reg;
                smR[rr * 65 + w * 16 + n16] = acc[reg];
            }
        }
    }
    __syncthreads();

    {
        int o = tid & 63, wv = tid >> 6;
        float g = gamma[o], bb = beta[o];
        for (int j = 0; j < 16; j++) {
            int rr = wv * 16 + j;
            float r = smR[rr * 65 + o] + xin_g[(t0 + rr) * 64 + o];
            float s = r;
#pragma unroll
            for (int mS = 0; mS < 6; mS++) s += __shfl_xor(s, 1 << mS, 64);
            float mu = s * (1.f / 64.f);
            float dv = r - mu;
            float vs = dv * dv;
#pragma unroll
            for (int mS = 0; mS < 6; mS++) vs += __shfl_xor(vs, 1 << mS, 64);
            out[(t0 + rr) * 64 + o] = g * dv * rsqrtf(vs * (1.f / 64.f) + LN_EPS) + bb;
        }
    }
}

extern "C" void kernel_launch(void* const* d_in, const int* in_sizes, int n_in,
                              void* d_out, int out_size, void* d_ws, size_t ws_size,
                              hipStream_t stream)
{
    const float* x       = (const float*)d_in[0];
    const float* W_in    = (const float*)d_in[1];
    const float* b_in    = (const float*)d_in[2];
    const float* in_proj = (const float*)d_in[3];
    const float* conv_w  = (const float*)d_in[4];
    const float* conv_b  = (const float*)d_in[5];
    const float* x_proj  = (const float*)d_in[6];
    const float* dt_w    = (const float*)d_in[7];
    const float* dt_b    = (const float*)d_in[8];
    const float* A_log   = (const float*)d_in[9];
    const float* D_skip  = (const float*)d_in[10];
    const float* Wout    = (const float*)d_in[11];
    const float* gamma   = (const float*)d_in[12];
    const float* beta    = (const float*)d_in[13];
    float* out = (float*)d_out;

    const long long NT = (long long)B_SZ * L_SZ;  // 131072 tokens
    char* ws = (char*)d_ws;
    float*  xin_g = (float*)ws;   ws += NT * 64 * 4;
    u32*    dtu_g = (u32*)ws;     ws += NT * 128 * 4;   // (dt fp16 | u bf16)
    float*  B_g   = (float*)ws;   ws += NT * 16 * 4;
    float*  C_g   = (float*)ws;   ws += NT * 16 * 4;
    u16*    sz_g  = (u16*)ws;     ws += NT * 128 * 2;
    u16*    y_g   = (u16*)ws;     ws += NT * 128 * 2;
    float*  hl_ws  = (float*)ws;  ws += (long long)B_SZ * NCH * 2048 * 4;
    float*  sdt_ws = (float*)ws;  ws += (long long)B_SZ * NCH * 128 * 4;
    float*  hin_ws = (float*)ws;  ws += (long long)B_SZ * NCH * 2048 * 4;
    u16* Wf1 = (u16*)ws; ws += 4096 * 2;
    u16* Wf2 = (u16*)ws; ws += 16384 * 2;
    u16* Wf3 = (u16*)ws; ws += 6144 * 2;
    u16* Wf4 = (u16*)ws; ws += 8192 * 2;

    k_prep<<<1, 256, 0, stream>>>(W_in, in_proj, x_proj, Wout, Wf1, Wf2, Wf3, Wf4);

    k_frontend<<<dim3(L_SZ / CH, B_SZ), 256, 0, stream>>>(
        x, b_in, conv_w, conv_b, dt_w, dt_b, Wf1, Wf2, Wf3,
        xin_g, dtu_g, B_g, C_g, sz_g);

    k_scan1<<<dim3(NCH, B_SZ), 256, 0, stream>>>(
        dtu_g, B_g, A_log, hl_ws, sdt_ws);

    k_combine<<<128, 256, 0, stream>>>(A_log, hl_ws, sdt_ws, hin_ws);

    k_scan3<<<dim3(NCH, B_SZ), 256, 0, stream>>>(
        dtu_g, B_g, C_g, sz_g, A_log, D_skip, hin_ws, y_g);

    k_epilogue<<<2048, 256, 0, stream>>>(y_g, xin_g, Wf4, gamma, beta, out);
}

// Round 2
// 363.257 us; speedup vs baseline: 1.0099x; 1.0099x over previous
//
#include <hip/hip_runtime.h>
#include <hip/hip_bf16.h>
#include <hip/hip_fp16.h>

#define B_SZ   16
#define L_SZ   8192
#define DM     64
#define DI     128
#define NCH    128      // scan chunks
#define CLEN   64       // L_SZ / NCH
#define CH     64       // frontend tokens per block
#define RT     80       // padded rows (5 mtiles of 16; 67 used)
#define PA     72       // LDS pitch (u16) for 64-wide acts: 144B
#define PU     136      // LDS pitch (u16) for 128-wide acts: 272B
#define PC     132      // LDS pitch (u16) for conv input: 264B
#define LN_EPS 1e-3f

typedef float  f4 __attribute__((ext_vector_type(4)));
typedef short  s8 __attribute__((ext_vector_type(8)));
typedef unsigned short u16;
typedef unsigned int   u32;
#define MFMA16 __builtin_amdgcn_mfma_f32_16x16x32_bf16

__device__ __forceinline__ u16 f2bfu(float f) {
    u32 u = __float_as_uint(f);
    return (u16)((u + 0x7FFFu + ((u >> 16) & 1u)) >> 16);
}
__device__ __forceinline__ u32 pk2bf(float a, float b) {
    return (u32)f2bfu(a) | ((u32)f2bfu(b) << 16);
}
__device__ __forceinline__ float bflo(u32 u) { return __uint_as_float(u << 16); }
__device__ __forceinline__ float bfhi(u32 u) { return __uint_as_float(u & 0xFFFF0000u); }
__device__ __forceinline__ float bfu2f(u16 h) { return __uint_as_float((u32)h << 16); }
__device__ __forceinline__ float h2f(u32 lo16) {
    return __half2float(__ushort_as_half((u16)(lo16 & 0xFFFFu)));
}
__device__ __forceinline__ float fsig(float v) {
    return __builtin_amdgcn_rcpf(1.f + __expf(-v));
}
__device__ __forceinline__ float fsp(float v) {   // softplus
    return fmaxf(v, 0.f) + __logf(1.f + __expf(-fabsf(v)));
}

// ---------------- Weight prep: fragment-linear bf16 granules ----------------
__global__ __launch_bounds__(256) void k_prep(
    const float* __restrict__ W_in, const float* __restrict__ in_proj,
    const float* __restrict__ x_proj, const float* __restrict__ Wout,
    u16* __restrict__ Wf1, u16* __restrict__ Wf2,
    u16* __restrict__ Wf3, u16* __restrict__ Wf4)
{
    const int tid = threadIdx.x;
    for (int g = tid; g < 512; g += 256) {          // W_in: 4 nt x 2 ks
        int lane = g & 63, ks = (g >> 6) & 1, nt = g >> 7;
        int n = nt * 16 + (lane & 15), kb = ks * 32 + (lane >> 4) * 8;
        for (int j = 0; j < 8; j++) Wf1[g * 8 + j] = f2bfu(W_in[(kb + j) * 64 + n]);
    }
    for (int g = tid; g < 2048; g += 256) {         // in_proj: 16 nt x 2 ks
        int lane = g & 63, ks = (g >> 6) & 1, nt = g >> 7;
        int n = nt * 16 + (lane & 15), kb = ks * 32 + (lane >> 4) * 8;
        for (int j = 0; j < 8; j++) Wf2[g * 8 + j] = f2bfu(in_proj[(kb + j) * 256 + n]);
    }
    for (int g = tid; g < 768; g += 256) {          // x_proj (pad N 36->48): 3 nt x 4 ks
        int lane = g & 63, ks = (g >> 6) & 3, nt = g >> 8;
        int n = nt * 16 + (lane & 15), kb = ks * 32 + (lane >> 4) * 8;
        for (int j = 0; j < 8; j++)
            Wf3[g * 8 + j] = f2bfu(n < 36 ? x_proj[(kb + j) * 36 + n] : 0.f);
    }
    for (int g = tid; g < 1024; g += 256) {         // out_proj: 4 nt x 4 ks
        int lane = g & 63, ks = (g >> 6) & 3, nt = g >> 8;
        int n = nt * 16 + (lane & 15), kb = ks * 32 + (lane >> 4) * 8;
        for (int j = 0; j < 8; j++) Wf4[g * 8 + j] = f2bfu(Wout[(kb + j) * 64 + n]);
    }
}

// ---------------- Frontend ----------------
__global__ __launch_bounds__(256) void k_frontend(
    const float* __restrict__ x, const float* __restrict__ b_in,
    const float* __restrict__ conv_w, const float* __restrict__ conv_b,
    const float* __restrict__ dt_w, const float* __restrict__ dt_b,
    const u16* __restrict__ Wf1, const u16* __restrict__ Wf2, const u16* __restrict__ Wf3,
    float* __restrict__ xin_g, u32* __restrict__ dtu_g,
    float* __restrict__ B_g, float* __restrict__ C_g, u16* __restrict__ sz_g)
{
    __shared__ __align__(16) char sm[41088];
    u16*   smA   = (u16*)sm;              // [80][72] x (bf16)
    u16*   smB   = (u16*)(sm + 11520);    // [80][72] xin
    u16*   smU   = (u16*)sm;              // [64][136] u (reuses smA/smB)
    float* smDtr = (float*)(sm + 17408);  // [64][4]
    u16*   smC   = (u16*)(sm + 23040);    // [67][132] xc

    const int tid = threadIdx.x;
    const int w = tid >> 6, lane = tid & 63;
    const int n16 = lane & 15, quad = lane >> 4;
    const int b = blockIdx.y, c0 = blockIdx.x * CH;
    const long long tokbase = (long long)b * L_SZ + c0;

    // P0: stage x rows (bf16), float4-vectorized
    for (int idx = tid; idx < RT * 16; idx += 256) {
        int r = idx >> 4, c4 = idx & 15;
        int l = c0 - 3 + r;
        float4 v = make_float4(0.f, 0.f, 0.f, 0.f);
        if (r < 67 && l >= 0)
            v = *(const float4*)(x + ((long long)b * L_SZ + l) * 64 + c4 * 4);
        *(uint2*)((char*)smA + r * 144 + c4 * 8) = make_uint2(pk2bf(v.x, v.y), pk2bf(v.z, v.w));
    }
    __syncthreads();

    // GEMM1: xin = x @ W_in + b_in
    {
        s8 b0 = *(const s8*)(Wf1 + ((w * 2 + 0) * 64 + lane) * 8);
        s8 b1 = *(const s8*)(Wf1 + ((w * 2 + 1) * 64 + lane) * 8);
        float bias = b_in[w * 16 + n16];
        for (int m = 0; m < 5; m++) {
            int ar = m * 16 + n16;
            s8 a0 = *(const s8*)(smA + ar * PA + quad * 8);
            s8 a1 = *(const s8*)(smA + ar * PA + 32 + quad * 8);
            f4 acc = {0.f, 0.f, 0.f, 0.f};
            acc = MFMA16(a0, b0, acc, 0, 0, 0);
            acc = MFMA16(a1, b1, acc, 0, 0, 0);
#pragma unroll
            for (int reg = 0; reg < 4; reg++) {
                int rr = m * 16 + quad * 4 + reg;
                float v = acc[reg] + bias;
                smB[rr * PA + w * 16 + n16] = f2bfu(v);
                if (rr >= 3 && rr < 67)
                    xin_g[(tokbase + rr - 3) * 64 + w * 16 + n16] = v;
            }
        }
    }
    __syncthreads();

    // GEMM2: xz = xin @ in_proj (waves 0-1 -> xc, waves 2-3 -> silu(z))
    {
        s8 bf[4][2];
#pragma unroll
        for (int i = 0; i < 4; i++)
#pragma unroll
            for (int ks = 0; ks < 2; ks++)
                bf[i][ks] = *(const s8*)(Wf2 + (((w * 4 + i) * 2 + ks) * 64 + lane) * 8);
        for (int m = 0; m < 5; m++) {
            int ar = m * 16 + n16;
            s8 a0 = *(const s8*)(smB + ar * PA + quad * 8);
            s8 a1 = *(const s8*)(smB + ar * PA + 32 + quad * 8);
#pragma unroll
            for (int i = 0; i < 4; i++) {
                f4 acc = {0.f, 0.f, 0.f, 0.f};
                acc = MFMA16(a0, bf[i][0], acc, 0, 0, 0);
                acc = MFMA16(a1, bf[i][1], acc, 0, 0, 0);
                int cg = (w * 4 + i) * 16 + n16;
#pragma unroll
                for (int reg = 0; reg < 4; reg++) {
                    int rr = m * 16 + quad * 4 + reg;
                    float v = acc[reg];
                    if (cg < 128) {                     // wave-uniform branch
                        if (rr < 67) {
                            int l = c0 - 3 + rr;
                            smC[rr * PC + cg] = f2bfu(l >= 0 ? v : 0.f);
                        }
                    } else if (rr >= 3 && rr < 67) {
                        sz_g[(tokbase + rr - 3) * 128 + (cg - 128)] = f2bfu(v * fsig(v));
                    }
                }
            }
        }
    }
    __syncthreads();

    // conv(4) + silu -> u (LDS only; global u rides packed with dt below)
    {
        const int d2 = lane * 2, ctb = w * 16;
        float4 cw0 = ((const float4*)conv_w)[d2];
        float4 cw1 = ((const float4*)conv_w)[d2 + 1];
        float cb0 = conv_b[d2], cb1 = conv_b[d2 + 1];
        u32 r0 = *(const u32*)((char*)smC + (ctb + 0) * 264 + lane * 4);
        u32 r1 = *(const u32*)((char*)smC + (ctb + 1) * 264 + lane * 4);
        u32 r2 = *(const u32*)((char*)smC + (ctb + 2) * 264 + lane * 4);
#pragma unroll 4
        for (int j = 0; j < 16; j++) {
            int ct = ctb + j;
            u32 r3 = *(const u32*)((char*)smC + (ct + 3) * 264 + lane * 4);
            float v0 = cb0 + bflo(r0) * cw0.x + bflo(r1) * cw0.y + bflo(r2) * cw0.z + bflo(r3) * cw0.w;
            float v1 = cb1 + bfhi(r0) * cw1.x + bfhi(r1) * cw1.y + bfhi(r2) * cw1.z + bfhi(r3) * cw1.w;
            u32 pk = pk2bf(v0 * fsig(v0), v1 * fsig(v1));
            *(u32*)(smU + ct * PU + d2) = pk;
            r0 = r1; r1 = r2; r2 = r3;
        }
    }
    __syncthreads();

    // GEMM3: dbc = u @ x_proj  (M=64, N=48(36), K=128); wave w -> mtile w
    {
        s8 bf3[3][4];
#pragma unroll
        for (int nt = 0; nt < 3; nt++)
#pragma unroll
            for (int ks = 0; ks < 4; ks++)
                bf3[nt][ks] = *(const s8*)(Wf3 + ((nt * 4 + ks) * 64 + lane) * 8);
        f4 acc[3] = {{0.f,0.f,0.f,0.f},{0.f,0.f,0.f,0.f},{0.f,0.f,0.f,0.f}};
        int ar = w * 16 + n16;
#pragma unroll
        for (int ks = 0; ks < 4; ks++) {
            s8 a = *(const s8*)(smU + ar * PU + ks * 32 + quad * 8);
#pragma unroll
            for (int nt = 0; nt < 3; nt++) acc[nt] = MFMA16(a, bf3[nt][ks], acc[nt], 0, 0, 0);
        }
#pragma unroll
        for (int nt = 0; nt < 3; nt++) {
            int c = nt * 16 + n16;
#pragma unroll
            for (int reg = 0; reg < 4; reg++) {
                int rr = w * 16 + quad * 4 + reg;
                float v = acc[nt][reg];
                long long t = tokbase + rr;
                if (c < 4)       smDtr[rr * 4 + c] = v;
                else if (c < 20) B_g[t * 16 + (c - 4)] = v;
                else if (c < 36) C_g[t * 16 + (c - 20)] = v;
            }
        }
    }
    __syncthreads();

    // dt = softplus(dtr @ dt_proj_w + dt_proj_b); pack (dt fp16 | u bf16) per channel
    {
        const int o2 = lane * 2, grp = w;
        float w00 = dt_w[o2],       w01 = dt_w[o2 + 1];
        float w10 = dt_w[128 + o2], w11 = dt_w[128 + o2 + 1];
        float w20 = dt_w[256 + o2], w21 = dt_w[256 + o2 + 1];
        float w30 = dt_w[384 + o2], w31 = dt_w[384 + o2 + 1];
        float b0 = dt_b[o2], b1 = dt_b[o2 + 1];
#pragma unroll 4
        for (int j = 0; j < 16; j++) {
            int ct = grp * 16 + j;
            float4 q = *(const float4*)(smDtr + ct * 4);
            float v0 = b0 + q.x * w00 + q.y * w10 + q.z * w20 + q.w * w30;
            float v1 = b1 + q.x * w01 + q.y * w11 + q.z * w21 + q.w * w31;
            u32 upk = *(const u32*)(smU + ct * PU + o2);
            u32 pk0 = (u32)__half_as_ushort(__float2half_rn(fsp(v0))) | (upk << 16);
            u32 pk1 = (u32)__half_as_ushort(__float2half_rn(fsp(v1))) | (upk & 0xFFFF0000u);
            *(uint2*)(dtu_g + (tokbase + ct) * 128 + o2) = make_uint2(pk0, pk1);
        }
    }
}

// ---------------- Scan phase 1: per-chunk local states (LDS-staged dtu) ----------------
__global__ __launch_bounds__(128) void k_scan1(
    const u32* __restrict__ dtu_g, const float* __restrict__ B_g,
    const float* __restrict__ A_log,
    float* __restrict__ hl_ws, float* __restrict__ sdt_ws)
{
    __shared__ __align__(16) u32 sdtu[CLEN * 128];   // 32 KB
    const int d = threadIdx.x, c = blockIdx.x, b = blockIdx.y;
    const long long tok0 = (long long)b * L_SZ + (long long)c * CLEN;

    // Stage chunk's dtu tile: 16 independent coalesced dwordx4 per thread
    {
        const uint4* src = (const uint4*)(dtu_g + tok0 * 128);
        uint4* dst = (uint4*)sdtu;
#pragma unroll
        for (int k = 0; k < 16; k++) dst[d + k * 128] = src[d + k * 128];
    }

    float A[16];
#pragma unroll
    for (int s = 0; s < 16; s++) A[s] = -__expf(A_log[d * 16 + s]);
    const float A0 = A[0];
    bool chain = true;
#pragma unroll
    for (int s = 1; s < 16; s++)
        chain = chain && (fabsf(A[s] - (float)(s + 1) * A0) <= 1e-4f * fabsf(A[s]));

    float h[16];
#pragma unroll
    for (int s = 0; s < 16; s++) h[s] = 0.f;
    float sdt = 0.f;
    __syncthreads();

    if (chain) {
        for (int i = 0; i < CLEN; i++) {
            u32 pk = sdtu[i * 128 + d];
            float dtv = h2f(pk);
            float uv  = bfhi(pk);
            const float4* Bp = (const float4*)(B_g + (tok0 + i) * 16);
            float4 B0 = Bp[0], B1 = Bp[1], B2 = Bp[2], B3 = Bp[3];
            float Bv[16] = { B0.x, B0.y, B0.z, B0.w, B1.x, B1.y, B1.z, B1.w,
                             B2.x, B2.y, B2.z, B2.w, B3.x, B3.y, B3.z, B3.w };
            float du = dtv * uv;  sdt += dtv;
            float p = __expf(dtv * A0), dA = p;
            h[0] = dA * h[0] + du * Bv[0];
#pragma unroll
            for (int s = 1; s < 16; s++) { dA *= p; h[s] = dA * h[s] + du * Bv[s]; }
        }
    } else {
        for (int i = 0; i < CLEN; i++) {
            u32 pk = sdtu[i * 128 + d];
            float dtv = h2f(pk);
            float uv  = bfhi(pk);
            const float4* Bp = (const float4*)(B_g + (tok0 + i) * 16);
            float4 B0 = Bp[0], B1 = Bp[1], B2 = Bp[2], B3 = Bp[3];
            float Bv[16] = { B0.x, B0.y, B0.z, B0.w, B1.x, B1.y, B1.z, B1.w,
                             B2.x, B2.y, B2.z, B2.w, B3.x, B3.y, B3.z, B3.w };
            float du = dtv * uv;  sdt += dtv;
#pragma unroll
            for (int s = 0; s < 16; s++) h[s] = __expf(dtv * A[s]) * h[s] + du * Bv[s];
        }
    }

    float4* hp4 = (float4*)(hl_ws + (((long long)b * NCH + c) * 128 + d) * 16);
    hp4[0] = make_float4(h[0], h[1], h[2], h[3]);
    hp4[1] = make_float4(h[4], h[5], h[6], h[7]);
    hp4[2] = make_float4(h[8], h[9], h[10], h[11]);
    hp4[3] = make_float4(h[12], h[13], h[14], h[15]);
    sdt_ws[((long long)b * NCH + c) * 128 + d] = sdt;
}

// ---------------- Chunk-boundary combine ----------------
__global__ __launch_bounds__(256) void k_combine(
    const float* __restrict__ A_log, const float* __restrict__ hl_ws,
    const float* __restrict__ sdt_ws, float* __restrict__ hin_ws)
{
    int gid = blockIdx.x * 256 + threadIdx.x;   // 0..32767
    int b = gid >> 11;
    int rem = gid & 2047;     // d*16+s
    int d = rem >> 4;
    float A = -__expf(A_log[rem]);
    float h = 0.f;
    for (int c = 0; c < NCH; c++) {
        long long o = ((long long)b * NCH + c) * 2048 + rem;
        hin_ws[o] = h;
        float sdt = sdt_ws[((long long)b * NCH + c) * 128 + d];
        h = __expf(A * sdt) * h + hl_ws[o];
    }
}

// ---------------- Scan phase 3: final states + y (LDS-staged dtu) ----------------
__global__ __launch_bounds__(128) void k_scan3(
    const u32* __restrict__ dtu_g, const float* __restrict__ B_g,
    const float* __restrict__ C_g, const u16* __restrict__ sz_g,
    const float* __restrict__ A_log, const float* __restrict__ D_skip,
    const float* __restrict__ hin_ws, u16* __restrict__ y_g)
{
    __shared__ __align__(16) u32 sdtu[CLEN * 128];   // 32 KB
    const int d = threadIdx.x, c = blockIdx.x, b = blockIdx.y;
    const long long tok0 = (long long)b * L_SZ + (long long)c * CLEN;

    {
        const uint4* src = (const uint4*)(dtu_g + tok0 * 128);
        uint4* dst = (uint4*)sdtu;
#pragma unroll
        for (int k = 0; k < 16; k++) dst[d + k * 128] = src[d + k * 128];
    }

    float A[16];
#pragma unroll
    for (int s = 0; s < 16; s++) A[s] = -__expf(A_log[d * 16 + s]);
    const float A0 = A[0];
    bool chain = true;
#pragma unroll
    for (int s = 1; s < 16; s++)
        chain = chain && (fabsf(A[s] - (float)(s + 1) * A0) <= 1e-4f * fabsf(A[s]));

    float h[16];
    {
        const float4* hp = (const float4*)(hin_ws + (((long long)b * NCH + c) * 128 + d) * 16);
        float4 h0 = hp[0], h1 = hp[1], h2 = hp[2], h3 = hp[3];
        h[0]=h0.x; h[1]=h0.y; h[2]=h0.z; h[3]=h0.w;
        h[4]=h1.x; h[5]=h1.y; h[6]=h1.z; h[7]=h1.w;
        h[8]=h2.x; h[9]=h2.y; h[10]=h2.z; h[11]=h2.w;
        h[12]=h3.x; h[13]=h3.y; h[14]=h3.z; h[15]=h3.w;
    }
    const float Dv = D_skip[d];
    __syncthreads();

    if (chain) {
        for (int i = 0; i < CLEN; i++) {
            const long long t = tok0 + i;
            u32 pk = sdtu[i * 128 + d];
            float dtv = h2f(pk);
            float uv  = bfhi(pk);
            const float4* Bp = (const float4*)(B_g + t * 16);
            float4 B0 = Bp[0], B1 = Bp[1], B2 = Bp[2], B3 = Bp[3];
            float Bv[16] = { B0.x, B0.y, B0.z, B0.w, B1.x, B1.y, B1.z, B1.w,
                             B2.x, B2.y, B2.z, B2.w, B3.x, B3.y, B3.z, B3.w };
            const float4* Cp = (const float4*)(C_g + t * 16);
            float4 C0 = Cp[0], C1 = Cp[1], C2 = Cp[2], C3 = Cp[3];
            float Cv[16] = { C0.x, C0.y, C0.z, C0.w, C1.x, C1.y, C1.z, C1.w,
                             C2.x, C2.y, C2.z, C2.w, C3.x, C3.y, C3.z, C3.w };
            float du = dtv * uv;
            float p = __expf(dtv * A0), dA = p;
            h[0] = dA * h[0] + du * Bv[0];
            float ysum = h[0] * Cv[0];
#pragma unroll
            for (int s = 1; s < 16; s++) {
                dA *= p;
                h[s] = dA * h[s] + du * Bv[s];
                ysum += h[s] * Cv[s];
            }
            float szv = bfu2f(sz_g[t * 128 + d]);
            y_g[t * 128 + d] = f2bfu((ysum + uv * Dv) * szv);
        }
    } else {
        for (int i = 0; i < CLEN; i++) {
            const long long t = tok0 + i;
            u32 pk = sdtu[i * 128 + d];
            float dtv = h2f(pk);
            float uv  = bfhi(pk);
            const float4* Bp = (const float4*)(B_g + t * 16);
            float4 B0 = Bp[0], B1 = Bp[1], B2 = Bp[2], B3 = Bp[3];
            float Bv[16] = { B0.x, B0.y, B0.z, B0.w, B1.x, B1.y, B1.z, B1.w,
                             B2.x, B2.y, B2.z, B2.w, B3.x, B3.y, B3.z, B3.w };
            const float4* Cp = (const float4*)(C_g + t * 16);
            float4 C0 = Cp[0], C1 = Cp[1], C2 = Cp[2], C3 = Cp[3];
            float Cv[16] = { C0.x, C0.y, C0.z, C0.w, C1.x, C1.y, C1.z, C1.w,
                             C2.x, C2.y, C2.z, C2.w, C3.x, C3.y, C3.z, C3.w };
            float du = dtv * uv;
            float ysum = 0.f;
#pragma unroll
            for (int s = 0; s < 16; s++) {
                h[s] = __expf(dtv * A[s]) * h[s] + du * Bv[s];
                ysum += h[s] * Cv[s];
            }
            float szv = bfu2f(sz_g[t * 128 + d]);
            y_g[t * 128 + d] = f2bfu((ysum + uv * Dv) * szv);
        }
    }
}

// ---------------- Epilogue: out = LN(y @ out_proj + xin) ----------------
__global__ __launch_bounds__(256) void k_epilogue(
    const u16* __restrict__ y_g, const float* __restrict__ xin_g,
    const u16* __restrict__ Wf4, const float* __restrict__ gamma,
    const float* __restrict__ beta, float* __restrict__ out)
{
    __shared__ __align__(16) char sm[34048];
    u16*   yA  = (u16*)sm;            // [64][136]
    float* smR = (float*)(sm + 17408);// [64][65]

    const int tid = threadIdx.x;
    const int w = tid >> 6, lane = tid & 63;
    const int n16 = lane & 15, quad = lane >> 4;
    const long long t0 = (long long)blockIdx.x * 64;

    for (int idx = tid; idx < 64 * 64; idx += 256) {
        int r = idx >> 6, cp = idx & 63;
        u32 v = ((const u32*)y_g)[(t0 + r) * 64 + cp];
        *(u32*)((char*)yA + r * 272 + cp * 4) = v;
    }
    __syncthreads();

    {
        s8 bf[4];
#pragma unroll
        for (int ks = 0; ks < 4; ks++)
            bf[ks] = *(const s8*)(Wf4 + ((w * 4 + ks) * 64 + lane) * 8);
#pragma unroll
        for (int m = 0; m < 4; m++) {
            int ar = m * 16 + n16;
            f4 acc = {0.f, 0.f, 0.f, 0.f};
#pragma unroll
            for (int ks = 0; ks < 4; ks++) {
                s8 a = *(const s8*)(yA + ar * PU + ks * 32 + quad * 8);
                acc = MFMA16(a, bf[ks], acc, 0, 0, 0);
            }
#pragma unroll
            for (int reg = 0; reg < 4; reg++) {
                int rr = m * 16 + quad * 4 + reg;
                smR[rr * 65 + w * 16 + n16] = acc[reg];
            }
        }
    }
    __syncthreads();

    {
        int o = tid & 63, wv = tid >> 6;
        float g = gamma[o], bb = beta[o];
        for (int j = 0; j < 16; j++) {
            int rr = wv * 16 + j;
            float r = smR[rr * 65 + o] + xin_g[(t0 + rr) * 64 + o];
            float s = r;
#pragma unroll
            for (int mS = 0; mS < 6; mS++) s += __shfl_xor(s, 1 << mS, 64);
            float mu = s * (1.f / 64.f);
            float dv = r - mu;
            float vs = dv * dv;
#pragma unroll
            for (int mS = 0; mS < 6; mS++) vs += __shfl_xor(vs, 1 << mS, 64);
            out[(t0 + rr) * 64 + o] = g * dv * rsqrtf(vs * (1.f / 64.f) + LN_EPS) + bb;
        }
    }
}

extern "C" void kernel_launch(void* const* d_in, const int* in_sizes, int n_in,
                              void* d_out, int out_size, void* d_ws, size_t ws_size,
                              hipStream_t stream)
{
    const float* x       = (const float*)d_in[0];
    const float* W_in    = (const float*)d_in[1];
    const float* b_in    = (const float*)d_in[2];
    const float* in_proj = (const float*)d_in[3];
    const float* conv_w  = (const float*)d_in[4];
    const float* conv_b  = (const float*)d_in[5];
    const float* x_proj  = (const float*)d_in[6];
    const float* dt_w    = (const float*)d_in[7];
    const float* dt_b    = (const float*)d_in[8];
    const float* A_log   = (const float*)d_in[9];
    const float* D_skip  = (const float*)d_in[10];
    const float* Wout    = (const float*)d_in[11];
    const float* gamma   = (const float*)d_in[12];
    const float* beta    = (const float*)d_in[13];
    float* out = (float*)d_out;

    const long long NT = (long long)B_SZ * L_SZ;  // 131072 tokens
    char* ws = (char*)d_ws;
    float*  xin_g = (float*)ws;   ws += NT * 64 * 4;
    u32*    dtu_g = (u32*)ws;     ws += NT * 128 * 4;   // (dt fp16 | u bf16)
    float*  B_g   = (float*)ws;   ws += NT * 16 * 4;
    float*  C_g   = (float*)ws;   ws += NT * 16 * 4;
    u16*    sz_g  = (u16*)ws;     ws += NT * 128 * 2;
    u16*    y_g   = (u16*)ws;     ws += NT * 128 * 2;
    float*  hl_ws  = (float*)ws;  ws += (long long)B_SZ * NCH * 2048 * 4;
    float*  sdt_ws = (float*)ws;  ws += (long long)B_SZ * NCH * 128 * 4;
    float*  hin_ws = (float*)ws;  ws += (long long)B_SZ * NCH * 2048 * 4;
    u16* Wf1 = (u16*)ws; ws += 4096 * 2;
    u16* Wf2 = (u16*)ws; ws += 16384 * 2;
    u16* Wf3 = (u16*)ws; ws += 6144 * 2;
    u16* Wf4 = (u16*)ws; ws += 8192 * 2;

    k_prep<<<1, 256, 0, stream>>>(W_in, in_proj, x_proj, Wout, Wf1, Wf2, Wf3, Wf4);

    k_frontend<<<dim3(L_SZ / CH, B_SZ), 256, 0, stream>>>(
        x, b_in, conv_w, conv_b, dt_w, dt_b, Wf1, Wf2, Wf3,
        xin_g, dtu_g, B_g, C_g, sz_g);

    k_scan1<<<dim3(NCH, B_SZ), 128, 0, stream>>>(
        dtu_g, B_g, A_log, hl_ws, sdt_ws);

    k_combine<<<128, 256, 0, stream>>>(A_log, hl_ws, sdt_ws, hin_ws);

    k_scan3<<<dim3(NCH, B_SZ), 128, 0, stream>>>(
        dtu_g, B_g, C_g, sz_g, A_log, D_skip, hin_ws, y_g);

    k_epilogue<<<2048, 256, 0, stream>>>(y_g, xin_g, Wf4, gamma, beta, out);
}

// Round 3
// 349.065 us; speedup vs baseline: 1.0510x; 1.0407x over previous
//
#include <hip/hip_runtime.h>
#include <hip/hip_bf16.h>
#include <hip/hip_fp16.h>

#define B_SZ   16
#define L_SZ   8192
#define DM     64
#define DI     128
#define NCH    128      // scan chunks
#define CLEN   64       // L_SZ / NCH
#define CH     64       // frontend tokens per block (== CLEN: one scan chunk)
#define RT     80       // padded rows (5 mtiles of 16; 67 used)
#define PA     72       // LDS pitch (u16) for 64-wide acts: 144B
#define PU     136      // LDS pitch (u16) for 128-wide acts: 272B
#define PC     132      // LDS pitch (u16) for conv input: 264B
#define LN_EPS 1e-3f

typedef float  f4 __attribute__((ext_vector_type(4)));
typedef short  s8 __attribute__((ext_vector_type(8)));
typedef unsigned short u16;
typedef unsigned int   u32;
#define MFMA16 __builtin_amdgcn_mfma_f32_16x16x32_bf16

__device__ __forceinline__ u16 f2bfu(float f) {
    u32 u = __float_as_uint(f);
    return (u16)((u + 0x7FFFu + ((u >> 16) & 1u)) >> 16);
}
__device__ __forceinline__ u32 pk2bf(float a, float b) {
    return (u32)f2bfu(a) | ((u32)f2bfu(b) << 16);
}
__device__ __forceinline__ float bflo(u32 u) { return __uint_as_float(u << 16); }
__device__ __forceinline__ float bfhi(u32 u) { return __uint_as_float(u & 0xFFFF0000u); }
__device__ __forceinline__ float bfu2f(u16 h) { return __uint_as_float((u32)h << 16); }
__device__ __forceinline__ float h2f(u32 lo16) {
    return __half2float(__ushort_as_half((u16)(lo16 & 0xFFFFu)));
}
__device__ __forceinline__ float fsig(float v) {
    return __builtin_amdgcn_rcpf(1.f + __expf(-v));
}
__device__ __forceinline__ float fsp(float v) {   // softplus
    return fmaxf(v, 0.f) + __logf(1.f + __expf(-fabsf(v)));
}

// ---------------- Weight prep: fragment-linear bf16 granules ----------------
__global__ __launch_bounds__(256) void k_prep(
    const float* __restrict__ W_in, const float* __restrict__ in_proj,
    const float* __restrict__ x_proj, const float* __restrict__ Wout,
    u16* __restrict__ Wf1, u16* __restrict__ Wf2,
    u16* __restrict__ Wf3, u16* __restrict__ Wf4)
{
    const int tid = threadIdx.x;
    for (int g = tid; g < 512; g += 256) {          // W_in: 4 nt x 2 ks
        int lane = g & 63, ks = (g >> 6) & 1, nt = g >> 7;
        int n = nt * 16 + (lane & 15), kb = ks * 32 + (lane >> 4) * 8;
        for (int j = 0; j < 8; j++) Wf1[g * 8 + j] = f2bfu(W_in[(kb + j) * 64 + n]);
    }
    for (int g = tid; g < 2048; g += 256) {         // in_proj: 16 nt x 2 ks
        int lane = g & 63, ks = (g >> 6) & 1, nt = g >> 7;
        int n = nt * 16 + (lane & 15), kb = ks * 32 + (lane >> 4) * 8;
        for (int j = 0; j < 8; j++) Wf2[g * 8 + j] = f2bfu(in_proj[(kb + j) * 256 + n]);
    }
    for (int g = tid; g < 768; g += 256) {          // x_proj (pad N 36->48): 3 nt x 4 ks
        int lane = g & 63, ks = (g >> 6) & 3, nt = g >> 8;
        int n = nt * 16 + (lane & 15), kb = ks * 32 + (lane >> 4) * 8;
        for (int j = 0; j < 8; j++)
            Wf3[g * 8 + j] = f2bfu(n < 36 ? x_proj[(kb + j) * 36 + n] : 0.f);
    }
    for (int g = tid; g < 1024; g += 256) {         // out_proj: 4 nt x 4 ks
        int lane = g & 63, ks = (g >> 6) & 3, nt = g >> 8;
        int n = nt * 16 + (lane & 15), kb = ks * 32 + (lane >> 4) * 8;
        for (int j = 0; j < 8; j++) Wf4[g * 8 + j] = f2bfu(Wout[(kb + j) * 64 + n]);
    }
}

// ---------------- Frontend + fused chunk-local scan (scan1) ----------------
// LDS map (bytes):
//   0     .. 11520  smA  [80][72] u16  (x bf16)        } smU [64][136] u16 overlays 0..17408
//   11520 .. 23040  smB  [80][72] u16  (xin bf16)      }
//   17408 .. 18432  smDtr [64][4] f32
//   18432 .. 22528  smBf  [64][16] f32 (B for scan)
//   23040 .. 40728  smC  [67][132] u16 (conv input)    } smDtu [64][128] u32 overlays 23040..55808
__global__ __launch_bounds__(256) void k_frontend(
    const float* __restrict__ x, const float* __restrict__ b_in,
    const float* __restrict__ conv_w, const float* __restrict__ conv_b,
    const float* __restrict__ dt_w, const float* __restrict__ dt_b,
    const u16* __restrict__ Wf1, const u16* __restrict__ Wf2, const u16* __restrict__ Wf3,
    const float* __restrict__ A_log,
    float* __restrict__ xin_g, u32* __restrict__ dtu_g,
    float* __restrict__ B_g, float* __restrict__ C_g, u16* __restrict__ sz_g,
    float* __restrict__ hl_ws, float* __restrict__ sdt_ws)
{
    __shared__ __align__(16) char sm[55808];
    u16*   smA   = (u16*)sm;              // [80][72] x (bf16)
    u16*   smB   = (u16*)(sm + 11520);    // [80][72] xin
    u16*   smU   = (u16*)sm;              // [64][136] u (reuses smA/smB)
    float* smDtr = (float*)(sm + 17408);  // [64][4]
    float* smBf  = (float*)(sm + 18432);  // [64][16] B for scan
    u16*   smC   = (u16*)(sm + 23040);    // [67][132] xc
    u32*   smDtu = (u32*)(sm + 23040);    // [64][128] packed (dt|u), overlays smC after conv

    const int tid = threadIdx.x;
    const int w = tid >> 6, lane = tid & 63;
    const int n16 = lane & 15, quad = lane >> 4;
    const int b = blockIdx.y, c0 = blockIdx.x * CH;
    const long long tokbase = (long long)b * L_SZ + c0;

    // P0: stage x rows (bf16), float4-vectorized
    for (int idx = tid; idx < RT * 16; idx += 256) {
        int r = idx >> 4, c4 = idx & 15;
        int l = c0 - 3 + r;
        float4 v = make_float4(0.f, 0.f, 0.f, 0.f);
        if (r < 67 && l >= 0)
            v = *(const float4*)(x + ((long long)b * L_SZ + l) * 64 + c4 * 4);
        *(uint2*)((char*)smA + r * 144 + c4 * 8) = make_uint2(pk2bf(v.x, v.y), pk2bf(v.z, v.w));
    }
    __syncthreads();

    // GEMM1: xin = x @ W_in + b_in
    {
        s8 b0 = *(const s8*)(Wf1 + ((w * 2 + 0) * 64 + lane) * 8);
        s8 b1 = *(const s8*)(Wf1 + ((w * 2 + 1) * 64 + lane) * 8);
        float bias = b_in[w * 16 + n16];
        for (int m = 0; m < 5; m++) {
            int ar = m * 16 + n16;
            s8 a0 = *(const s8*)(smA + ar * PA + quad * 8);
            s8 a1 = *(const s8*)(smA + ar * PA + 32 + quad * 8);
            f4 acc = {0.f, 0.f, 0.f, 0.f};
            acc = MFMA16(a0, b0, acc, 0, 0, 0);
            acc = MFMA16(a1, b1, acc, 0, 0, 0);
#pragma unroll
            for (int reg = 0; reg < 4; reg++) {
                int rr = m * 16 + quad * 4 + reg;
                float v = acc[reg] + bias;
                smB[rr * PA + w * 16 + n16] = f2bfu(v);
                if (rr >= 3 && rr < 67)
                    xin_g[(tokbase + rr - 3) * 64 + w * 16 + n16] = v;
            }
        }
    }
    __syncthreads();

    // GEMM2: xz = xin @ in_proj (waves 0-1 -> xc, waves 2-3 -> silu(z))
    {
        s8 bf[4][2];
#pragma unroll
        for (int i = 0; i < 4; i++)
#pragma unroll
            for (int ks = 0; ks < 2; ks++)
                bf[i][ks] = *(const s8*)(Wf2 + (((w * 4 + i) * 2 + ks) * 64 + lane) * 8);
        for (int m = 0; m < 5; m++) {
            int ar = m * 16 + n16;
            s8 a0 = *(const s8*)(smB + ar * PA + quad * 8);
            s8 a1 = *(const s8*)(smB + ar * PA + 32 + quad * 8);
#pragma unroll
            for (int i = 0; i < 4; i++) {
                f4 acc = {0.f, 0.f, 0.f, 0.f};
                acc = MFMA16(a0, bf[i][0], acc, 0, 0, 0);
                acc = MFMA16(a1, bf[i][1], acc, 0, 0, 0);
                int cg = (w * 4 + i) * 16 + n16;
#pragma unroll
                for (int reg = 0; reg < 4; reg++) {
                    int rr = m * 16 + quad * 4 + reg;
                    float v = acc[reg];
                    if (cg < 128) {                     // wave-uniform branch
                        if (rr < 67) {
                            int l = c0 - 3 + rr;
                            smC[rr * PC + cg] = f2bfu(l >= 0 ? v : 0.f);
                        }
                    } else if (rr >= 3 && rr < 67) {
                        sz_g[(tokbase + rr - 3) * 128 + (cg - 128)] = f2bfu(v * fsig(v));
                    }
                }
            }
        }
    }
    __syncthreads();

    // conv(4) + silu -> u (LDS only)
    {
        const int d2 = lane * 2, ctb = w * 16;
        float4 cw0 = ((const float4*)conv_w)[d2];
        float4 cw1 = ((const float4*)conv_w)[d2 + 1];
        float cb0 = conv_b[d2], cb1 = conv_b[d2 + 1];
        u32 r0 = *(const u32*)((char*)smC + (ctb + 0) * 264 + lane * 4);
        u32 r1 = *(const u32*)((char*)smC + (ctb + 1) * 264 + lane * 4);
        u32 r2 = *(const u32*)((char*)smC + (ctb + 2) * 264 + lane * 4);
#pragma unroll 4
        for (int j = 0; j < 16; j++) {
            int ct = ctb + j;
            u32 r3 = *(const u32*)((char*)smC + (ct + 3) * 264 + lane * 4);
            float v0 = cb0 + bflo(r0) * cw0.x + bflo(r1) * cw0.y + bflo(r2) * cw0.z + bflo(r3) * cw0.w;
            float v1 = cb1 + bfhi(r0) * cw1.x + bfhi(r1) * cw1.y + bfhi(r2) * cw1.z + bfhi(r3) * cw1.w;
            u32 pk = pk2bf(v0 * fsig(v0), v1 * fsig(v1));
            *(u32*)(smU + ct * PU + d2) = pk;
            r0 = r1; r1 = r2; r2 = r3;
        }
    }
    __syncthreads();

    // GEMM3: dbc = u @ x_proj  (M=64, N=48(36), K=128); wave w -> mtile w
    {
        s8 bf3[3][4];
#pragma unroll
        for (int nt = 0; nt < 3; nt++)
#pragma unroll
            for (int ks = 0; ks < 4; ks++)
                bf3[nt][ks] = *(const s8*)(Wf3 + ((nt * 4 + ks) * 64 + lane) * 8);
        f4 acc[3] = {{0.f,0.f,0.f,0.f},{0.f,0.f,0.f,0.f},{0.f,0.f,0.f,0.f}};
        int ar = w * 16 + n16;
#pragma unroll
        for (int ks = 0; ks < 4; ks++) {
            s8 a = *(const s8*)(smU + ar * PU + ks * 32 + quad * 8);
#pragma unroll
            for (int nt = 0; nt < 3; nt++) acc[nt] = MFMA16(a, bf3[nt][ks], acc[nt], 0, 0, 0);
        }
#pragma unroll
        for (int nt = 0; nt < 3; nt++) {
            int c = nt * 16 + n16;
#pragma unroll
            for (int reg = 0; reg < 4; reg++) {
                int rr = w * 16 + quad * 4 + reg;
                float v = acc[nt][reg];
                long long t = tokbase + rr;
                if (c < 4)       smDtr[rr * 4 + c] = v;
                else if (c < 20) { B_g[t * 16 + (c - 4)] = v; smBf[rr * 16 + (c - 4)] = v; }
                else if (c < 36) C_g[t * 16 + (c - 20)] = v;
            }
        }
    }
    __syncthreads();   // smC dead; smDtu region now writable

    // dt = softplus(dtr @ dt_proj_w + dt_proj_b); pack (dt fp16 | u bf16) -> global + LDS
    {
        const int o2 = lane * 2, grp = w;
        float w00 = dt_w[o2],       w01 = dt_w[o2 + 1];
        float w10 = dt_w[128 + o2], w11 = dt_w[128 + o2 + 1];
        float w20 = dt_w[256 + o2], w21 = dt_w[256 + o2 + 1];
        float w30 = dt_w[384 + o2], w31 = dt_w[384 + o2 + 1];
        float b0 = dt_b[o2], b1 = dt_b[o2 + 1];
#pragma unroll 4
        for (int j = 0; j < 16; j++) {
            int ct = grp * 16 + j;
            float4 q = *(const float4*)(smDtr + ct * 4);
            float v0 = b0 + q.x * w00 + q.y * w10 + q.z * w20 + q.w * w30;
            float v1 = b1 + q.x * w01 + q.y * w11 + q.z * w21 + q.w * w31;
            u32 upk = *(const u32*)(smU + ct * PU + o2);
            u32 pk0 = (u32)__half_as_ushort(__float2half_rn(fsp(v0))) | (upk << 16);
            u32 pk1 = (u32)__half_as_ushort(__float2half_rn(fsp(v1))) | (upk & 0xFFFF0000u);
            *(uint2*)(dtu_g + (tokbase + ct) * 128 + o2) = make_uint2(pk0, pk1);
            *(uint2*)(smDtu + ct * 128 + o2) = make_uint2(pk0, pk1);
        }
    }
    __syncthreads();

    // Fused chunk-local scan (was k_scan1): 2 threads/channel x 8 states, no shuffles
    {
        const int d = tid & 127, sh = tid >> 7, s0 = sh * 8;
        const float A0g = -__expf(A_log[d * 16]);
        float A[8];
#pragma unroll
        for (int s = 0; s < 8; s++) A[s] = -__expf(A_log[d * 16 + s0 + s]);
        bool chl = true;
#pragma unroll
        for (int s = 0; s < 8; s++)
            chl = chl && (fabsf(A[s] - (float)(s0 + s + 1) * A0g) <= 1e-4f * fabsf(A[s]));
        const bool chain = __all(chl);

        float h[8];
#pragma unroll
        for (int s = 0; s < 8; s++) h[s] = 0.f;
        float sdt = 0.f;

        if (chain) {
            for (int i = 0; i < CLEN; i++) {
                u32 pk = smDtu[i * 128 + d];
                float dtv = h2f(pk);
                float uv  = bfhi(pk);
                float du  = dtv * uv;  sdt += dtv;
                float4 b0 = *(const float4*)(smBf + i * 16 + s0);
                float4 b1 = *(const float4*)(smBf + i * 16 + s0 + 4);
                float p  = __expf(dtv * A0g);
                float p2 = p * p, p4 = p2 * p2;
                float dA = sh ? p4 * p4 * p : p;      // p^9 or p^1
                h[0] = dA * h[0] + du * b0.x;
                dA *= p; h[1] = dA * h[1] + du * b0.y;
                dA *= p; h[2] = dA * h[2] + du * b0.z;
                dA *= p; h[3] = dA * h[3] + du * b0.w;
                dA *= p; h[4] = dA * h[4] + du * b1.x;
                dA *= p; h[5] = dA * h[5] + du * b1.y;
                dA *= p; h[6] = dA * h[6] + du * b1.z;
                dA *= p; h[7] = dA * h[7] + du * b1.w;
            }
        } else {
            for (int i = 0; i < CLEN; i++) {
                u32 pk = smDtu[i * 128 + d];
                float dtv = h2f(pk);
                float uv  = bfhi(pk);
                float du  = dtv * uv;  sdt += dtv;
                const float* Bp = smBf + i * 16 + s0;
#pragma unroll
                for (int s = 0; s < 8; s++) h[s] = __expf(dtv * A[s]) * h[s] + du * Bp[s];
            }
        }

        const int c = blockIdx.x;
        float4* hp4 = (float4*)(hl_ws + (((long long)b * NCH + c) * 128 + d) * 16 + s0);
        hp4[0] = make_float4(h[0], h[1], h[2], h[3]);
        hp4[1] = make_float4(h[4], h[5], h[6], h[7]);
        if (sh == 0) sdt_ws[((long long)b * NCH + c) * 128 + d] = sdt;
    }
}

// ---------------- Chunk-boundary combine ----------------
__global__ __launch_bounds__(256) void k_combine(
    const float* __restrict__ A_log, const float* __restrict__ hl_ws,
    const float* __restrict__ sdt_ws, float* __restrict__ hin_ws)
{
    int gid = blockIdx.x * 256 + threadIdx.x;   // 0..32767
    int b = gid >> 11;
    int rem = gid & 2047;     // d*16+s
    int d = rem >> 4;
    float A = -__expf(A_log[rem]);
    float h = 0.f;
    for (int c = 0; c < NCH; c++) {
        long long o = ((long long)b * NCH + c) * 2048 + rem;
        hin_ws[o] = h;
        float sdt = sdt_ws[((long long)b * NCH + c) * 128 + d];
        h = __expf(A * sdt) * h + hl_ws[o];
    }
}

// ---------------- Scan phase 3: final states + y (LDS-staged dtu + B) ----------------
__global__ __launch_bounds__(128) void k_scan3(
    const u32* __restrict__ dtu_g, const float* __restrict__ B_g,
    const float* __restrict__ C_g, const u16* __restrict__ sz_g,
    const float* __restrict__ A_log, const float* __restrict__ D_skip,
    const float* __restrict__ hin_ws, u16* __restrict__ y_g)
{
    __shared__ __align__(16) u32 sdtu[CLEN * 128];   // 32 KB
    __shared__ __align__(16) float sB[CLEN * 16];    // 4 KB
    const int d = threadIdx.x, c = blockIdx.x, b = blockIdx.y;
    const long long tok0 = (long long)b * L_SZ + (long long)c * CLEN;

    {
        const uint4* src = (const uint4*)(dtu_g + tok0 * 128);
        uint4* dst = (uint4*)sdtu;
#pragma unroll
        for (int k = 0; k < 16; k++) dst[d + k * 128] = src[d + k * 128];
        const float4* bs = (const float4*)(B_g + tok0 * 16);
        float4* bd = (float4*)sB;
        bd[d] = bs[d];
        bd[d + 128] = bs[d + 128];
    }

    float A[16];
#pragma unroll
    for (int s = 0; s < 16; s++) A[s] = -__expf(A_log[d * 16 + s]);
    const float A0 = A[0];
    bool chain = true;
#pragma unroll
    for (int s = 1; s < 16; s++)
        chain = chain && (fabsf(A[s] - (float)(s + 1) * A0) <= 1e-4f * fabsf(A[s]));

    float h[16];
    {
        const float4* hp = (const float4*)(hin_ws + (((long long)b * NCH + c) * 128 + d) * 16);
        float4 h0 = hp[0], h1 = hp[1], h2 = hp[2], h3 = hp[3];
        h[0]=h0.x; h[1]=h0.y; h[2]=h0.z; h[3]=h0.w;
        h[4]=h1.x; h[5]=h1.y; h[6]=h1.z; h[7]=h1.w;
        h[8]=h2.x; h[9]=h2.y; h[10]=h2.z; h[11]=h2.w;
        h[12]=h3.x; h[13]=h3.y; h[14]=h3.z; h[15]=h3.w;
    }
    const float Dv = D_skip[d];
    __syncthreads();

    if (chain) {
        for (int i = 0; i < CLEN; i++) {
            const long long t = tok0 + i;
            u32 pk = sdtu[i * 128 + d];
            float dtv = h2f(pk);
            float uv  = bfhi(pk);
            const float4* Bp = (const float4*)(sB + i * 16);
            float4 B0 = Bp[0], B1 = Bp[1], B2 = Bp[2], B3 = Bp[3];
            float Bv[16] = { B0.x, B0.y, B0.z, B0.w, B1.x, B1.y, B1.z, B1.w,
                             B2.x, B2.y, B2.z, B2.w, B3.x, B3.y, B3.z, B3.w };
            const float4* Cp = (const float4*)(C_g + t * 16);
            float4 C0 = Cp[0], C1 = Cp[1], C2 = Cp[2], C3 = Cp[3];
            float Cv[16] = { C0.x, C0.y, C0.z, C0.w, C1.x, C1.y, C1.z, C1.w,
                             C2.x, C2.y, C2.z, C2.w, C3.x, C3.y, C3.z, C3.w };
            float du = dtv * uv;
            float p = __expf(dtv * A0), dA = p;
            h[0] = dA * h[0] + du * Bv[0];
            float ysum = h[0] * Cv[0];
#pragma unroll
            for (int s = 1; s < 16; s++) {
                dA *= p;
                h[s] = dA * h[s] + du * Bv[s];
                ysum += h[s] * Cv[s];
            }
            float szv = bfu2f(sz_g[t * 128 + d]);
            y_g[t * 128 + d] = f2bfu((ysum + uv * Dv) * szv);
        }
    } else {
        for (int i = 0; i < CLEN; i++) {
            const long long t = tok0 + i;
            u32 pk = sdtu[i * 128 + d];
            float dtv = h2f(pk);
            float uv  = bfhi(pk);
            const float4* Bp = (const float4*)(sB + i * 16);
            float4 B0 = Bp[0], B1 = Bp[1], B2 = Bp[2], B3 = Bp[3];
            float Bv[16] = { B0.x, B0.y, B0.z, B0.w, B1.x, B1.y, B1.z, B1.w,
                             B2.x, B2.y, B2.z, B2.w, B3.x, B3.y, B3.z, B3.w };
            const float4* Cp = (const float4*)(C_g + t * 16);
            float4 C0 = Cp[0], C1 = Cp[1], C2 = Cp[2], C3 = Cp[3];
            float Cv[16] = { C0.x, C0.y, C0.z, C0.w, C1.x, C1.y, C1.z, C1.w,
                             C2.x, C2.y, C2.z, C2.w, C3.x, C3.y, C3.z, C3.w };
            float du = dtv * uv;
            float ysum = 0.f;
#pragma unroll
            for (int s = 0; s < 16; s++) {
                h[s] = __expf(dtv * A[s]) * h[s] + du * Bv[s];
                ysum += h[s] * Cv[s];
            }
            float szv = bfu2f(sz_g[t * 128 + d]);
            y_g[t * 128 + d] = f2bfu((ysum + uv * Dv) * szv);
        }
    }
}

// ---------------- Epilogue: out = LN(y @ out_proj + xin) ----------------
__global__ __launch_bounds__(256) void k_epilogue(
    const u16* __restrict__ y_g, const float* __restrict__ xin_g,
    const u16* __restrict__ Wf4, const float* __restrict__ gamma,
    const float* __restrict__ beta, float* __restrict__ out)
{
    __shared__ __align__(16) char sm[34048];
    u16*   yA  = (u16*)sm;            // [64][136]
    float* smR = (float*)(sm + 17408);// [64][65]

    const int tid = threadIdx.x;
    const int w = tid >> 6, lane = tid & 63;
    const int n16 = lane & 15, quad = lane >> 4;
    const long long t0 = (long long)blockIdx.x * 64;

    for (int idx = tid; idx < 64 * 64; idx += 256) {
        int r = idx >> 6, cp = idx & 63;
        u32 v = ((const u32*)y_g)[(t0 + r) * 64 + cp];
        *(u32*)((char*)yA + r * 272 + cp * 4) = v;
    }
    __syncthreads();

    {
        s8 bf[4];
#pragma unroll
        for (int ks = 0; ks < 4; ks++)
            bf[ks] = *(const s8*)(Wf4 + ((w * 4 + ks) * 64 + lane) * 8);
#pragma unroll
        for (int m = 0; m < 4; m++) {
            int ar = m * 16 + n16;
            f4 acc = {0.f, 0.f, 0.f, 0.f};
#pragma unroll
            for (int ks = 0; ks < 4; ks++) {
                s8 a = *(const s8*)(yA + ar * PU + ks * 32 + quad * 8);
                acc = MFMA16(a, bf[ks], acc, 0, 0, 0);
            }
#pragma unroll
            for (int reg = 0; reg < 4; reg++) {
                int rr = m * 16 + quad * 4 + reg;
                smR[rr * 65 + w * 16 + n16] = acc[reg];
            }
        }
    }
    __syncthreads();

    {
        int o = tid & 63, wv = tid >> 6;
        float g = gamma[o], bb = beta[o];
        for (int j = 0; j < 16; j++) {
            int rr = wv * 16 + j;
            float r = smR[rr * 65 + o] + xin_g[(t0 + rr) * 64 + o];
            float s = r;
#pragma unroll
            for (int mS = 0; mS < 6; mS++) s += __shfl_xor(s, 1 << mS, 64);
            float mu = s * (1.f / 64.f);
            float dv = r - mu;
            float vs = dv * dv;
#pragma unroll
            for (int mS = 0; mS < 6; mS++) vs += __shfl_xor(vs, 1 << mS, 64);
            out[(t0 + rr) * 64 + o] = g * dv * rsqrtf(vs * (1.f / 64.f) + LN_EPS) + bb;
        }
    }
}

extern "C" void kernel_launch(void* const* d_in, const int* in_sizes, int n_in,
                              void* d_out, int out_size, void* d_ws, size_t ws_size,
                              hipStream_t stream)
{
    const float* x       = (const float*)d_in[0];
    const float* W_in    = (const float*)d_in[1];
    const float* b_in    = (const float*)d_in[2];
    const float* in_proj = (const float*)d_in[3];
    const float* conv_w  = (const float*)d_in[4];
    const float* conv_b  = (const float*)d_in[5];
    const float* x_proj  = (const float*)d_in[6];
    const float* dt_w    = (const float*)d_in[7];
    const float* dt_b    = (const float*)d_in[8];
    const float* A_log   = (const float*)d_in[9];
    const float* D_skip  = (const float*)d_in[10];
    const float* Wout    = (const float*)d_in[11];
    const float* gamma   = (const float*)d_in[12];
    const float* beta    = (const float*)d_in[13];
    float* out = (float*)d_out;

    const long long NT = (long long)B_SZ * L_SZ;  // 131072 tokens
    char* ws = (char*)d_ws;
    float*  xin_g = (float*)ws;   ws += NT * 64 * 4;
    u32*    dtu_g = (u32*)ws;     ws += NT * 128 * 4;   // (dt fp16 | u bf16)
    float*  B_g   = (float*)ws;   ws += NT * 16 * 4;
    float*  C_g   = (float*)ws;   ws += NT * 16 * 4;
    u16*    sz_g  = (u16*)ws;     ws += NT * 128 * 2;
    u16*    y_g   = (u16*)ws;     ws += NT * 128 * 2;
    float*  hl_ws  = (float*)ws;  ws += (long long)B_SZ * NCH * 2048 * 4;
    float*  sdt_ws = (float*)ws;  ws += (long long)B_SZ * NCH * 128 * 4;
    float*  hin_ws = (float*)ws;  ws += (long long)B_SZ * NCH * 2048 * 4;
    u16* Wf1 = (u16*)ws; ws += 4096 * 2;
    u16* Wf2 = (u16*)ws; ws += 16384 * 2;
    u16* Wf3 = (u16*)ws; ws += 6144 * 2;
    u16* Wf4 = (u16*)ws; ws += 8192 * 2;

    k_prep<<<1, 256, 0, stream>>>(W_in, in_proj, x_proj, Wout, Wf1, Wf2, Wf3, Wf4);

    k_frontend<<<dim3(L_SZ / CH, B_SZ), 256, 0, stream>>>(
        x, b_in, conv_w, conv_b, dt_w, dt_b, Wf1, Wf2, Wf3, A_log,
        xin_g, dtu_g, B_g, C_g, sz_g, hl_ws, sdt_ws);

    k_combine<<<128, 256, 0, stream>>>(A_log, hl_ws, sdt_ws, hin_ws);

    k_scan3<<<dim3(NCH, B_SZ), 128, 0, stream>>>(
        dtu_g, B_g, C_g, sz_g, A_log, D_skip, hin_ws, y_g);

    k_epilogue<<<2048, 256, 0, stream>>>(y_g, xin_g, Wf4, gamma, beta, out);
}

// Round 4
// 347.328 us; speedup vs baseline: 1.0562x; 1.0050x over previous
//
#include <hip/hip_runtime.h>
#include <hip/hip_bf16.h>
#include <hip/hip_fp16.h>

#define B_SZ   16
#define L_SZ   8192
#define DM     64
#define DI     128
#define NCH    128      // scan chunks
#define CLEN   64       // L_SZ / NCH
#define CH     64       // frontend tokens per block (== CLEN: one scan chunk)
#define RT     80       // padded rows (5 mtiles of 16; 67 used)
#define PA     72       // LDS pitch (u16) for 64-wide acts: 144B
#define PU     136      // LDS pitch (u16) for 128-wide acts: 272B
#define PC     132      // LDS pitch (u16) for conv input: 264B
#define LN_EPS 1e-3f

typedef float  f4 __attribute__((ext_vector_type(4)));
typedef short  s8 __attribute__((ext_vector_type(8)));
typedef unsigned short u16;
typedef unsigned int   u32;
#define MFMA16 __builtin_amdgcn_mfma_f32_16x16x32_bf16

__device__ __forceinline__ u16 f2bfu(float f) {
    u32 u = __float_as_uint(f);
    return (u16)((u + 0x7FFFu + ((u >> 16) & 1u)) >> 16);
}
__device__ __forceinline__ u32 pk2bf(float a, float b) {
    return (u32)f2bfu(a) | ((u32)f2bfu(b) << 16);
}
__device__ __forceinline__ float bflo(u32 u) { return __uint_as_float(u << 16); }
__device__ __forceinline__ float bfhi(u32 u) { return __uint_as_float(u & 0xFFFF0000u); }
__device__ __forceinline__ float bfu2f(u16 h) { return __uint_as_float((u32)h << 16); }
__device__ __forceinline__ float h2f(u32 lo16) {
    return __half2float(__ushort_as_half((u16)(lo16 & 0xFFFFu)));
}
__device__ __forceinline__ float fsig(float v) {
    return __builtin_amdgcn_rcpf(1.f + __expf(-v));
}
__device__ __forceinline__ float fsp(float v) {   // softplus
    return fmaxf(v, 0.f) + __logf(1.f + __expf(-fabsf(v)));
}

// ---------------- Weight prep: fragment-linear bf16 granules ----------------
__global__ __launch_bounds__(256) void k_prep(
    const float* __restrict__ W_in, const float* __restrict__ in_proj,
    const float* __restrict__ x_proj, const float* __restrict__ Wout,
    u16* __restrict__ Wf1, u16* __restrict__ Wf2,
    u16* __restrict__ Wf3, u16* __restrict__ Wf4)
{
    const int tid = threadIdx.x;
    for (int g = tid; g < 512; g += 256) {          // W_in: 4 nt x 2 ks
        int lane = g & 63, ks = (g >> 6) & 1, nt = g >> 7;
        int n = nt * 16 + (lane & 15), kb = ks * 32 + (lane >> 4) * 8;
        for (int j = 0; j < 8; j++) Wf1[g * 8 + j] = f2bfu(W_in[(kb + j) * 64 + n]);
    }
    for (int g = tid; g < 2048; g += 256) {         // in_proj: 16 nt x 2 ks
        int lane = g & 63, ks = (g >> 6) & 1, nt = g >> 7;
        int n = nt * 16 + (lane & 15), kb = ks * 32 + (lane >> 4) * 8;
        for (int j = 0; j < 8; j++) Wf2[g * 8 + j] = f2bfu(in_proj[(kb + j) * 256 + n]);
    }
    for (int g = tid; g < 768; g += 256) {          // x_proj (pad N 36->48): 3 nt x 4 ks
        int lane = g & 63, ks = (g >> 6) & 3, nt = g >> 8;
        int n = nt * 16 + (lane & 15), kb = ks * 32 + (lane >> 4) * 8;
        for (int j = 0; j < 8; j++)
            Wf3[g * 8 + j] = f2bfu(n < 36 ? x_proj[(kb + j) * 36 + n] : 0.f);
    }
    for (int g = tid; g < 1024; g += 256) {         // out_proj: 4 nt x 4 ks
        int lane = g & 63, ks = (g >> 6) & 3, nt = g >> 8;
        int n = nt * 16 + (lane & 15), kb = ks * 32 + (lane >> 4) * 8;
        for (int j = 0; j < 8; j++) Wf4[g * 8 + j] = f2bfu(Wout[(kb + j) * 64 + n]);
    }
}

// ---------------- Frontend + fused chunk-local scan (scan1) ----------------
// LDS map (bytes), total 40736 -> 4 blocks/CU:
//   0     .. 17408  smA/smB (x, xin)  -> smU [64][136] u16 after conv
//   17408 .. 18432  smDtr [64][4] f32
//   18432 .. 22528  smBf  [64][16] f32 (B for scan)
//   23040 .. 40728  smC   [67][132] u16 (conv input)
//   23040 .. 39424  smDt  [64][64] u32 (fp16 dt pairs) overlays dead smC
__global__ __launch_bounds__(256) void k_frontend(
    const float* __restrict__ x, const float* __restrict__ b_in,
    const float* __restrict__ conv_w, const float* __restrict__ conv_b,
    const float* __restrict__ dt_w, const float* __restrict__ dt_b,
    const u16* __restrict__ Wf1, const u16* __restrict__ Wf2, const u16* __restrict__ Wf3,
    const float* __restrict__ A_log,
    float* __restrict__ xin_g, u32* __restrict__ dtu_g,
    float* __restrict__ B_g, float* __restrict__ C_g, u16* __restrict__ sz_g,
    float* __restrict__ hl_ws, float* __restrict__ sdt_ws)
{
    __shared__ __align__(16) char sm[40736];
    u16*   smA   = (u16*)sm;              // [80][72] x (bf16)
    u16*   smB   = (u16*)(sm + 11520);    // [80][72] xin
    u16*   smU   = (u16*)sm;              // [64][136] u (reuses smA/smB)
    float* smDtr = (float*)(sm + 17408);  // [64][4]
    float* smBf  = (float*)(sm + 18432);  // [64][16] B for scan
    u16*   smC   = (u16*)(sm + 23040);    // [67][132] xc
    u32*   smDt  = (u32*)(sm + 23040);    // [64][64] fp16 dt pairs, overlays dead smC

    const int tid = threadIdx.x;
    const int w = tid >> 6, lane = tid & 63;
    const int n16 = lane & 15, quad = lane >> 4;
    const int b = blockIdx.y, c0 = blockIdx.x * CH;
    const long long tokbase = (long long)b * L_SZ + c0;

    // P0: stage x rows (bf16), float4-vectorized
    for (int idx = tid; idx < RT * 16; idx += 256) {
        int r = idx >> 4, c4 = idx & 15;
        int l = c0 - 3 + r;
        float4 v = make_float4(0.f, 0.f, 0.f, 0.f);
        if (r < 67 && l >= 0)
            v = *(const float4*)(x + ((long long)b * L_SZ + l) * 64 + c4 * 4);
        *(uint2*)((char*)smA + r * 144 + c4 * 8) = make_uint2(pk2bf(v.x, v.y), pk2bf(v.z, v.w));
    }
    __syncthreads();

    // GEMM1: xin = x @ W_in + b_in
    {
        s8 b0 = *(const s8*)(Wf1 + ((w * 2 + 0) * 64 + lane) * 8);
        s8 b1 = *(const s8*)(Wf1 + ((w * 2 + 1) * 64 + lane) * 8);
        float bias = b_in[w * 16 + n16];
        for (int m = 0; m < 5; m++) {
            int ar = m * 16 + n16;
            s8 a0 = *(const s8*)(smA + ar * PA + quad * 8);
            s8 a1 = *(const s8*)(smA + ar * PA + 32 + quad * 8);
            f4 acc = {0.f, 0.f, 0.f, 0.f};
            acc = MFMA16(a0, b0, acc, 0, 0, 0);
            acc = MFMA16(a1, b1, acc, 0, 0, 0);
#pragma unroll
            for (int reg = 0; reg < 4; reg++) {
                int rr = m * 16 + quad * 4 + reg;
                float v = acc[reg] + bias;
                smB[rr * PA + w * 16 + n16] = f2bfu(v);
                if (rr >= 3 && rr < 67)
                    xin_g[(tokbase + rr - 3) * 64 + w * 16 + n16] = v;
            }
        }
    }
    __syncthreads();

    // GEMM2: xz = xin @ in_proj (waves 0-1 -> xc, waves 2-3 -> silu(z))
    {
        s8 bf[4][2];
#pragma unroll
        for (int i = 0; i < 4; i++)
#pragma unroll
            for (int ks = 0; ks < 2; ks++)
                bf[i][ks] = *(const s8*)(Wf2 + (((w * 4 + i) * 2 + ks) * 64 + lane) * 8);
        for (int m = 0; m < 5; m++) {
            int ar = m * 16 + n16;
            s8 a0 = *(const s8*)(smB + ar * PA + quad * 8);
            s8 a1 = *(const s8*)(smB + ar * PA + 32 + quad * 8);
#pragma unroll
            for (int i = 0; i < 4; i++) {
                f4 acc = {0.f, 0.f, 0.f, 0.f};
                acc = MFMA16(a0, bf[i][0], acc, 0, 0, 0);
                acc = MFMA16(a1, bf[i][1], acc, 0, 0, 0);
                int cg = (w * 4 + i) * 16 + n16;
#pragma unroll
                for (int reg = 0; reg < 4; reg++) {
                    int rr = m * 16 + quad * 4 + reg;
                    float v = acc[reg];
                    if (cg < 128) {                     // wave-uniform branch
                        if (rr < 67) {
                            int l = c0 - 3 + rr;
                            smC[rr * PC + cg] = f2bfu(l >= 0 ? v : 0.f);
                        }
                    } else if (rr >= 3 && rr < 67) {
                        sz_g[(tokbase + rr - 3) * 128 + (cg - 128)] = f2bfu(v * fsig(v));
                    }
                }
            }
        }
    }
    __syncthreads();

    // conv(4) + silu -> u (LDS only)
    {
        const int d2 = lane * 2, ctb = w * 16;
        float4 cw0 = ((const float4*)conv_w)[d2];
        float4 cw1 = ((const float4*)conv_w)[d2 + 1];
        float cb0 = conv_b[d2], cb1 = conv_b[d2 + 1];
        u32 r0 = *(const u32*)((char*)smC + (ctb + 0) * 264 + lane * 4);
        u32 r1 = *(const u32*)((char*)smC + (ctb + 1) * 264 + lane * 4);
        u32 r2 = *(const u32*)((char*)smC + (ctb + 2) * 264 + lane * 4);
#pragma unroll 4
        for (int j = 0; j < 16; j++) {
            int ct = ctb + j;
            u32 r3 = *(const u32*)((char*)smC + (ct + 3) * 264 + lane * 4);
            float v0 = cb0 + bflo(r0) * cw0.x + bflo(r1) * cw0.y + bflo(r2) * cw0.z + bflo(r3) * cw0.w;
            float v1 = cb1 + bfhi(r0) * cw1.x + bfhi(r1) * cw1.y + bfhi(r2) * cw1.z + bfhi(r3) * cw1.w;
            u32 pk = pk2bf(v0 * fsig(v0), v1 * fsig(v1));
            *(u32*)(smU + ct * PU + d2) = pk;
            r0 = r1; r1 = r2; r2 = r3;
        }
    }
    __syncthreads();

    // GEMM3: dbc = u @ x_proj  (M=64, N=48(36), K=128); wave w -> mtile w
    {
        s8 bf3[3][4];
#pragma unroll
        for (int nt = 0; nt < 3; nt++)
#pragma unroll
            for (int ks = 0; ks < 4; ks++)
                bf3[nt][ks] = *(const s8*)(Wf3 + ((nt * 4 + ks) * 64 + lane) * 8);
        f4 acc[3] = {{0.f,0.f,0.f,0.f},{0.f,0.f,0.f,0.f},{0.f,0.f,0.f,0.f}};
        int ar = w * 16 + n16;
#pragma unroll
        for (int ks = 0; ks < 4; ks++) {
            s8 a = *(const s8*)(smU + ar * PU + ks * 32 + quad * 8);
#pragma unroll
            for (int nt = 0; nt < 3; nt++) acc[nt] = MFMA16(a, bf3[nt][ks], acc[nt], 0, 0, 0);
        }
#pragma unroll
        for (int nt = 0; nt < 3; nt++) {
            int c = nt * 16 + n16;
#pragma unroll
            for (int reg = 0; reg < 4; reg++) {
                int rr = w * 16 + quad * 4 + reg;
                float v = acc[nt][reg];
                long long t = tokbase + rr;
                if (c < 4)       smDtr[rr * 4 + c] = v;
                else if (c < 20) { B_g[t * 16 + (c - 4)] = v; smBf[rr * 16 + (c - 4)] = v; }
                else if (c < 36) C_g[t * 16 + (c - 20)] = v;
            }
        }
    }
    __syncthreads();   // smC dead; smDt region now writable

    // dt = softplus(dtr @ dt_proj_w + dt_proj_b); fp16 pair -> smDt; packed (dt|u) -> global
    {
        const int o2 = lane * 2, grp = w;
        float w00 = dt_w[o2],       w01 = dt_w[o2 + 1];
        float w10 = dt_w[128 + o2], w11 = dt_w[128 + o2 + 1];
        float w20 = dt_w[256 + o2], w21 = dt_w[256 + o2 + 1];
        float w30 = dt_w[384 + o2], w31 = dt_w[384 + o2 + 1];
        float b0 = dt_b[o2], b1 = dt_b[o2 + 1];
#pragma unroll 4
        for (int j = 0; j < 16; j++) {
            int ct = grp * 16 + j;
            float4 q = *(const float4*)(smDtr + ct * 4);
            float v0 = b0 + q.x * w00 + q.y * w10 + q.z * w20 + q.w * w30;
            float v1 = b1 + q.x * w01 + q.y * w11 + q.z * w21 + q.w * w31;
            u32 hpk = (u32)__half_as_ushort(__float2half_rn(fsp(v0))) |
                      ((u32)__half_as_ushort(__float2half_rn(fsp(v1))) << 16);
            smDt[ct * 64 + lane] = hpk;
            u32 upk = *(const u32*)(smU + ct * PU + o2);
            u32 pk0 = (hpk & 0xFFFFu) | (upk << 16);
            u32 pk1 = (hpk >> 16) | (upk & 0xFFFF0000u);
            *(uint2*)(dtu_g + (tokbase + ct) * 128 + o2) = make_uint2(pk0, pk1);
        }
    }
    __syncthreads();

    // Fused chunk-local scan (was k_scan1): 2 threads/channel x 8 states, no shuffles
    {
        const int d = tid & 127, sh = tid >> 7, s0 = sh * 8;
        const float A0g = -__expf(A_log[d * 16]);
        float A[8];
#pragma unroll
        for (int s = 0; s < 8; s++) A[s] = -__expf(A_log[d * 16 + s0 + s]);
        bool chl = true;
#pragma unroll
        for (int s = 0; s < 8; s++)
            chl = chl && (fabsf(A[s] - (float)(s0 + s + 1) * A0g) <= 1e-4f * fabsf(A[s]));
        const bool chain = __all(chl);

        float h[8];
#pragma unroll
        for (int s = 0; s < 8; s++) h[s] = 0.f;
        float sdt = 0.f;
        const int j2 = d >> 1, hi = d & 1;

        if (chain) {
            for (int i = 0; i < CLEN; i++) {
                u32 q = smDt[i * 64 + j2];
                float dtv = __half2float(__ushort_as_half((u16)(hi ? (q >> 16) : (q & 0xFFFFu))));
                float uv  = bfu2f(smU[i * PU + d]);
                float du  = dtv * uv;  sdt += dtv;
                float4 b0 = *(const float4*)(smBf + i * 16 + s0);
                float4 b1 = *(const float4*)(smBf + i * 16 + s0 + 4);
                float p  = __expf(dtv * A0g);
                float p2 = p * p, p4 = p2 * p2;
                float dA = sh ? p4 * p4 * p : p;      // p^9 or p^1
                h[0] = dA * h[0] + du * b0.x;
                dA *= p; h[1] = dA * h[1] + du * b0.y;
                dA *= p; h[2] = dA * h[2] + du * b0.z;
                dA *= p; h[3] = dA * h[3] + du * b0.w;
                dA *= p; h[4] = dA * h[4] + du * b1.x;
                dA *= p; h[5] = dA * h[5] + du * b1.y;
                dA *= p; h[6] = dA * h[6] + du * b1.z;
                dA *= p; h[7] = dA * h[7] + du * b1.w;
            }
        } else {
            for (int i = 0; i < CLEN; i++) {
                u32 q = smDt[i * 64 + j2];
                float dtv = __half2float(__ushort_as_half((u16)(hi ? (q >> 16) : (q & 0xFFFFu))));
                float uv  = bfu2f(smU[i * PU + d]);
                float du  = dtv * uv;  sdt += dtv;
                const float* Bp = smBf + i * 16 + s0;
#pragma unroll
                for (int s = 0; s < 8; s++) h[s] = __expf(dtv * A[s]) * h[s] + du * Bp[s];
            }
        }

        const int c = blockIdx.x;
        float4* hp4 = (float4*)(hl_ws + (((long long)b * NCH + c) * 128 + d) * 16 + s0);
        hp4[0] = make_float4(h[0], h[1], h[2], h[3]);
        hp4[1] = make_float4(h[4], h[5], h[6], h[7]);
        if (sh == 0) sdt_ws[((long long)b * NCH + c) * 128 + d] = sdt;
    }
}

// ---------------- Chunk-boundary combine ----------------
__global__ __launch_bounds__(256) void k_combine(
    const float* __restrict__ A_log, const float* __restrict__ hl_ws,
    const float* __restrict__ sdt_ws, float* __restrict__ hin_ws)
{
    int gid = blockIdx.x * 256 + threadIdx.x;   // 0..32767
    int b = gid >> 11;
    int rem = gid & 2047;     // d*16+s
    int d = rem >> 4;
    float A = -__expf(A_log[rem]);
    float h = 0.f;
    for (int c = 0; c < NCH; c++) {
        long long o = ((long long)b * NCH + c) * 2048 + rem;
        hin_ws[o] = h;
        float sdt = sdt_ws[((long long)b * NCH + c) * 128 + d];
        h = __expf(A * sdt) * h + hl_ws[o];
    }
}

// ---------------- Backend: scan3 + epilogue fused ----------------
// LDS (50176 B -> 3 blocks/CU): sdtu [64][128] u32 @0 (dead after scan, smR overlays),
//                               sy [64][136] u16 @32768, smR [64][65] f32 @0
__global__ __launch_bounds__(256) void k_backend(
    const u32* __restrict__ dtu_g, const float* __restrict__ B_g,
    const float* __restrict__ C_g, const u16* __restrict__ sz_g,
    const float* __restrict__ A_log, const float* __restrict__ D_skip,
    const float* __restrict__ hin_ws, const float* __restrict__ xin_g,
    const u16* __restrict__ Wf4, const float* __restrict__ gamma,
    const float* __restrict__ beta, float* __restrict__ out)
{
    __shared__ __align__(16) char sm[50176];
    u32*   sdtu = (u32*)sm;              // [64][128]
    u16*   sy   = (u16*)(sm + 32768);    // [64][136]
    float* smR  = (float*)sm;            // [64][65], overlays sdtu after scan

    const int tid = threadIdx.x;
    const int c = blockIdx.x, b = blockIdx.y;
    const long long tok0 = (long long)b * L_SZ + (long long)c * CLEN;

    // stage dtu tile (32 KB), coalesced dwordx4
    {
        const uint4* src = (const uint4*)(dtu_g + tok0 * 128);
        uint4* dst = (uint4*)sdtu;
#pragma unroll
        for (int k = 0; k < 8; k++) dst[tid + k * 256] = src[tid + k * 256];
    }

    // ---- scan: 2 threads per channel, 8 states each ----
    {
        const int d = tid >> 1, sh = tid & 1, s0 = sh * 8;
        const float A0g = -__expf(A_log[d * 16]);
        float A[8];
#pragma unroll
        for (int s = 0; s < 8; s++) A[s] = -__expf(A_log[d * 16 + s0 + s]);
        bool chl = true;
#pragma unroll
        for (int s = 0; s < 8; s++)
            chl = chl && (fabsf(A[s] - (float)(s0 + s + 1) * A0g) <= 1e-4f * fabsf(A[s]));
        const bool chain = __all(chl);

        float h[8];
        {
            const float4* hp = (const float4*)(hin_ws + (((long long)b * NCH + c) * 128 + d) * 16 + s0);
            float4 h0 = hp[0], h1 = hp[1];
            h[0]=h0.x; h[1]=h0.y; h[2]=h0.z; h[3]=h0.w;
            h[4]=h1.x; h[5]=h1.y; h[6]=h1.z; h[7]=h1.w;
        }
        const float Dv = D_skip[d];
        __syncthreads();   // sdtu staged

        if (chain) {
            for (int i = 0; i < CLEN; i++) {
                const long long t = tok0 + i;
                u32 pk = sdtu[i * 128 + d];
                float dtv = h2f(pk);
                float uv  = bfhi(pk);
                float du  = dtv * uv;
                const float4* Bp = (const float4*)(B_g + t * 16 + s0);
                float4 b0 = Bp[0], b1 = Bp[1];
                const float4* Cp = (const float4*)(C_g + t * 16 + s0);
                float4 c0 = Cp[0], c1 = Cp[1];
                float p  = __expf(dtv * A0g);
                float p2 = p * p, p4 = p2 * p2;
                float dA = sh ? p4 * p4 * p : p;      // p^9 or p^1
                h[0] = dA * h[0] + du * b0.x; float ys = h[0] * c0.x;
                dA *= p; h[1] = dA * h[1] + du * b0.y; ys += h[1] * c0.y;
                dA *= p; h[2] = dA * h[2] + du * b0.z; ys += h[2] * c0.z;
                dA *= p; h[3] = dA * h[3] + du * b0.w; ys += h[3] * c0.w;
                dA *= p; h[4] = dA * h[4] + du * b1.x; ys += h[4] * c1.x;
                dA *= p; h[5] = dA * h[5] + du * b1.y; ys += h[5] * c1.y;
                dA *= p; h[6] = dA * h[6] + du * b1.z; ys += h[6] * c1.z;
                dA *= p; h[7] = dA * h[7] + du * b1.w; ys += h[7] * c1.w;
                ys += __shfl_xor(ys, 1, 64);
                float yv = (ys + uv * Dv) * bfu2f(sz_g[t * 128 + d]);
                float yo = __shfl_xor(yv, 2, 64);
                if ((tid & 3) == 0)
                    *(u32*)((char*)sy + i * 272 + d * 2) = pk2bf(yv, yo);
            }
        } else {
            for (int i = 0; i < CLEN; i++) {
                const long long t = tok0 + i;
                u32 pk = sdtu[i * 128 + d];
                float dtv = h2f(pk);
                float uv  = bfhi(pk);
                float du  = dtv * uv;
                const float4* Bp = (const float4*)(B_g + t * 16 + s0);
                float4 b0 = Bp[0], b1 = Bp[1];
                const float4* Cp = (const float4*)(C_g + t * 16 + s0);
                float4 c0 = Cp[0], c1 = Cp[1];
                float Bv[8] = { b0.x, b0.y, b0.z, b0.w, b1.x, b1.y, b1.z, b1.w };
                float Cv[8] = { c0.x, c0.y, c0.z, c0.w, c1.x, c1.y, c1.z, c1.w };
                float ys = 0.f;
#pragma unroll
                for (int s = 0; s < 8; s++) {
                    h[s] = __expf(dtv * A[s]) * h[s] + du * Bv[s];
                    ys += h[s] * Cv[s];
                }
                ys += __shfl_xor(ys, 1, 64);
                float yv = (ys + uv * Dv) * bfu2f(sz_g[t * 128 + d]);
                float yo = __shfl_xor(yv, 2, 64);
                if ((tid & 3) == 0)
                    *(u32*)((char*)sy + i * 272 + d * 2) = pk2bf(yv, yo);
            }
        }
    }
    __syncthreads();   // sy complete; sdtu dead

    // ---- epilogue: out = LN(y @ out_proj + xin) ----
    const int w = tid >> 6, lane = tid & 63;
    const int n16 = lane & 15, quad = lane >> 4;
    {
        s8 bf[4];
#pragma unroll
        for (int ks = 0; ks < 4; ks++)
            bf[ks] = *(const s8*)(Wf4 + ((w * 4 + ks) * 64 + lane) * 8);
#pragma unroll
        for (int m = 0; m < 4; m++) {
            int ar = m * 16 + n16;
            f4 acc = {0.f, 0.f, 0.f, 0.f};
#pragma unroll
            for (int ks = 0; ks < 4; ks++) {
                s8 a = *(const s8*)(sy + ar * PU + ks * 32 + quad * 8);
                acc = MFMA16(a, bf[ks], acc, 0, 0, 0);
            }
#pragma unroll
            for (int reg = 0; reg < 4; reg++) {
                int rr = m * 16 + quad * 4 + reg;
                smR[rr * 65 + w * 16 + n16] = acc[reg];
            }
        }
    }
    __syncthreads();

    {
        int o = tid & 63, wv = tid >> 6;
        float g = gamma[o], bb = beta[o];
        for (int j = 0; j < 16; j++) {
            int rr = wv * 16 + j;
            float r = smR[rr * 65 + o] + xin_g[(tok0 + rr) * 64 + o];
            float s = r;
#pragma unroll
            for (int mS = 0; mS < 6; mS++) s += __shfl_xor(s, 1 << mS, 64);
            float mu = s * (1.f / 64.f);
            float dv = r - mu;
            float vs = dv * dv;
#pragma unroll
            for (int mS = 0; mS < 6; mS++) vs += __shfl_xor(vs, 1 << mS, 64);
            out[(tok0 + rr) * 64 + o] = g * dv * rsqrtf(vs * (1.f / 64.f) + LN_EPS) + bb;
        }
    }
}

extern "C" void kernel_launch(void* const* d_in, const int* in_sizes, int n_in,
                              void* d_out, int out_size, void* d_ws, size_t ws_size,
                              hipStream_t stream)
{
    const float* x       = (const float*)d_in[0];
    const float* W_in    = (const float*)d_in[1];
    const float* b_in    = (const float*)d_in[2];
    const float* in_proj = (const float*)d_in[3];
    const float* conv_w  = (const float*)d_in[4];
    const float* conv_b  = (const float*)d_in[5];
    const float* x_proj  = (const float*)d_in[6];
    const float* dt_w    = (const float*)d_in[7];
    const float* dt_b    = (const float*)d_in[8];
    const float* A_log   = (const float*)d_in[9];
    const float* D_skip  = (const float*)d_in[10];
    const float* Wout    = (const float*)d_in[11];
    const float* gamma   = (const float*)d_in[12];
    const float* beta    = (const float*)d_in[13];
    float* out = (float*)d_out;

    const long long NT = (long long)B_SZ * L_SZ;  // 131072 tokens
    char* ws = (char*)d_ws;
    float*  xin_g = (float*)ws;   ws += NT * 64 * 4;
    u32*    dtu_g = (u32*)ws;     ws += NT * 128 * 4;   // (dt fp16 | u bf16)
    float*  B_g   = (float*)ws;   ws += NT * 16 * 4;
    float*  C_g   = (float*)ws;   ws += NT * 16 * 4;
    u16*    sz_g  = (u16*)ws;     ws += NT * 128 * 2;
    float*  hl_ws  = (float*)ws;  ws += (long long)B_SZ * NCH * 2048 * 4;
    float*  sdt_ws = (float*)ws;  ws += (long long)B_SZ * NCH * 128 * 4;
    float*  hin_ws = (float*)ws;  ws += (long long)B_SZ * NCH * 2048 * 4;
    u16* Wf1 = (u16*)ws; ws += 4096 * 2;
    u16* Wf2 = (u16*)ws; ws += 16384 * 2;
    u16* Wf3 = (u16*)ws; ws += 6144 * 2;
    u16* Wf4 = (u16*)ws; ws += 8192 * 2;

    k_prep<<<1, 256, 0, stream>>>(W_in, in_proj, x_proj, Wout, Wf1, Wf2, Wf3, Wf4);

    k_frontend<<<dim3(L_SZ / CH, B_SZ), 256, 0, stream>>>(
        x, b_in, conv_w, conv_b, dt_w, dt_b, Wf1, Wf2, Wf3, A_log,
        xin_g, dtu_g, B_g, C_g, sz_g, hl_ws, sdt_ws);

    k_combine<<<128, 256, 0, stream>>>(A_log, hl_ws, sdt_ws, hin_ws);

    k_backend<<<dim3(NCH, B_SZ), 256, 0, stream>>>(
        dtu_g, B_g, C_g, sz_g, A_log, D_skip, hin_ws, xin_g,
        Wf4, gamma, beta, out);
}

// Round 5
// 320.246 us; speedup vs baseline: 1.1455x; 1.0846x over previous
//
#include <hip/hip_runtime.h>
#include <hip/hip_bf16.h>
#include <hip/hip_fp16.h>

#define B_SZ   16
#define L_SZ   8192
#define DM     64
#define DI     128
#define NCH    256      // scan sub-chunks (32 tokens each)
#define CLEN   32       // L_SZ / NCH
#define CH     64       // frontend tokens per block (= 2 sub-chunks)
#define RT     80       // padded rows (5 mtiles of 16; 67 used)
#define PA     72       // LDS pitch (u16) for 64-wide acts: 144B
#define PU     136      // LDS pitch (u16) for 128-wide acts: 272B
#define PC     132      // LDS pitch (u16) for conv input: 264B
#define LN_EPS 1e-3f

typedef float  f4 __attribute__((ext_vector_type(4)));
typedef short  s8 __attribute__((ext_vector_type(8)));
typedef unsigned short u16;
typedef unsigned int   u32;
#define MFMA16 __builtin_amdgcn_mfma_f32_16x16x32_bf16

__device__ __forceinline__ u16 f2bfu(float f) {
    u32 u = __float_as_uint(f);
    return (u16)((u + 0x7FFFu + ((u >> 16) & 1u)) >> 16);
}
__device__ __forceinline__ u32 pk2bf(float a, float b) {
    return (u32)f2bfu(a) | ((u32)f2bfu(b) << 16);
}
__device__ __forceinline__ float bflo(u32 u) { return __uint_as_float(u << 16); }
__device__ __forceinline__ float bfhi(u32 u) { return __uint_as_float(u & 0xFFFF0000u); }
__device__ __forceinline__ float bfu2f(u16 h) { return __uint_as_float((u32)h << 16); }
__device__ __forceinline__ float h2f(u32 lo16) {
    return __half2float(__ushort_as_half((u16)(lo16 & 0xFFFFu)));
}
__device__ __forceinline__ float fsig(float v) {
    return __builtin_amdgcn_rcpf(1.f + __expf(-v));
}
__device__ __forceinline__ float fsp(float v) {   // softplus
    return fmaxf(v, 0.f) + __logf(1.f + __expf(-fabsf(v)));
}

// ---------------- Weight prep: fragment-linear bf16 granules ----------------
__global__ __launch_bounds__(256) void k_prep(
    const float* __restrict__ W_in, const float* __restrict__ in_proj,
    const float* __restrict__ x_proj, const float* __restrict__ Wout,
    u16* __restrict__ Wf1, u16* __restrict__ Wf2,
    u16* __restrict__ Wf3, u16* __restrict__ Wf4)
{
    const int tid = threadIdx.x;
    for (int g = tid; g < 512; g += 256) {          // W_in: 4 nt x 2 ks
        int lane = g & 63, ks = (g >> 6) & 1, nt = g >> 7;
        int n = nt * 16 + (lane & 15), kb = ks * 32 + (lane >> 4) * 8;
        for (int j = 0; j < 8; j++) Wf1[g * 8 + j] = f2bfu(W_in[(kb + j) * 64 + n]);
    }
    for (int g = tid; g < 2048; g += 256) {         // in_proj: 16 nt x 2 ks
        int lane = g & 63, ks = (g >> 6) & 1, nt = g >> 7;
        int n = nt * 16 + (lane & 15), kb = ks * 32 + (lane >> 4) * 8;
        for (int j = 0; j < 8; j++) Wf2[g * 8 + j] = f2bfu(in_proj[(kb + j) * 256 + n]);
    }
    for (int g = tid; g < 768; g += 256) {          // x_proj (pad N 36->48): 3 nt x 4 ks
        int lane = g & 63, ks = (g >> 6) & 3, nt = g >> 8;
        int n = nt * 16 + (lane & 15), kb = ks * 32 + (lane >> 4) * 8;
        for (int j = 0; j < 8; j++)
            Wf3[g * 8 + j] = f2bfu(n < 36 ? x_proj[(kb + j) * 36 + n] : 0.f);
    }
    for (int g = tid; g < 1024; g += 256) {         // out_proj: 4 nt x 4 ks
        int lane = g & 63, ks = (g >> 6) & 3, nt = g >> 8;
        int n = nt * 16 + (lane & 15), kb = ks * 32 + (lane >> 4) * 8;
        for (int j = 0; j < 8; j++) Wf4[g * 8 + j] = f2bfu(Wout[(kb + j) * 64 + n]);
    }
}

// ---------------- Frontend + fused sub-chunk scan (scan1) ----------------
// LDS map (bytes), total 40736 -> 4 blocks/CU:
//   0     .. 17408  smA/smB (x, xin)  -> smU [64][136] u16 after conv
//   17408 .. 18432  smDtr [64][4] f32
//   18432 .. 22528  smBf  [64][16] f32 (B for scan)
//   23040 .. 40728  smC   [67][132] u16 (conv input)
//   23040 .. 39424  smDt  [64][64] u32 (fp16 dt pairs) overlays dead smC
__global__ __launch_bounds__(256, 4) void k_frontend(
    const float* __restrict__ x, const float* __restrict__ b_in,
    const float* __restrict__ conv_w, const float* __restrict__ conv_b,
    const float* __restrict__ dt_w, const float* __restrict__ dt_b,
    const u16* __restrict__ Wf1, const u16* __restrict__ Wf2, const u16* __restrict__ Wf3,
    const float* __restrict__ A_log,
    float* __restrict__ xin_g, u32* __restrict__ dtu_g,
    float* __restrict__ B_g, float* __restrict__ C_g, u16* __restrict__ sz_g,
    float* __restrict__ hl_ws, float* __restrict__ sdt_ws)
{
    __shared__ __align__(16) char sm[40736];
    u16*   smA   = (u16*)sm;              // [80][72] x (bf16)
    u16*   smB   = (u16*)(sm + 11520);    // [80][72] xin
    u16*   smU   = (u16*)sm;              // [64][136] u (reuses smA/smB)
    float* smDtr = (float*)(sm + 17408);  // [64][4]
    float* smBf  = (float*)(sm + 18432);  // [64][16] B for scan
    u16*   smC   = (u16*)(sm + 23040);    // [67][132] xc
    u32*   smDt  = (u32*)(sm + 23040);    // [64][64] fp16 dt pairs, overlays dead smC

    const int tid = threadIdx.x;
    const int w = tid >> 6, lane = tid & 63;
    const int n16 = lane & 15, quad = lane >> 4;
    const int b = blockIdx.y, c0 = blockIdx.x * CH;
    const long long tokbase = (long long)b * L_SZ + c0;

    // P0: stage x rows (bf16), float4-vectorized
    for (int idx = tid; idx < RT * 16; idx += 256) {
        int r = idx >> 4, c4 = idx & 15;
        int l = c0 - 3 + r;
        float4 v = make_float4(0.f, 0.f, 0.f, 0.f);
        if (r < 67 && l >= 0)
            v = *(const float4*)(x + ((long long)b * L_SZ + l) * 64 + c4 * 4);
        *(uint2*)((char*)smA + r * 144 + c4 * 8) = make_uint2(pk2bf(v.x, v.y), pk2bf(v.z, v.w));
    }
    __syncthreads();

    // GEMM1: xin = x @ W_in + b_in
    {
        s8 b0 = *(const s8*)(Wf1 + ((w * 2 + 0) * 64 + lane) * 8);
        s8 b1 = *(const s8*)(Wf1 + ((w * 2 + 1) * 64 + lane) * 8);
        float bias = b_in[w * 16 + n16];
        for (int m = 0; m < 5; m++) {
            int ar = m * 16 + n16;
            s8 a0 = *(const s8*)(smA + ar * PA + quad * 8);
            s8 a1 = *(const s8*)(smA + ar * PA + 32 + quad * 8);
            f4 acc = {0.f, 0.f, 0.f, 0.f};
            acc = MFMA16(a0, b0, acc, 0, 0, 0);
            acc = MFMA16(a1, b1, acc, 0, 0, 0);
#pragma unroll
            for (int reg = 0; reg < 4; reg++) {
                int rr = m * 16 + quad * 4 + reg;
                float v = acc[reg] + bias;
                smB[rr * PA + w * 16 + n16] = f2bfu(v);
                if (rr >= 3 && rr < 67)
                    xin_g[(tokbase + rr - 3) * 64 + w * 16 + n16] = v;
            }
        }
    }
    __syncthreads();

    // GEMM2: xz = xin @ in_proj (waves 0-1 -> xc, waves 2-3 -> silu(z))
    {
        s8 bf[4][2];
#pragma unroll
        for (int i = 0; i < 4; i++)
#pragma unroll
            for (int ks = 0; ks < 2; ks++)
                bf[i][ks] = *(const s8*)(Wf2 + (((w * 4 + i) * 2 + ks) * 64 + lane) * 8);
        for (int m = 0; m < 5; m++) {
            int ar = m * 16 + n16;
            s8 a0 = *(const s8*)(smB + ar * PA + quad * 8);
            s8 a1 = *(const s8*)(smB + ar * PA + 32 + quad * 8);
#pragma unroll
            for (int i = 0; i < 4; i++) {
                f4 acc = {0.f, 0.f, 0.f, 0.f};
                acc = MFMA16(a0, bf[i][0], acc, 0, 0, 0);
                acc = MFMA16(a1, bf[i][1], acc, 0, 0, 0);
                int cg = (w * 4 + i) * 16 + n16;
#pragma unroll
                for (int reg = 0; reg < 4; reg++) {
                    int rr = m * 16 + quad * 4 + reg;
                    float v = acc[reg];
                    if (cg < 128) {                     // wave-uniform branch
                        if (rr < 67) {
                            int l = c0 - 3 + rr;
                            smC[rr * PC + cg] = f2bfu(l >= 0 ? v : 0.f);
                        }
                    } else if (rr >= 3 && rr < 67) {
                        sz_g[(tokbase + rr - 3) * 128 + (cg - 128)] = f2bfu(v * fsig(v));
                    }
                }
            }
        }
    }
    __syncthreads();

    // conv(4) + silu -> u (LDS only)
    {
        const int d2 = lane * 2, ctb = w * 16;
        float4 cw0 = ((const float4*)conv_w)[d2];
        float4 cw1 = ((const float4*)conv_w)[d2 + 1];
        float cb0 = conv_b[d2], cb1 = conv_b[d2 + 1];
        u32 r0 = *(const u32*)((char*)smC + (ctb + 0) * 264 + lane * 4);
        u32 r1 = *(const u32*)((char*)smC + (ctb + 1) * 264 + lane * 4);
        u32 r2 = *(const u32*)((char*)smC + (ctb + 2) * 264 + lane * 4);
#pragma unroll 4
        for (int j = 0; j < 16; j++) {
            int ct = ctb + j;
            u32 r3 = *(const u32*)((char*)smC + (ct + 3) * 264 + lane * 4);
            float v0 = cb0 + bflo(r0) * cw0.x + bflo(r1) * cw0.y + bflo(r2) * cw0.z + bflo(r3) * cw0.w;
            float v1 = cb1 + bfhi(r0) * cw1.x + bfhi(r1) * cw1.y + bfhi(r2) * cw1.z + bfhi(r3) * cw1.w;
            u32 pk = pk2bf(v0 * fsig(v0), v1 * fsig(v1));
            *(u32*)(smU + ct * PU + d2) = pk;
            r0 = r1; r1 = r2; r2 = r3;
        }
    }
    __syncthreads();

    // GEMM3: dbc = u @ x_proj  (M=64, N=48(36), K=128); wave w -> mtile w
    {
        s8 bf3[3][4];
#pragma unroll
        for (int nt = 0; nt < 3; nt++)
#pragma unroll
            for (int ks = 0; ks < 4; ks++)
                bf3[nt][ks] = *(const s8*)(Wf3 + ((nt * 4 + ks) * 64 + lane) * 8);
        f4 acc[3] = {{0.f,0.f,0.f,0.f},{0.f,0.f,0.f,0.f},{0.f,0.f,0.f,0.f}};
        int ar = w * 16 + n16;
#pragma unroll
        for (int ks = 0; ks < 4; ks++) {
            s8 a = *(const s8*)(smU + ar * PU + ks * 32 + quad * 8);
#pragma unroll
            for (int nt = 0; nt < 3; nt++) acc[nt] = MFMA16(a, bf3[nt][ks], acc[nt], 0, 0, 0);
        }
#pragma unroll
        for (int nt = 0; nt < 3; nt++) {
            int c = nt * 16 + n16;
#pragma unroll
            for (int reg = 0; reg < 4; reg++) {
                int rr = w * 16 + quad * 4 + reg;
                float v = acc[nt][reg];
                long long t = tokbase + rr;
                if (c < 4)       smDtr[rr * 4 + c] = v;
                else if (c < 20) { B_g[t * 16 + (c - 4)] = v; smBf[rr * 16 + (c - 4)] = v; }
                else if (c < 36) C_g[t * 16 + (c - 20)] = v;
            }
        }
    }
    __syncthreads();   // smC dead; smDt region now writable

    // dt = softplus(dtr @ dt_proj_w + dt_proj_b); fp16 pair -> smDt; packed (dt|u) -> global
    {
        const int o2 = lane * 2, grp = w;
        float w00 = dt_w[o2],       w01 = dt_w[o2 + 1];
        float w10 = dt_w[128 + o2], w11 = dt_w[128 + o2 + 1];
        float w20 = dt_w[256 + o2], w21 = dt_w[256 + o2 + 1];
        float w30 = dt_w[384 + o2], w31 = dt_w[384 + o2 + 1];
        float b0 = dt_b[o2], b1 = dt_b[o2 + 1];
#pragma unroll 4
        for (int j = 0; j < 16; j++) {
            int ct = grp * 16 + j;
            float4 q = *(const float4*)(smDtr + ct * 4);
            float v0 = b0 + q.x * w00 + q.y * w10 + q.z * w20 + q.w * w30;
            float v1 = b1 + q.x * w01 + q.y * w11 + q.z * w21 + q.w * w31;
            u32 hpk = (u32)__half_as_ushort(__float2half_rn(fsp(v0))) |
                      ((u32)__half_as_ushort(__float2half_rn(fsp(v1))) << 16);
            smDt[ct * 64 + lane] = hpk;
            u32 upk = *(const u32*)(smU + ct * PU + o2);
            u32 pk0 = (hpk & 0xFFFFu) | (upk << 16);
            u32 pk1 = (hpk >> 16) | (upk & 0xFFFF0000u);
            *(uint2*)(dtu_g + (tokbase + ct) * 128 + o2) = make_uint2(pk0, pk1);
        }
    }
    __syncthreads();

    // Fused sub-chunk scan: 1 thread per (sub-chunk, channel), 16 states, 32 tokens.
    // NO cross-lane ops, NO conditional stores in the loop.
    {
        const int d = tid & 127, cs = tid >> 7;
        const int j2 = d >> 1, hi = d & 1;
        float A[16];
#pragma unroll
        for (int s = 0; s < 16; s++) A[s] = -__expf(A_log[d * 16 + s]);
        const float A0 = A[0];
        bool chain = true;
#pragma unroll
        for (int s = 1; s < 16; s++)
            chain = chain && (fabsf(A[s] - (float)(s + 1) * A0) <= 1e-4f * fabsf(A[s]));

        float h[16];
#pragma unroll
        for (int s = 0; s < 16; s++) h[s] = 0.f;
        float sdt = 0.f;

        if (chain) {
            for (int i = 0; i < CLEN; i++) {
                int t = cs * CLEN + i;
                u32 q = smDt[t * 64 + j2];
                float dtv = __half2float(__ushort_as_half((u16)(hi ? (q >> 16) : (q & 0xFFFFu))));
                float uv  = bfu2f(smU[t * PU + d]);
                float du  = dtv * uv;  sdt += dtv;
                float4 b0 = *(const float4*)(smBf + t * 16);
                float4 b1 = *(const float4*)(smBf + t * 16 + 4);
                float4 b2 = *(const float4*)(smBf + t * 16 + 8);
                float4 b3 = *(const float4*)(smBf + t * 16 + 12);
                float p = __expf(dtv * A0), dA = p;
                h[0] = dA * h[0] + du * b0.x;
                dA *= p; h[1]  = dA * h[1]  + du * b0.y;
                dA *= p; h[2]  = dA * h[2]  + du * b0.z;
                dA *= p; h[3]  = dA * h[3]  + du * b0.w;
                dA *= p; h[4]  = dA * h[4]  + du * b1.x;
                dA *= p; h[5]  = dA * h[5]  + du * b1.y;
                dA *= p; h[6]  = dA * h[6]  + du * b1.z;
                dA *= p; h[7]  = dA * h[7]  + du * b1.w;
                dA *= p; h[8]  = dA * h[8]  + du * b2.x;
                dA *= p; h[9]  = dA * h[9]  + du * b2.y;
                dA *= p; h[10] = dA * h[10] + du * b2.z;
                dA *= p; h[11] = dA * h[11] + du * b2.w;
                dA *= p; h[12] = dA * h[12] + du * b3.x;
                dA *= p; h[13] = dA * h[13] + du * b3.y;
                dA *= p; h[14] = dA * h[14] + du * b3.z;
                dA *= p; h[15] = dA * h[15] + du * b3.w;
            }
        } else {
            for (int i = 0; i < CLEN; i++) {
                int t = cs * CLEN + i;
                u32 q = smDt[t * 64 + j2];
                float dtv = __half2float(__ushort_as_half((u16)(hi ? (q >> 16) : (q & 0xFFFFu))));
                float uv  = bfu2f(smU[t * PU + d]);
                float du  = dtv * uv;  sdt += dtv;
                const float* Bp = smBf + t * 16;
#pragma unroll
                for (int s = 0; s < 16; s++) h[s] = __expf(dtv * A[s]) * h[s] + du * Bp[s];
            }
        }

        const int ch = blockIdx.x * 2 + cs;
        float4* hp4 = (float4*)(hl_ws + (((long long)b * NCH + ch) * 128 + d) * 16);
        hp4[0] = make_float4(h[0], h[1], h[2], h[3]);
        hp4[1] = make_float4(h[4], h[5], h[6], h[7]);
        hp4[2] = make_float4(h[8], h[9], h[10], h[11]);
        hp4[3] = make_float4(h[12], h[13], h[14], h[15]);
        sdt_ws[((long long)b * NCH + ch) * 128 + d] = sdt;
    }
}

// ---------------- Chunk-boundary combine (in-place: hl -> hin) ----------------
__global__ __launch_bounds__(256) void k_combine(
    const float* __restrict__ A_log, float* __restrict__ hl_ws,
    const float* __restrict__ sdt_ws)
{
    int gid = blockIdx.x * 256 + threadIdx.x;   // 0..32767
    int b = gid >> 11;
    int rem = gid & 2047;     // d*16+s
    int d = rem >> 4;
    float A = -__expf(A_log[rem]);
    float h = 0.f;
    for (int c = 0; c < NCH; c++) {
        long long o = ((long long)b * NCH + c) * 2048 + rem;
        float v = hl_ws[o];
        float sdt = sdt_ws[((long long)b * NCH + c) * 128 + d];
        hl_ws[o] = h;                       // becomes hin
        h = __expf(A * sdt) * h + v;
    }
}

// ---------------- Backend: scan (2 sub-chunks, all 256 threads) + epilogue ----------------
// LDS (54272 B -> 3 blocks/CU): sdtu [64][128] u32 @0 (smR overlays after scan),
//                               sB [64][16] f32 @32768, sy [64][136] u16 @36864
__global__ __launch_bounds__(256) void k_backend(
    const u32* __restrict__ dtu_g, const float* __restrict__ B_g,
    const float* __restrict__ C_g, const u16* __restrict__ sz_g,
    const float* __restrict__ A_log, const float* __restrict__ D_skip,
    const float* __restrict__ hin_ws, const float* __restrict__ xin_g,
    const u16* __restrict__ Wf4, const float* __restrict__ gamma,
    const float* __restrict__ beta, float* __restrict__ out)
{
    __shared__ __align__(16) char sm[54272];
    u32*   sdtu = (u32*)sm;               // [64][128]
    float* sB   = (float*)(sm + 32768);   // [64][16]
    u16*   sy   = (u16*)(sm + 36864);     // [64][136]
    float* smR  = (float*)sm;             // [64][65], overlays sdtu after scan

    const int tid = threadIdx.x;
    const int cb = blockIdx.x, b = blockIdx.y;   // 64-token tile
    const long long tok0 = (long long)b * L_SZ + (long long)cb * 64;

    // stage dtu tile (32 KB) + B tile (4 KB), coalesced
    {
        const uint4* src = (const uint4*)(dtu_g + tok0 * 128);
        uint4* dst = (uint4*)sdtu;
#pragma unroll
        for (int k = 0; k < 8; k++) dst[tid + k * 256] = src[tid + k * 256];
        ((float4*)sB)[tid] = ((const float4*)(B_g + tok0 * 16))[tid];
    }

    // ---- scan: 1 thread per (half, channel), 16 states, 32 tokens, no cross-lane ----
    {
        const int d = tid & 127, half = tid >> 7;
        float A[16];
#pragma unroll
        for (int s = 0; s < 16; s++) A[s] = -__expf(A_log[d * 16 + s]);
        const float A0 = A[0];
        bool chain = true;
#pragma unroll
        for (int s = 1; s < 16; s++)
            chain = chain && (fabsf(A[s] - (float)(s + 1) * A0) <= 1e-4f * fabsf(A[s]));

        float h[16];
        {
            const float4* hp = (const float4*)(hin_ws +
                (((long long)b * NCH + 2 * cb + half) * 128 + d) * 16);
            float4 h0 = hp[0], h1 = hp[1], h2 = hp[2], h3 = hp[3];
            h[0]=h0.x; h[1]=h0.y; h[2]=h0.z; h[3]=h0.w;
            h[4]=h1.x; h[5]=h1.y; h[6]=h1.z; h[7]=h1.w;
            h[8]=h2.x; h[9]=h2.y; h[10]=h2.z; h[11]=h2.w;
            h[12]=h3.x; h[13]=h3.y; h[14]=h3.z; h[15]=h3.w;
        }
        const float Dv = D_skip[d];
        __syncthreads();   // staging complete

        if (chain) {
            for (int i = 0; i < CLEN; i++) {
                int t = half * CLEN + i;
                u32 pk = sdtu[t * 128 + d];
                float dtv = h2f(pk);
                float uv  = bfhi(pk);
                float du  = dtv * uv;
                float4 b0 = *(const float4*)(sB + t * 16);
                float4 b1 = *(const float4*)(sB + t * 16 + 4);
                float4 b2 = *(const float4*)(sB + t * 16 + 8);
                float4 b3 = *(const float4*)(sB + t * 16 + 12);
                const float4* Cp = (const float4*)(C_g + (tok0 + t) * 16);
                float4 c0 = Cp[0], c1 = Cp[1], c2 = Cp[2], c3 = Cp[3];
                float p = __expf(dtv * A0), dA = p;
                h[0] = dA * h[0] + du * b0.x; float ys = h[0] * c0.x;
                dA *= p; h[1]  = dA * h[1]  + du * b0.y; ys += h[1]  * c0.y;
                dA *= p; h[2]  = dA * h[2]  + du * b0.z; ys += h[2]  * c0.z;
                dA *= p; h[3]  = dA * h[3]  + du * b0.w; ys += h[3]  * c0.w;
                dA *= p; h[4]  = dA * h[4]  + du * b1.x; ys += h[4]  * c1.x;
                dA *= p; h[5]  = dA * h[5]  + du * b1.y; ys += h[5]  * c1.y;
                dA *= p; h[6]  = dA * h[6]  + du * b1.z; ys += h[6]  * c1.z;
                dA *= p; h[7]  = dA * h[7]  + du * b1.w; ys += h[7]  * c1.w;
                dA *= p; h[8]  = dA * h[8]  + du * b2.x; ys += h[8]  * c2.x;
                dA *= p; h[9]  = dA * h[9]  + du * b2.y; ys += h[9]  * c2.y;
                dA *= p; h[10] = dA * h[10] + du * b2.z; ys += h[10] * c2.z;
                dA *= p; h[11] = dA * h[11] + du * b2.w; ys += h[11] * c2.w;
                dA *= p; h[12] = dA * h[12] + du * b3.x; ys += h[12] * c3.x;
                dA *= p; h[13] = dA * h[13] + du * b3.y; ys += h[13] * c3.y;
                dA *= p; h[14] = dA * h[14] + du * b3.z; ys += h[14] * c3.z;
                dA *= p; h[15] = dA * h[15] + du * b3.w; ys += h[15] * c3.w;
                float szv = bfu2f(sz_g[(tok0 + t) * 128 + d]);
                sy[t * PU + d] = f2bfu((ys + uv * Dv) * szv);
            }
        } else {
            for (int i = 0; i < CLEN; i++) {
                int t = half * CLEN + i;
                u32 pk = sdtu[t * 128 + d];
                float dtv = h2f(pk);
                float uv  = bfhi(pk);
                float du  = dtv * uv;
                const float* Bp = sB + t * 16;
                const float4* Cp = (const float4*)(C_g + (tok0 + t) * 16);
                float4 c0 = Cp[0], c1 = Cp[1], c2 = Cp[2], c3 = Cp[3];
                float Cv[16] = { c0.x, c0.y, c0.z, c0.w, c1.x, c1.y, c1.z, c1.w,
                                 c2.x, c2.y, c2.z, c2.w, c3.x, c3.y, c3.z, c3.w };
                float ys = 0.f;
#pragma unroll
                for (int s = 0; s < 16; s++) {
                    h[s] = __expf(dtv * A[s]) * h[s] + du * Bp[s];
                    ys += h[s] * Cv[s];
                }
                float szv = bfu2f(sz_g[(tok0 + t) * 128 + d]);
                sy[t * PU + d] = f2bfu((ys + uv * Dv) * szv);
            }
        }
    }
    __syncthreads();   // sy complete; sdtu dead

    // ---- epilogue: out = LN(y @ out_proj + xin) ----
    const int w = tid >> 6, lane = tid & 63;
    const int n16 = lane & 15, quad = lane >> 4;
    {
        s8 bf[4];
#pragma unroll
        for (int ks = 0; ks < 4; ks++)
            bf[ks] = *(const s8*)(Wf4 + ((w * 4 + ks) * 64 + lane) * 8);
#pragma unroll
        for (int m = 0; m < 4; m++) {
            int ar = m * 16 + n16;
            f4 acc = {0.f, 0.f, 0.f, 0.f};
#pragma unroll
            for (int ks = 0; ks < 4; ks++) {
                s8 a = *(const s8*)(sy + ar * PU + ks * 32 + quad * 8);
                acc = MFMA16(a, bf[ks], acc, 0, 0, 0);
            }
#pragma unroll
            for (int reg = 0; reg < 4; reg++) {
                int rr = m * 16 + quad * 4 + reg;
                smR[rr * 65 + w * 16 + n16] = acc[reg];
            }
        }
    }
    __syncthreads();

    {
        int o = tid & 63, wv = tid >> 6;
        float g = gamma[o], bb = beta[o];
        for (int j = 0; j < 16; j++) {
            int rr = wv * 16 + j;
            float r = smR[rr * 65 + o] + xin_g[(tok0 + rr) * 64 + o];
            float s = r;
#pragma unroll
            for (int mS = 0; mS < 6; mS++) s += __shfl_xor(s, 1 << mS, 64);
            float mu = s * (1.f / 64.f);
            float dv = r - mu;
            float vs = dv * dv;
#pragma unroll
            for (int mS = 0; mS < 6; mS++) vs += __shfl_xor(vs, 1 << mS, 64);
            out[(tok0 + rr) * 64 + o] = g * dv * rsqrtf(vs * (1.f / 64.f) + LN_EPS) + bb;
        }
    }
}

extern "C" void kernel_launch(void* const* d_in, const int* in_sizes, int n_in,
                              void* d_out, int out_size, void* d_ws, size_t ws_size,
                              hipStream_t stream)
{
    const float* x       = (const float*)d_in[0];
    const float* W_in    = (const float*)d_in[1];
    const float* b_in    = (const float*)d_in[2];
    const float* in_proj = (const float*)d_in[3];
    const float* conv_w  = (const float*)d_in[4];
    const float* conv_b  = (const float*)d_in[5];
    const float* x_proj  = (const float*)d_in[6];
    const float* dt_w    = (const float*)d_in[7];
    const float* dt_b    = (const float*)d_in[8];
    const float* A_log   = (const float*)d_in[9];
    const float* D_skip  = (const float*)d_in[10];
    const float* Wout    = (const float*)d_in[11];
    const float* gamma   = (const float*)d_in[12];
    const float* beta    = (const float*)d_in[13];
    float* out = (float*)d_out;

    const long long NT = (long long)B_SZ * L_SZ;  // 131072 tokens
    char* ws = (char*)d_ws;
    float*  xin_g = (float*)ws;   ws += NT * 64 * 4;
    u32*    dtu_g = (u32*)ws;     ws += NT * 128 * 4;   // (dt fp16 | u bf16)
    float*  B_g   = (float*)ws;   ws += NT * 16 * 4;
    float*  C_g   = (float*)ws;   ws += NT * 16 * 4;
    u16*    sz_g  = (u16*)ws;     ws += NT * 128 * 2;
    float*  hl_ws  = (float*)ws;  ws += (long long)B_SZ * NCH * 2048 * 4;  // hl -> hin (in place)
    float*  sdt_ws = (float*)ws;  ws += (long long)B_SZ * NCH * 128 * 4;
    u16* Wf1 = (u16*)ws; ws += 4096 * 2;
    u16* Wf2 = (u16*)ws; ws += 16384 * 2;
    u16* Wf3 = (u16*)ws; ws += 6144 * 2;
    u16* Wf4 = (u16*)ws; ws += 8192 * 2;

    k_prep<<<1, 256, 0, stream>>>(W_in, in_proj, x_proj, Wout, Wf1, Wf2, Wf3, Wf4);

    k_frontend<<<dim3(L_SZ / CH, B_SZ), 256, 0, stream>>>(
        x, b_in, conv_w, conv_b, dt_w, dt_b, Wf1, Wf2, Wf3, A_log,
        xin_g, dtu_g, B_g, C_g, sz_g, hl_ws, sdt_ws);

    k_combine<<<128, 256, 0, stream>>>(A_log, hl_ws, sdt_ws);

    k_backend<<<dim3(L_SZ / 64, B_SZ), 256, 0, stream>>>(
        dtu_g, B_g, C_g, sz_g, A_log, D_skip, hl_ws, xin_g,
        Wf4, gamma, beta, out);
}

// Round 6
// 302.488 us; speedup vs baseline: 1.2128x; 1.0587x over previous
//
#include <hip/hip_runtime.h>
#include <hip/hip_bf16.h>
#include <hip/hip_fp16.h>

#define B_SZ   16
#define L_SZ   8192
#define DM     64
#define DI     128
#define NCH    256      // scan sub-chunks (32 tokens each)
#define CLEN   32       // L_SZ / NCH
#define CH     64       // frontend tokens per block (= 2 sub-chunks)
#define RT     80       // padded rows (5 mtiles of 16; 67 used)
#define PA     72       // LDS pitch (u16) for 64-wide acts: 144B
#define PU     136      // LDS pitch (u16) for 128-wide acts: 272B
#define PC     132      // LDS pitch (u16) for conv input: 264B
#define LN_EPS 1e-3f

typedef float  f4 __attribute__((ext_vector_type(4)));
typedef short  s8 __attribute__((ext_vector_type(8)));
typedef unsigned short u16;
typedef unsigned int   u32;
#define MFMA16 __builtin_amdgcn_mfma_f32_16x16x32_bf16

__device__ __forceinline__ u16 f2bfu(float f) {
    u32 u = __float_as_uint(f);
    return (u16)((u + 0x7FFFu + ((u >> 16) & 1u)) >> 16);
}
__device__ __forceinline__ u32 pk2bf(float a, float b) {
    return (u32)f2bfu(a) | ((u32)f2bfu(b) << 16);
}
__device__ __forceinline__ float bflo(u32 u) { return __uint_as_float(u << 16); }
__device__ __forceinline__ float bfhi(u32 u) { return __uint_as_float(u & 0xFFFF0000u); }
__device__ __forceinline__ float bfu2f(u16 h) { return __uint_as_float((u32)h << 16); }
__device__ __forceinline__ float h2f(u32 lo16) {
    return __half2float(__ushort_as_half((u16)(lo16 & 0xFFFFu)));
}
__device__ __forceinline__ float fsig(float v) {
    return __builtin_amdgcn_rcpf(1.f + __expf(-v));
}
__device__ __forceinline__ float fsp(float v) {   // softplus
    return fmaxf(v, 0.f) + __logf(1.f + __expf(-fabsf(v)));
}

// ---------------- Weight prep: fragment-linear bf16 granules ----------------
__global__ __launch_bounds__(256) void k_prep(
    const float* __restrict__ W_in, const float* __restrict__ in_proj,
    const float* __restrict__ x_proj, const float* __restrict__ Wout,
    u16* __restrict__ Wf1, u16* __restrict__ Wf2,
    u16* __restrict__ Wf3, u16* __restrict__ Wf4)
{
    const int tid = threadIdx.x;
    for (int g = tid; g < 512; g += 256) {          // W_in: 4 nt x 2 ks
        int lane = g & 63, ks = (g >> 6) & 1, nt = g >> 7;
        int n = nt * 16 + (lane & 15), kb = ks * 32 + (lane >> 4) * 8;
        for (int j = 0; j < 8; j++) Wf1[g * 8 + j] = f2bfu(W_in[(kb + j) * 64 + n]);
    }
    for (int g = tid; g < 2048; g += 256) {         // in_proj: 16 nt x 2 ks
        int lane = g & 63, ks = (g >> 6) & 1, nt = g >> 7;
        int n = nt * 16 + (lane & 15), kb = ks * 32 + (lane >> 4) * 8;
        for (int j = 0; j < 8; j++) Wf2[g * 8 + j] = f2bfu(in_proj[(kb + j) * 256 + n]);
    }
    for (int g = tid; g < 768; g += 256) {          // x_proj (pad N 36->48): 3 nt x 4 ks
        int lane = g & 63, ks = (g >> 6) & 3, nt = g >> 8;
        int n = nt * 16 + (lane & 15), kb = ks * 32 + (lane >> 4) * 8;
        for (int j = 0; j < 8; j++)
            Wf3[g * 8 + j] = f2bfu(n < 36 ? x_proj[(kb + j) * 36 + n] : 0.f);
    }
    for (int g = tid; g < 1024; g += 256) {         // out_proj: 4 nt x 4 ks
        int lane = g & 63, ks = (g >> 6) & 3, nt = g >> 8;
        int n = nt * 16 + (lane & 15), kb = ks * 32 + (lane >> 4) * 8;
        for (int j = 0; j < 8; j++) Wf4[g * 8 + j] = f2bfu(Wout[(kb + j) * 64 + n]);
    }
}

// ---------------- Frontend + fused sub-chunk scan (scan1) ----------------
// LDS map (bytes), total 40736 -> 4 blocks/CU:
//   0     .. 17408  smA/smB (x, xin)  -> smU [64][136] u16 after conv
//   17408 .. 18432  smDtr [64][4] f32
//   18432 .. 22528  smBf  [64][16] f32 (B for scan)
//   23040 .. 40728  smC   [67][132] u16 (conv input)
//   23040 .. 39424  smDt  [64][64] u32 (fp16 dt pairs) overlays dead smC
__global__ __launch_bounds__(256, 4) void k_frontend(
    const float* __restrict__ x, const float* __restrict__ b_in,
    const float* __restrict__ conv_w, const float* __restrict__ conv_b,
    const float* __restrict__ dt_w, const float* __restrict__ dt_b,
    const u16* __restrict__ Wf1, const u16* __restrict__ Wf2, const u16* __restrict__ Wf3,
    const float* __restrict__ A_log,
    float* __restrict__ xin_g, u32* __restrict__ dtu_g,
    float* __restrict__ B_g, float* __restrict__ C_g, u16* __restrict__ sz_g,
    float* __restrict__ hl_ws, float* __restrict__ sdt_ws)
{
    __shared__ __align__(16) char sm[40736];
    u16*   smA   = (u16*)sm;              // [80][72] x (bf16)
    u16*   smB   = (u16*)(sm + 11520);    // [80][72] xin
    u16*   smU   = (u16*)sm;              // [64][136] u (reuses smA/smB)
    float* smDtr = (float*)(sm + 17408);  // [64][4]
    float* smBf  = (float*)(sm + 18432);  // [64][16] B for scan
    u16*   smC   = (u16*)(sm + 23040);    // [67][132] xc
    u32*   smDt  = (u32*)(sm + 23040);    // [64][64] fp16 dt pairs, overlays dead smC

    const int tid = threadIdx.x;
    const int w = tid >> 6, lane = tid & 63;
    const int n16 = lane & 15, quad = lane >> 4;
    const int b = blockIdx.y, c0 = blockIdx.x * CH;
    const long long tokbase = (long long)b * L_SZ + c0;

    // P0: stage x rows (bf16), float4-vectorized
    for (int idx = tid; idx < RT * 16; idx += 256) {
        int r = idx >> 4, c4 = idx & 15;
        int l = c0 - 3 + r;
        float4 v = make_float4(0.f, 0.f, 0.f, 0.f);
        if (r < 67 && l >= 0)
            v = *(const float4*)(x + ((long long)b * L_SZ + l) * 64 + c4 * 4);
        *(uint2*)((char*)smA + r * 144 + c4 * 8) = make_uint2(pk2bf(v.x, v.y), pk2bf(v.z, v.w));
    }
    __syncthreads();

    // GEMM1: xin = x @ W_in + b_in
    {
        s8 b0 = *(const s8*)(Wf1 + ((w * 2 + 0) * 64 + lane) * 8);
        s8 b1 = *(const s8*)(Wf1 + ((w * 2 + 1) * 64 + lane) * 8);
        float bias = b_in[w * 16 + n16];
        for (int m = 0; m < 5; m++) {
            int ar = m * 16 + n16;
            s8 a0 = *(const s8*)(smA + ar * PA + quad * 8);
            s8 a1 = *(const s8*)(smA + ar * PA + 32 + quad * 8);
            f4 acc = {0.f, 0.f, 0.f, 0.f};
            acc = MFMA16(a0, b0, acc, 0, 0, 0);
            acc = MFMA16(a1, b1, acc, 0, 0, 0);
#pragma unroll
            for (int reg = 0; reg < 4; reg++) {
                int rr = m * 16 + quad * 4 + reg;
                float v = acc[reg] + bias;
                smB[rr * PA + w * 16 + n16] = f2bfu(v);
                if (rr >= 3 && rr < 67)
                    xin_g[(tokbase + rr - 3) * 64 + w * 16 + n16] = v;
            }
        }
    }
    __syncthreads();

    // GEMM2: xz = xin @ in_proj (waves 0-1 -> xc, waves 2-3 -> silu(z))
    {
        s8 bf[4][2];
#pragma unroll
        for (int i = 0; i < 4; i++)
#pragma unroll
            for (int ks = 0; ks < 2; ks++)
                bf[i][ks] = *(const s8*)(Wf2 + (((w * 4 + i) * 2 + ks) * 64 + lane) * 8);
        for (int m = 0; m < 5; m++) {
            int ar = m * 16 + n16;
            s8 a0 = *(const s8*)(smB + ar * PA + quad * 8);
            s8 a1 = *(const s8*)(smB + ar * PA + 32 + quad * 8);
#pragma unroll
            for (int i = 0; i < 4; i++) {
                f4 acc = {0.f, 0.f, 0.f, 0.f};
                acc = MFMA16(a0, bf[i][0], acc, 0, 0, 0);
                acc = MFMA16(a1, bf[i][1], acc, 0, 0, 0);
                int cg = (w * 4 + i) * 16 + n16;
#pragma unroll
                for (int reg = 0; reg < 4; reg++) {
                    int rr = m * 16 + quad * 4 + reg;
                    float v = acc[reg];
                    if (cg < 128) {                     // wave-uniform branch
                        if (rr < 67) {
                            int l = c0 - 3 + rr;
                            smC[rr * PC + cg] = f2bfu(l >= 0 ? v : 0.f);
                        }
                    } else if (rr >= 3 && rr < 67) {
                        sz_g[(tokbase + rr - 3) * 128 + (cg - 128)] = f2bfu(v * fsig(v));
                    }
                }
            }
        }
    }
    __syncthreads();

    // conv(4) + silu -> u (LDS only)
    {
        const int d2 = lane * 2, ctb = w * 16;
        float4 cw0 = ((const float4*)conv_w)[d2];
        float4 cw1 = ((const float4*)conv_w)[d2 + 1];
        float cb0 = conv_b[d2], cb1 = conv_b[d2 + 1];
        u32 r0 = *(const u32*)((char*)smC + (ctb + 0) * 264 + lane * 4);
        u32 r1 = *(const u32*)((char*)smC + (ctb + 1) * 264 + lane * 4);
        u32 r2 = *(const u32*)((char*)smC + (ctb + 2) * 264 + lane * 4);
#pragma unroll 4
        for (int j = 0; j < 16; j++) {
            int ct = ctb + j;
            u32 r3 = *(const u32*)((char*)smC + (ct + 3) * 264 + lane * 4);
            float v0 = cb0 + bflo(r0) * cw0.x + bflo(r1) * cw0.y + bflo(r2) * cw0.z + bflo(r3) * cw0.w;
            float v1 = cb1 + bfhi(r0) * cw1.x + bfhi(r1) * cw1.y + bfhi(r2) * cw1.z + bfhi(r3) * cw1.w;
            u32 pk = pk2bf(v0 * fsig(v0), v1 * fsig(v1));
            *(u32*)(smU + ct * PU + d2) = pk;
            r0 = r1; r1 = r2; r2 = r3;
        }
    }
    __syncthreads();

    // GEMM3: dbc = u @ x_proj  (M=64, N=48(36), K=128); wave w -> mtile w
    {
        s8 bf3[3][4];
#pragma unroll
        for (int nt = 0; nt < 3; nt++)
#pragma unroll
            for (int ks = 0; ks < 4; ks++)
                bf3[nt][ks] = *(const s8*)(Wf3 + ((nt * 4 + ks) * 64 + lane) * 8);
        f4 acc[3] = {{0.f,0.f,0.f,0.f},{0.f,0.f,0.f,0.f},{0.f,0.f,0.f,0.f}};
        int ar = w * 16 + n16;
#pragma unroll
        for (int ks = 0; ks < 4; ks++) {
            s8 a = *(const s8*)(smU + ar * PU + ks * 32 + quad * 8);
#pragma unroll
            for (int nt = 0; nt < 3; nt++) acc[nt] = MFMA16(a, bf3[nt][ks], acc[nt], 0, 0, 0);
        }
#pragma unroll
        for (int nt = 0; nt < 3; nt++) {
            int c = nt * 16 + n16;
#pragma unroll
            for (int reg = 0; reg < 4; reg++) {
                int rr = w * 16 + quad * 4 + reg;
                float v = acc[nt][reg];
                long long t = tokbase + rr;
                if (c < 4)       smDtr[rr * 4 + c] = v;
                else if (c < 20) { B_g[t * 16 + (c - 4)] = v; smBf[rr * 16 + (c - 4)] = v; }
                else if (c < 36) C_g[t * 16 + (c - 20)] = v;
            }
        }
    }
    __syncthreads();   // smC dead; smDt region now writable

    // dt = softplus(dtr @ dt_proj_w + dt_proj_b); fp16 pair -> smDt; packed (dt|u) -> global
    {
        const int o2 = lane * 2, grp = w;
        float w00 = dt_w[o2],       w01 = dt_w[o2 + 1];
        float w10 = dt_w[128 + o2], w11 = dt_w[128 + o2 + 1];
        float w20 = dt_w[256 + o2], w21 = dt_w[256 + o2 + 1];
        float w30 = dt_w[384 + o2], w31 = dt_w[384 + o2 + 1];
        float b0 = dt_b[o2], b1 = dt_b[o2 + 1];
#pragma unroll 4
        for (int j = 0; j < 16; j++) {
            int ct = grp * 16 + j;
            float4 q = *(const float4*)(smDtr + ct * 4);
            float v0 = b0 + q.x * w00 + q.y * w10 + q.z * w20 + q.w * w30;
            float v1 = b1 + q.x * w01 + q.y * w11 + q.z * w21 + q.w * w31;
            u32 hpk = (u32)__half_as_ushort(__float2half_rn(fsp(v0))) |
                      ((u32)__half_as_ushort(__float2half_rn(fsp(v1))) << 16);
            smDt[ct * 64 + lane] = hpk;
            u32 upk = *(const u32*)(smU + ct * PU + o2);
            u32 pk0 = (hpk & 0xFFFFu) | (upk << 16);
            u32 pk1 = (hpk >> 16) | (upk & 0xFFFF0000u);
            *(uint2*)(dtu_g + (tokbase + ct) * 128 + o2) = make_uint2(pk0, pk1);
        }
    }
    __syncthreads();

    // Fused sub-chunk scan: 1 thread per (sub-chunk, channel), 16 states, 32 tokens.
    // NO cross-lane ops, NO conditional stores in the loop.
    {
        const int d = tid & 127, cs = tid >> 7;
        const int j2 = d >> 1, hi = d & 1;
        float A[16];
#pragma unroll
        for (int s = 0; s < 16; s++) A[s] = -__expf(A_log[d * 16 + s]);
        const float A0 = A[0];
        bool chain = true;
#pragma unroll
        for (int s = 1; s < 16; s++)
            chain = chain && (fabsf(A[s] - (float)(s + 1) * A0) <= 1e-4f * fabsf(A[s]));

        float h[16];
#pragma unroll
        for (int s = 0; s < 16; s++) h[s] = 0.f;
        float sdt = 0.f;

        if (chain) {
            for (int i = 0; i < CLEN; i++) {
                int t = cs * CLEN + i;
                u32 q = smDt[t * 64 + j2];
                float dtv = __half2float(__ushort_as_half((u16)(hi ? (q >> 16) : (q & 0xFFFFu))));
                float uv  = bfu2f(smU[t * PU + d]);
                float du  = dtv * uv;  sdt += dtv;
                float4 b0 = *(const float4*)(smBf + t * 16);
                float4 b1 = *(const float4*)(smBf + t * 16 + 4);
                float4 b2 = *(const float4*)(smBf + t * 16 + 8);
                float4 b3 = *(const float4*)(smBf + t * 16 + 12);
                float p = __expf(dtv * A0), dA = p;
                h[0] = dA * h[0] + du * b0.x;
                dA *= p; h[1]  = dA * h[1]  + du * b0.y;
                dA *= p; h[2]  = dA * h[2]  + du * b0.z;
                dA *= p; h[3]  = dA * h[3]  + du * b0.w;
                dA *= p; h[4]  = dA * h[4]  + du * b1.x;
                dA *= p; h[5]  = dA * h[5]  + du * b1.y;
                dA *= p; h[6]  = dA * h[6]  + du * b1.z;
                dA *= p; h[7]  = dA * h[7]  + du * b1.w;
                dA *= p; h[8]  = dA * h[8]  + du * b2.x;
                dA *= p; h[9]  = dA * h[9]  + du * b2.y;
                dA *= p; h[10] = dA * h[10] + du * b2.z;
                dA *= p; h[11] = dA * h[11] + du * b2.w;
                dA *= p; h[12] = dA * h[12] + du * b3.x;
                dA *= p; h[13] = dA * h[13] + du * b3.y;
                dA *= p; h[14] = dA * h[14] + du * b3.z;
                dA *= p; h[15] = dA * h[15] + du * b3.w;
            }
        } else {
            for (int i = 0; i < CLEN; i++) {
                int t = cs * CLEN + i;
                u32 q = smDt[t * 64 + j2];
                float dtv = __half2float(__ushort_as_half((u16)(hi ? (q >> 16) : (q & 0xFFFFu))));
                float uv  = bfu2f(smU[t * PU + d]);
                float du  = dtv * uv;  sdt += dtv;
                const float* Bp = smBf + t * 16;
#pragma unroll
                for (int s = 0; s < 16; s++) h[s] = __expf(dtv * A[s]) * h[s] + du * Bp[s];
            }
        }

        const int ch = blockIdx.x * 2 + cs;
        float4* hp4 = (float4*)(hl_ws + (((long long)b * NCH + ch) * 128 + d) * 16);
        hp4[0] = make_float4(h[0], h[1], h[2], h[3]);
        hp4[1] = make_float4(h[4], h[5], h[6], h[7]);
        hp4[2] = make_float4(h[8], h[9], h[10], h[11]);
        hp4[3] = make_float4(h[12], h[13], h[14], h[15]);
        sdt_ws[((long long)b * NCH + ch) * 128 + d] = sdt;
    }
}

// ---------------- Chunk-boundary combine (in-place: hl -> hin), all-CU spread ----------------
__global__ __launch_bounds__(128) void k_combine(
    const float* __restrict__ A_log, float* __restrict__ hl_ws,
    const float* __restrict__ sdt_ws)
{
    int gid = blockIdx.x * 128 + threadIdx.x;   // 0..32767
    int b = gid >> 11;
    int rem = gid & 2047;     // d*16+s
    int d = rem >> 4;
    float A = -__expf(A_log[rem]);
    float h = 0.f;
    for (int c = 0; c < NCH; c++) {
        long long o = ((long long)b * NCH + c) * 2048 + rem;
        float v = hl_ws[o];
        float sdt = sdt_ws[((long long)b * NCH + c) * 128 + d];
        hl_ws[o] = h;                       // becomes hin
        h = __expf(A * sdt) * h + v;
    }
}

// ---------------- Backend: scan (direct loads, no staging) + epilogue ----------------
// LDS (34048 B -> 4 blocks/CU): sy [64][136] u16 @0, smR [64][65] f32 @17408
__global__ __launch_bounds__(256, 4) void k_backend(
    const u32* __restrict__ dtu_g, const float* __restrict__ B_g,
    const float* __restrict__ C_g, const u16* __restrict__ sz_g,
    const float* __restrict__ A_log, const float* __restrict__ D_skip,
    const float* __restrict__ hin_ws, const float* __restrict__ xin_g,
    const u16* __restrict__ Wf4, const float* __restrict__ gamma,
    const float* __restrict__ beta, float* __restrict__ out)
{
    __shared__ __align__(16) char sm[34048];
    u16*   sy   = (u16*)sm;               // [64][136]
    float* smR  = (float*)(sm + 17408);   // [64][65]

    const int tid = threadIdx.x;
    const int cb = blockIdx.x, b = blockIdx.y;   // 64-token tile
    const long long tok0 = (long long)b * L_SZ + (long long)cb * 64;

    // ---- scan: 1 thread per (half, channel), 16 states, 32 tokens, direct loads ----
    {
        const int d = tid & 127, half = tid >> 7;
        float A[16];
#pragma unroll
        for (int s = 0; s < 16; s++) A[s] = -__expf(A_log[d * 16 + s]);
        const float A0 = A[0];
        bool chain = true;
#pragma unroll
        for (int s = 1; s < 16; s++)
            chain = chain && (fabsf(A[s] - (float)(s + 1) * A0) <= 1e-4f * fabsf(A[s]));

        float h[16];
        {
            const float4* hp = (const float4*)(hin_ws +
                (((long long)b * NCH + 2 * cb + half) * 128 + d) * 16);
            float4 h0 = hp[0], h1 = hp[1], h2 = hp[2], h3 = hp[3];
            h[0]=h0.x; h[1]=h0.y; h[2]=h0.z; h[3]=h0.w;
            h[4]=h1.x; h[5]=h1.y; h[6]=h1.z; h[7]=h1.w;
            h[8]=h2.x; h[9]=h2.y; h[10]=h2.z; h[11]=h2.w;
            h[12]=h3.x; h[13]=h3.y; h[14]=h3.z; h[15]=h3.w;
        }
        const float Dv = D_skip[d];

        if (chain) {
            for (int i = 0; i < CLEN; i++) {
                int t = half * CLEN + i;
                u32 pk = dtu_g[(tok0 + t) * 128 + d];
                float dtv = h2f(pk);
                float uv  = bfhi(pk);
                float du  = dtv * uv;
                const float4* Bp = (const float4*)(B_g + (tok0 + t) * 16);
                float4 b0 = Bp[0], b1 = Bp[1], b2 = Bp[2], b3 = Bp[3];
                const float4* Cp = (const float4*)(C_g + (tok0 + t) * 16);
                float4 c0 = Cp[0], c1 = Cp[1], c2 = Cp[2], c3 = Cp[3];
                float p = __expf(dtv * A0), dA = p;
                h[0] = dA * h[0] + du * b0.x; float ys = h[0] * c0.x;
                dA *= p; h[1]  = dA * h[1]  + du * b0.y; ys += h[1]  * c0.y;
                dA *= p; h[2]  = dA * h[2]  + du * b0.z; ys += h[2]  * c0.z;
                dA *= p; h[3]  = dA * h[3]  + du * b0.w; ys += h[3]  * c0.w;
                dA *= p; h[4]  = dA * h[4]  + du * b1.x; ys += h[4]  * c1.x;
                dA *= p; h[5]  = dA * h[5]  + du * b1.y; ys += h[5]  * c1.y;
                dA *= p; h[6]  = dA * h[6]  + du * b1.z; ys += h[6]  * c1.z;
                dA *= p; h[7]  = dA * h[7]  + du * b1.w; ys += h[7]  * c1.w;
                dA *= p; h[8]  = dA * h[8]  + du * b2.x; ys += h[8]  * c2.x;
                dA *= p; h[9]  = dA * h[9]  + du * b2.y; ys += h[9]  * c2.y;
                dA *= p; h[10] = dA * h[10] + du * b2.z; ys += h[10] * c2.z;
                dA *= p; h[11] = dA * h[11] + du * b2.w; ys += h[11] * c2.w;
                dA *= p; h[12] = dA * h[12] + du * b3.x; ys += h[12] * c3.x;
                dA *= p; h[13] = dA * h[13] + du * b3.y; ys += h[13] * c3.y;
                dA *= p; h[14] = dA * h[14] + du * b3.z; ys += h[14] * c3.z;
                dA *= p; h[15] = dA * h[15] + du * b3.w; ys += h[15] * c3.w;
                float szv = bfu2f(sz_g[(tok0 + t) * 128 + d]);
                sy[t * PU + d] = f2bfu((ys + uv * Dv) * szv);
            }
        } else {
            for (int i = 0; i < CLEN; i++) {
                int t = half * CLEN + i;
                u32 pk = dtu_g[(tok0 + t) * 128 + d];
                float dtv = h2f(pk);
                float uv  = bfhi(pk);
                float du  = dtv * uv;
                const float4* Bp = (const float4*)(B_g + (tok0 + t) * 16);
                float4 b0 = Bp[0], b1 = Bp[1], b2 = Bp[2], b3 = Bp[3];
                float Bv[16] = { b0.x, b0.y, b0.z, b0.w, b1.x, b1.y, b1.z, b1.w,
                                 b2.x, b2.y, b2.z, b2.w, b3.x, b3.y, b3.z, b3.w };
                const float4* Cp = (const float4*)(C_g + (tok0 + t) * 16);
                float4 c0 = Cp[0], c1 = Cp[1], c2 = Cp[2], c3 = Cp[3];
                float Cv[16] = { c0.x, c0.y, c0.z, c0.w, c1.x, c1.y, c1.z, c1.w,
                                 c2.x, c2.y, c2.z, c2.w, c3.x, c3.y, c3.z, c3.w };
                float ys = 0.f;
#pragma unroll
                for (int s = 0; s < 16; s++) {
                    h[s] = __expf(dtv * A[s]) * h[s] + du * Bv[s];
                    ys += h[s] * Cv[s];
                }
                float szv = bfu2f(sz_g[(tok0 + t) * 128 + d]);
                sy[t * PU + d] = f2bfu((ys + uv * Dv) * szv);
            }
        }
    }
    __syncthreads();   // sy complete

    // ---- epilogue: out = LN(y @ out_proj + xin) ----
    const int w = tid >> 6, lane = tid & 63;
    const int n16 = lane & 15, quad = lane >> 4;
    {
        s8 bf[4];
#pragma unroll
        for (int ks = 0; ks < 4; ks++)
            bf[ks] = *(const s8*)(Wf4 + ((w * 4 + ks) * 64 + lane) * 8);
#pragma unroll
        for (int m = 0; m < 4; m++) {
            int ar = m * 16 + n16;
            f4 acc = {0.f, 0.f, 0.f, 0.f};
#pragma unroll
            for (int ks = 0; ks < 4; ks++) {
                s8 a = *(const s8*)(sy + ar * PU + ks * 32 + quad * 8);
                acc = MFMA16(a, bf[ks], acc, 0, 0, 0);
            }
#pragma unroll
            for (int reg = 0; reg < 4; reg++) {
                int rr = m * 16 + quad * 4 + reg;
                smR[rr * 65 + w * 16 + n16] = acc[reg];
            }
        }
    }
    __syncthreads();

    {
        int o = tid & 63, wv = tid >> 6;
        float g = gamma[o], bb = beta[o];
        for (int j = 0; j < 16; j++) {
            int rr = wv * 16 + j;
            float r = smR[rr * 65 + o] + xin_g[(tok0 + rr) * 64 + o];
            float s = r;
#pragma unroll
            for (int mS = 0; mS < 6; mS++) s += __shfl_xor(s, 1 << mS, 64);
            float mu = s * (1.f / 64.f);
            float dv = r - mu;
            float vs = dv * dv;
#pragma unroll
            for (int mS = 0; mS < 6; mS++) vs += __shfl_xor(vs, 1 << mS, 64);
            out[(tok0 + rr) * 64 + o] = g * dv * rsqrtf(vs * (1.f / 64.f) + LN_EPS) + bb;
        }
    }
}

extern "C" void kernel_launch(void* const* d_in, const int* in_sizes, int n_in,
                              void* d_out, int out_size, void* d_ws, size_t ws_size,
                              hipStream_t stream)
{
    const float* x       = (const float*)d_in[0];
    const float* W_in    = (const float*)d_in[1];
    const float* b_in    = (const float*)d_in[2];
    const float* in_proj = (const float*)d_in[3];
    const float* conv_w  = (const float*)d_in[4];
    const float* conv_b  = (const float*)d_in[5];
    const float* x_proj  = (const float*)d_in[6];
    const float* dt_w    = (const float*)d_in[7];
    const float* dt_b    = (const float*)d_in[8];
    const float* A_log   = (const float*)d_in[9];
    const float* D_skip  = (const float*)d_in[10];
    const float* Wout    = (const float*)d_in[11];
    const float* gamma   = (const float*)d_in[12];
    const float* beta    = (const float*)d_in[13];
    float* out = (float*)d_out;

    const long long NT = (long long)B_SZ * L_SZ;  // 131072 tokens
    char* ws = (char*)d_ws;
    float*  xin_g = (float*)ws;   ws += NT * 64 * 4;
    u32*    dtu_g = (u32*)ws;     ws += NT * 128 * 4;   // (dt fp16 | u bf16)
    float*  B_g   = (float*)ws;   ws += NT * 16 * 4;
    float*  C_g   = (float*)ws;   ws += NT * 16 * 4;
    u16*    sz_g  = (u16*)ws;     ws += NT * 128 * 2;
    float*  hl_ws  = (float*)ws;  ws += (long long)B_SZ * NCH * 2048 * 4;  // hl -> hin (in place)
    float*  sdt_ws = (float*)ws;  ws += (long long)B_SZ * NCH * 128 * 4;
    u16* Wf1 = (u16*)ws; ws += 4096 * 2;
    u16* Wf2 = (u16*)ws; ws += 16384 * 2;
    u16* Wf3 = (u16*)ws; ws += 6144 * 2;
    u16* Wf4 = (u16*)ws; ws += 8192 * 2;

    k_prep<<<1, 256, 0, stream>>>(W_in, in_proj, x_proj, Wout, Wf1, Wf2, Wf3, Wf4);

    k_frontend<<<dim3(L_SZ / CH, B_SZ), 256, 0, stream>>>(
        x, b_in, conv_w, conv_b, dt_w, dt_b, Wf1, Wf2, Wf3, A_log,
        xin_g, dtu_g, B_g, C_g, sz_g, hl_ws, sdt_ws);

    k_combine<<<256, 128, 0, stream>>>(A_log, hl_ws, sdt_ws);

    k_backend<<<dim3(L_SZ / 64, B_SZ), 256, 0, stream>>>(
        dtu_g, B_g, C_g, sz_g, A_log, D_skip, hl_ws, xin_g,
        Wf4, gamma, beta, out);
}

// Round 7
// 295.983 us; speedup vs baseline: 1.2394x; 1.0220x over previous
//
#include <hip/hip_runtime.h>
#include <hip/hip_bf16.h>
#include <hip/hip_fp16.h>

#define B_SZ   16
#define L_SZ   8192
#define DM     64
#define DI     128
#define NCH    256      // scan sub-chunks (32 tokens each)
#define CLEN   32       // L_SZ / NCH
#define CH     64       // frontend tokens per block (= 2 sub-chunks)
#define RT     80       // padded rows (5 mtiles of 16; 67 used)
#define PA     72       // LDS pitch (u16) for 64-wide acts: 144B
#define PU     136      // LDS pitch (u16) for 128-wide acts: 272B
#define PC     132      // LDS pitch (u16) for conv input: 264B
#define LN_EPS 1e-3f

typedef float  f4 __attribute__((ext_vector_type(4)));
typedef short  s8 __attribute__((ext_vector_type(8)));
typedef unsigned short u16;
typedef unsigned int   u32;
#define MFMA16 __builtin_amdgcn_mfma_f32_16x16x32_bf16

__device__ __forceinline__ u16 f2bfu(float f) {
    u32 u = __float_as_uint(f);
    return (u16)((u + 0x7FFFu + ((u >> 16) & 1u)) >> 16);
}
__device__ __forceinline__ u32 pk2bf(float a, float b) {
    return (u32)f2bfu(a) | ((u32)f2bfu(b) << 16);
}
__device__ __forceinline__ float bflo(u32 u) { return __uint_as_float(u << 16); }
__device__ __forceinline__ float bfhi(u32 u) { return __uint_as_float(u & 0xFFFF0000u); }
__device__ __forceinline__ float bfu2f(u16 h) { return __uint_as_float((u32)h << 16); }
__device__ __forceinline__ float h2f(u32 lo16) {
    return __half2float(__ushort_as_half((u16)(lo16 & 0xFFFFu)));
}
__device__ __forceinline__ float fsig(float v) {
    return __builtin_amdgcn_rcpf(1.f + __expf(-v));
}
__device__ __forceinline__ float fsp(float v) {   // softplus
    return fmaxf(v, 0.f) + __logf(1.f + __expf(-fabsf(v)));
}

// ---------------- Weight prep: fragment-linear bf16 granules ----------------
__global__ __launch_bounds__(256) void k_prep(
    const float* __restrict__ W_in, const float* __restrict__ in_proj,
    const float* __restrict__ x_proj, const float* __restrict__ Wout,
    u16* __restrict__ Wf1, u16* __restrict__ Wf2,
    u16* __restrict__ Wf3, u16* __restrict__ Wf4)
{
    const int tid = threadIdx.x;
    for (int g = tid; g < 512; g += 256) {          // W_in: 4 nt x 2 ks
        int lane = g & 63, ks = (g >> 6) & 1, nt = g >> 7;
        int n = nt * 16 + (lane & 15), kb = ks * 32 + (lane >> 4) * 8;
        for (int j = 0; j < 8; j++) Wf1[g * 8 + j] = f2bfu(W_in[(kb + j) * 64 + n]);
    }
    for (int g = tid; g < 2048; g += 256) {         // in_proj: 16 nt x 2 ks
        int lane = g & 63, ks = (g >> 6) & 1, nt = g >> 7;
        int n = nt * 16 + (lane & 15), kb = ks * 32 + (lane >> 4) * 8;
        for (int j = 0; j < 8; j++) Wf2[g * 8 + j] = f2bfu(in_proj[(kb + j) * 256 + n]);
    }
    for (int g = tid; g < 768; g += 256) {          // x_proj (pad N 36->48): 3 nt x 4 ks
        int lane = g & 63, ks = (g >> 6) & 3, nt = g >> 8;
        int n = nt * 16 + (lane & 15), kb = ks * 32 + (lane >> 4) * 8;
        for (int j = 0; j < 8; j++)
            Wf3[g * 8 + j] = f2bfu(n < 36 ? x_proj[(kb + j) * 36 + n] : 0.f);
    }
    for (int g = tid; g < 1024; g += 256) {         // out_proj: 4 nt x 4 ks
        int lane = g & 63, ks = (g >> 6) & 3, nt = g >> 8;
        int n = nt * 16 + (lane & 15), kb = ks * 32 + (lane >> 4) * 8;
        for (int j = 0; j < 8; j++) Wf4[g * 8 + j] = f2bfu(Wout[(kb + j) * 64 + n]);
    }
}

// ---------------- Frontend + fused sub-chunk scan (scan1) ----------------
__global__ __launch_bounds__(256, 4) void k_frontend(
    const float* __restrict__ x, const float* __restrict__ b_in,
    const float* __restrict__ conv_w, const float* __restrict__ conv_b,
    const float* __restrict__ dt_w, const float* __restrict__ dt_b,
    const u16* __restrict__ Wf1, const u16* __restrict__ Wf2, const u16* __restrict__ Wf3,
    const float* __restrict__ A_log,
    float* __restrict__ xin_g, u32* __restrict__ dtu_g,
    float* __restrict__ B_g, float* __restrict__ C_g, u16* __restrict__ sz_g,
    float* __restrict__ hl_ws, float* __restrict__ sdt_ws)
{
    __shared__ __align__(16) char sm[40736];
    u16*   smA   = (u16*)sm;              // [80][72] x (bf16)
    u16*   smB   = (u16*)(sm + 11520);    // [80][72] xin
    u16*   smU   = (u16*)sm;              // [64][136] u (reuses smA/smB)
    float* smDtr = (float*)(sm + 17408);  // [64][4]
    float* smBf  = (float*)(sm + 18432);  // [64][16] B for scan
    u16*   smC   = (u16*)(sm + 23040);    // [67][132] xc
    u32*   smDt  = (u32*)(sm + 23040);    // [64][64] fp16 dt pairs, overlays dead smC

    const int tid = threadIdx.x;
    const int w = tid >> 6, lane = tid & 63;
    const int n16 = lane & 15, quad = lane >> 4;
    const int b = blockIdx.y, c0 = blockIdx.x * CH;
    const long long tokbase = (long long)b * L_SZ + c0;

    // P0: stage x rows (bf16), float4-vectorized
    for (int idx = tid; idx < RT * 16; idx += 256) {
        int r = idx >> 4, c4 = idx & 15;
        int l = c0 - 3 + r;
        float4 v = make_float4(0.f, 0.f, 0.f, 0.f);
        if (r < 67 && l >= 0)
            v = *(const float4*)(x + ((long long)b * L_SZ + l) * 64 + c4 * 4);
        *(uint2*)((char*)smA + r * 144 + c4 * 8) = make_uint2(pk2bf(v.x, v.y), pk2bf(v.z, v.w));
    }
    __syncthreads();

    // GEMM1: xin = x @ W_in + b_in
    {
        s8 b0 = *(const s8*)(Wf1 + ((w * 2 + 0) * 64 + lane) * 8);
        s8 b1 = *(const s8*)(Wf1 + ((w * 2 + 1) * 64 + lane) * 8);
        float bias = b_in[w * 16 + n16];
        for (int m = 0; m < 5; m++) {
            int ar = m * 16 + n16;
            s8 a0 = *(const s8*)(smA + ar * PA + quad * 8);
            s8 a1 = *(const s8*)(smA + ar * PA + 32 + quad * 8);
            f4 acc = {0.f, 0.f, 0.f, 0.f};
            acc = MFMA16(a0, b0, acc, 0, 0, 0);
            acc = MFMA16(a1, b1, acc, 0, 0, 0);
#pragma unroll
            for (int reg = 0; reg < 4; reg++) {
                int rr = m * 16 + quad * 4 + reg;
                float v = acc[reg] + bias;
                smB[rr * PA + w * 16 + n16] = f2bfu(v);
                if (rr >= 3 && rr < 67)
                    xin_g[(tokbase + rr - 3) * 64 + w * 16 + n16] = v;
            }
        }
    }
    __syncthreads();

    // GEMM2: xz = xin @ in_proj (waves 0-1 -> xc, waves 2-3 -> silu(z))
    {
        s8 bf[4][2];
#pragma unroll
        for (int i = 0; i < 4; i++)
#pragma unroll
            for (int ks = 0; ks < 2; ks++)
                bf[i][ks] = *(const s8*)(Wf2 + (((w * 4 + i) * 2 + ks) * 64 + lane) * 8);
        for (int m = 0; m < 5; m++) {
            int ar = m * 16 + n16;
            s8 a0 = *(const s8*)(smB + ar * PA + quad * 8);
            s8 a1 = *(const s8*)(smB + ar * PA + 32 + quad * 8);
#pragma unroll
            for (int i = 0; i < 4; i++) {
                f4 acc = {0.f, 0.f, 0.f, 0.f};
                acc = MFMA16(a0, bf[i][0], acc, 0, 0, 0);
                acc = MFMA16(a1, bf[i][1], acc, 0, 0, 0);
                int cg = (w * 4 + i) * 16 + n16;
#pragma unroll
                for (int reg = 0; reg < 4; reg++) {
                    int rr = m * 16 + quad * 4 + reg;
                    float v = acc[reg];
                    if (cg < 128) {                     // wave-uniform branch
                        if (rr < 67) {
                            int l = c0 - 3 + rr;
                            smC[rr * PC + cg] = f2bfu(l >= 0 ? v : 0.f);
                        }
                    } else if (rr >= 3 && rr < 67) {
                        sz_g[(tokbase + rr - 3) * 128 + (cg - 128)] = f2bfu(v * fsig(v));
                    }
                }
            }
        }
    }
    __syncthreads();

    // conv(4) + silu -> u (LDS only)
    {
        const int d2 = lane * 2, ctb = w * 16;
        float4 cw0 = ((const float4*)conv_w)[d2];
        float4 cw1 = ((const float4*)conv_w)[d2 + 1];
        float cb0 = conv_b[d2], cb1 = conv_b[d2 + 1];
        u32 r0 = *(const u32*)((char*)smC + (ctb + 0) * 264 + lane * 4);
        u32 r1 = *(const u32*)((char*)smC + (ctb + 1) * 264 + lane * 4);
        u32 r2 = *(const u32*)((char*)smC + (ctb + 2) * 264 + lane * 4);
#pragma unroll 4
        for (int j = 0; j < 16; j++) {
            int ct = ctb + j;
            u32 r3 = *(const u32*)((char*)smC + (ct + 3) * 264 + lane * 4);
            float v0 = cb0 + bflo(r0) * cw0.x + bflo(r1) * cw0.y + bflo(r2) * cw0.z + bflo(r3) * cw0.w;
            float v1 = cb1 + bfhi(r0) * cw1.x + bfhi(r1) * cw1.y + bfhi(r2) * cw1.z + bfhi(r3) * cw1.w;
            u32 pk = pk2bf(v0 * fsig(v0), v1 * fsig(v1));
            *(u32*)(smU + ct * PU + d2) = pk;
            r0 = r1; r1 = r2; r2 = r3;
        }
    }
    __syncthreads();

    // GEMM3: dbc = u @ x_proj  (M=64, N=48(36), K=128); wave w -> mtile w
    {
        s8 bf3[3][4];
#pragma unroll
        for (int nt = 0; nt < 3; nt++)
#pragma unroll
            for (int ks = 0; ks < 4; ks++)
                bf3[nt][ks] = *(const s8*)(Wf3 + ((nt * 4 + ks) * 64 + lane) * 8);
        f4 acc[3] = {{0.f,0.f,0.f,0.f},{0.f,0.f,0.f,0.f},{0.f,0.f,0.f,0.f}};
        int ar = w * 16 + n16;
#pragma unroll
        for (int ks = 0; ks < 4; ks++) {
            s8 a = *(const s8*)(smU + ar * PU + ks * 32 + quad * 8);
#pragma unroll
            for (int nt = 0; nt < 3; nt++) acc[nt] = MFMA16(a, bf3[nt][ks], acc[nt], 0, 0, 0);
        }
#pragma unroll
        for (int nt = 0; nt < 3; nt++) {
            int c = nt * 16 + n16;
#pragma unroll
            for (int reg = 0; reg < 4; reg++) {
                int rr = w * 16 + quad * 4 + reg;
                float v = acc[nt][reg];
                long long t = tokbase + rr;
                if (c < 4)       smDtr[rr * 4 + c] = v;
                else if (c < 20) { B_g[t * 16 + (c - 4)] = v; smBf[rr * 16 + (c - 4)] = v; }
                else if (c < 36) C_g[t * 16 + (c - 20)] = v;
            }
        }
    }
    __syncthreads();   // smC dead; smDt region now writable

    // dt = softplus(dtr @ dt_proj_w + dt_proj_b); fp16 pair -> smDt; packed (dt|u) -> global
    {
        const int o2 = lane * 2, grp = w;
        float w00 = dt_w[o2],       w01 = dt_w[o2 + 1];
        float w10 = dt_w[128 + o2], w11 = dt_w[128 + o2 + 1];
        float w20 = dt_w[256 + o2], w21 = dt_w[256 + o2 + 1];
        float w30 = dt_w[384 + o2], w31 = dt_w[384 + o2 + 1];
        float b0 = dt_b[o2], b1 = dt_b[o2 + 1];
#pragma unroll 4
        for (int j = 0; j < 16; j++) {
            int ct = grp * 16 + j;
            float4 q = *(const float4*)(smDtr + ct * 4);
            float v0 = b0 + q.x * w00 + q.y * w10 + q.z * w20 + q.w * w30;
            float v1 = b1 + q.x * w01 + q.y * w11 + q.z * w21 + q.w * w31;
            u32 hpk = (u32)__half_as_ushort(__float2half_rn(fsp(v0))) |
                      ((u32)__half_as_ushort(__float2half_rn(fsp(v1))) << 16);
            smDt[ct * 64 + lane] = hpk;
            u32 upk = *(const u32*)(smU + ct * PU + o2);
            u32 pk0 = (hpk & 0xFFFFu) | (upk << 16);
            u32 pk1 = (hpk >> 16) | (upk & 0xFFFF0000u);
            *(uint2*)(dtu_g + (tokbase + ct) * 128 + o2) = make_uint2(pk0, pk1);
        }
    }
    __syncthreads();

    // Fused sub-chunk scan: 1 thread per (sub-chunk, channel), 16 states, 32 tokens.
    {
        const int d = tid & 127, cs = tid >> 7;
        const int j2 = d >> 1, hi = d & 1;
        float A[16];
#pragma unroll
        for (int s = 0; s < 16; s++) A[s] = -__expf(A_log[d * 16 + s]);
        const float A0 = A[0];
        bool chain = true;
#pragma unroll
        for (int s = 1; s < 16; s++)
            chain = chain && (fabsf(A[s] - (float)(s + 1) * A0) <= 1e-4f * fabsf(A[s]));

        float h[16];
#pragma unroll
        for (int s = 0; s < 16; s++) h[s] = 0.f;
        float sdt = 0.f;

        if (chain) {
            for (int i = 0; i < CLEN; i++) {
                int t = cs * CLEN + i;
                u32 q = smDt[t * 64 + j2];
                float dtv = __half2float(__ushort_as_half((u16)(hi ? (q >> 16) : (q & 0xFFFFu))));
                float uv  = bfu2f(smU[t * PU + d]);
                float du  = dtv * uv;  sdt += dtv;
                float4 b0 = *(const float4*)(smBf + t * 16);
                float4 b1 = *(const float4*)(smBf + t * 16 + 4);
                float4 b2 = *(const float4*)(smBf + t * 16 + 8);
                float4 b3 = *(const float4*)(smBf + t * 16 + 12);
                // depth-4 power tree: p^1..p^16
                float p  = __expf(dtv * A0);
                float p2 = p * p,  p3 = p2 * p,  p4 = p2 * p2;
                float p8 = p4 * p4;
                h[0]  = p        * h[0]  + du * b0.x;
                h[1]  = p2       * h[1]  + du * b0.y;
                h[2]  = p3       * h[2]  + du * b0.z;
                h[3]  = p4       * h[3]  + du * b0.w;
                h[4]  = (p4*p)   * h[4]  + du * b1.x;
                h[5]  = (p4*p2)  * h[5]  + du * b1.y;
                h[6]  = (p4*p3)  * h[6]  + du * b1.z;
                h[7]  = p8       * h[7]  + du * b1.w;
                h[8]  = (p8*p)   * h[8]  + du * b2.x;
                h[9]  = (p8*p2)  * h[9]  + du * b2.y;
                h[10] = (p8*p3)  * h[10] + du * b2.z;
                h[11] = (p8*p4)  * h[11] + du * b2.w;
                h[12] = (p8*p4*p)  * h[12] + du * b3.x;
                h[13] = (p8*p4*p2) * h[13] + du * b3.y;
                h[14] = (p8*p4*p3) * h[14] + du * b3.z;
                h[15] = (p8*p8)    * h[15] + du * b3.w;
            }
        } else {
            for (int i = 0; i < CLEN; i++) {
                int t = cs * CLEN + i;
                u32 q = smDt[t * 64 + j2];
                float dtv = __half2float(__ushort_as_half((u16)(hi ? (q >> 16) : (q & 0xFFFFu))));
                float uv  = bfu2f(smU[t * PU + d]);
                float du  = dtv * uv;  sdt += dtv;
                const float* Bp = smBf + t * 16;
#pragma unroll
                for (int s = 0; s < 16; s++) h[s] = __expf(dtv * A[s]) * h[s] + du * Bp[s];
            }
        }

        const int ch = blockIdx.x * 2 + cs;
        float4* hp4 = (float4*)(hl_ws + (((long long)b * NCH + ch) * 128 + d) * 16);
        hp4[0] = make_float4(h[0], h[1], h[2], h[3]);
        hp4[1] = make_float4(h[4], h[5], h[6], h[7]);
        hp4[2] = make_float4(h[8], h[9], h[10], h[11]);
        hp4[3] = make_float4(h[12], h[13], h[14], h[15]);
        sdt_ws[((long long)b * NCH + ch) * 128 + d] = sdt;
    }
}

// ---------------- Chunk-boundary combine (in-place: hl -> hin), all-CU spread ----------------
__global__ __launch_bounds__(128) void k_combine(
    const float* __restrict__ A_log, float* __restrict__ hl_ws,
    const float* __restrict__ sdt_ws)
{
    int gid = blockIdx.x * 128 + threadIdx.x;   // 0..32767
    int b = gid >> 11;
    int rem = gid & 2047;     // d*16+s
    int d = rem >> 4;
    float A = -__expf(A_log[rem]);
    float h = 0.f;
    for (int c = 0; c < NCH; c++) {
        long long o = ((long long)b * NCH + c) * 2048 + rem;
        float v = hl_ws[o];
        float sdt = sdt_ws[((long long)b * NCH + c) * 128 + d];
        hl_ws[o] = h;                       // becomes hin
        h = __expf(A * sdt) * h + v;
    }
}

// ---------------- Backend: scan (direct loads) + epilogue, smR overlays sy ----------------
// LDS = 17408 B only -> 8 blocks/CU (wave-capped). Epilogue holds MFMA accs in regs,
// then smR overwrites sy after a barrier.
__global__ __launch_bounds__(256, 6) void k_backend(
    const u32* __restrict__ dtu_g, const float* __restrict__ B_g,
    const float* __restrict__ C_g, const u16* __restrict__ sz_g,
    const float* __restrict__ A_log, const float* __restrict__ D_skip,
    const float* __restrict__ hin_ws, const float* __restrict__ xin_g,
    const u16* __restrict__ Wf4, const float* __restrict__ gamma,
    const float* __restrict__ beta, float* __restrict__ out)
{
    __shared__ __align__(16) char sm[17408];
    u16*   sy   = (u16*)sm;               // [64][136] bf16 y
    float* smR  = (float*)sm;             // [64][65] f32, overlays sy after MFMA reads

    const int tid = threadIdx.x;
    const int cb = blockIdx.x, b = blockIdx.y;   // 64-token tile
    const long long tok0 = (long long)b * L_SZ + (long long)cb * 64;

    // ---- scan: 1 thread per (half, channel), 16 states, 32 tokens, direct loads ----
    {
        const int d = tid & 127, half = tid >> 7;
        float A[16];
#pragma unroll
        for (int s = 0; s < 16; s++) A[s] = -__expf(A_log[d * 16 + s]);
        const float A0 = A[0];
        bool chain = true;
#pragma unroll
        for (int s = 1; s < 16; s++)
            chain = chain && (fabsf(A[s] - (float)(s + 1) * A0) <= 1e-4f * fabsf(A[s]));

        float h[16];
        {
            const float4* hp = (const float4*)(hin_ws +
                (((long long)b * NCH + 2 * cb + half) * 128 + d) * 16);
            float4 h0 = hp[0], h1 = hp[1], h2 = hp[2], h3 = hp[3];
            h[0]=h0.x; h[1]=h0.y; h[2]=h0.z; h[3]=h0.w;
            h[4]=h1.x; h[5]=h1.y; h[6]=h1.z; h[7]=h1.w;
            h[8]=h2.x; h[9]=h2.y; h[10]=h2.z; h[11]=h2.w;
            h[12]=h3.x; h[13]=h3.y; h[14]=h3.z; h[15]=h3.w;
        }
        const float Dv = D_skip[d];

        if (chain) {
            for (int i = 0; i < CLEN; i++) {
                int t = half * CLEN + i;
                u32 pk = dtu_g[(tok0 + t) * 128 + d];
                float dtv = h2f(pk);
                float uv  = bfhi(pk);
                float du  = dtv * uv;
                const float4* Bp = (const float4*)(B_g + (tok0 + t) * 16);
                float4 b0 = Bp[0], b1 = Bp[1], b2 = Bp[2], b3 = Bp[3];
                const float4* Cp = (const float4*)(C_g + (tok0 + t) * 16);
                float4 c0 = Cp[0], c1 = Cp[1], c2 = Cp[2], c3 = Cp[3];
                // depth-4 power tree: p^1..p^16
                float p  = __expf(dtv * A0);
                float p2 = p * p,  p3 = p2 * p,  p4 = p2 * p2;
                float p8 = p4 * p4;
                h[0]  = p        * h[0]  + du * b0.x; float ys = h[0] * c0.x;
                h[1]  = p2       * h[1]  + du * b0.y; ys += h[1]  * c0.y;
                h[2]  = p3       * h[2]  + du * b0.z; ys += h[2]  * c0.z;
                h[3]  = p4       * h[3]  + du * b0.w; ys += h[3]  * c0.w;
                h[4]  = (p4*p)   * h[4]  + du * b1.x; ys += h[4]  * c1.x;
                h[5]  = (p4*p2)  * h[5]  + du * b1.y; ys += h[5]  * c1.y;
                h[6]  = (p4*p3)  * h[6]  + du * b1.z; ys += h[6]  * c1.z;
                h[7]  = p8       * h[7]  + du * b1.w; ys += h[7]  * c1.w;
                h[8]  = (p8*p)   * h[8]  + du * b2.x; ys += h[8]  * c2.x;
                h[9]  = (p8*p2)  * h[9]  + du * b2.y; ys += h[9]  * c2.y;
                h[10] = (p8*p3)  * h[10] + du * b2.z; ys += h[10] * c2.z;
                h[11] = (p8*p4)  * h[11] + du * b2.w; ys += h[11] * c2.w;
                h[12] = (p8*p4*p)  * h[12] + du * b3.x; ys += h[12] * c3.x;
                h[13] = (p8*p4*p2) * h[13] + du * b3.y; ys += h[13] * c3.y;
                h[14] = (p8*p4*p3) * h[14] + du * b3.z; ys += h[14] * c3.z;
                h[15] = (p8*p8)    * h[15] + du * b3.w; ys += h[15] * c3.w;
                float szv = bfu2f(sz_g[(tok0 + t) * 128 + d]);
                sy[t * PU + d] = f2bfu((ys + uv * Dv) * szv);
            }
        } else {
            for (int i = 0; i < CLEN; i++) {
                int t = half * CLEN + i;
                u32 pk = dtu_g[(tok0 + t) * 128 + d];
                float dtv = h2f(pk);
                float uv  = bfhi(pk);
                float du  = dtv * uv;
                const float4* Bp = (const float4*)(B_g + (tok0 + t) * 16);
                float4 b0 = Bp[0], b1 = Bp[1], b2 = Bp[2], b3 = Bp[3];
                float Bv[16] = { b0.x, b0.y, b0.z, b0.w, b1.x, b1.y, b1.z, b1.w,
                                 b2.x, b2.y, b2.z, b2.w, b3.x, b3.y, b3.z, b3.w };
                const float4* Cp = (const float4*)(C_g + (tok0 + t) * 16);
                float4 c0 = Cp[0], c1 = Cp[1], c2 = Cp[2], c3 = Cp[3];
                float Cv[16] = { c0.x, c0.y, c0.z, c0.w, c1.x, c1.y, c1.z, c1.w,
                                 c2.x, c2.y, c2.z, c2.w, c3.x, c3.y, c3.z, c3.w };
                float ys = 0.f;
#pragma unroll
                for (int s = 0; s < 16; s++) {
                    h[s] = __expf(dtv * A[s]) * h[s] + du * Bv[s];
                    ys += h[s] * Cv[s];
                }
                float szv = bfu2f(sz_g[(tok0 + t) * 128 + d]);
                sy[t * PU + d] = f2bfu((ys + uv * Dv) * szv);
            }
        }
    }
    __syncthreads();   // sy complete

    // ---- epilogue: out = LN(y @ out_proj + xin); accs in regs, then smR overlays sy ----
    const int w = tid >> 6, lane = tid & 63;
    const int n16 = lane & 15, quad = lane >> 4;
    f4 accm[4];
    {
        s8 bf[4];
#pragma unroll
        for (int ks = 0; ks < 4; ks++)
            bf[ks] = *(const s8*)(Wf4 + ((w * 4 + ks) * 64 + lane) * 8);
#pragma unroll
        for (int m = 0; m < 4; m++) {
            int ar = m * 16 + n16;
            f4 acc = {0.f, 0.f, 0.f, 0.f};
#pragma unroll
            for (int ks = 0; ks < 4; ks++) {
                s8 a = *(const s8*)(sy + ar * PU + ks * 32 + quad * 8);
                acc = MFMA16(a, bf[ks], acc, 0, 0, 0);
            }
            accm[m] = acc;
        }
    }
    __syncthreads();   // all sy reads done; region now writable as smR

    {
#pragma unroll
        for (int m = 0; m < 4; m++)
#pragma unroll
            for (int reg = 0; reg < 4; reg++) {
                int rr = m * 16 + quad * 4 + reg;
                smR[rr * 65 + w * 16 + n16] = accm[m][reg];
            }
    }
    __syncthreads();

    {
        int o = tid & 63, wv = tid >> 6;
        float g = gamma[o], bb = beta[o];
        for (int j = 0; j < 16; j++) {
            int rr = wv * 16 + j;
            float r = smR[rr * 65 + o] + xin_g[(tok0 + rr) * 64 + o];
            float s = r;
#pragma unroll
            for (int mS = 0; mS < 6; mS++) s += __shfl_xor(s, 1 << mS, 64);
            float mu = s * (1.f / 64.f);
            float dv = r - mu;
            float vs = dv * dv;
#pragma unroll
            for (int mS = 0; mS < 6; mS++) vs += __shfl_xor(vs, 1 << mS, 64);
            out[(tok0 + rr) * 64 + o] = g * dv * rsqrtf(vs * (1.f / 64.f) + LN_EPS) + bb;
        }
    }
}

extern "C" void kernel_launch(void* const* d_in, const int* in_sizes, int n_in,
                              void* d_out, int out_size, void* d_ws, size_t ws_size,
                              hipStream_t stream)
{
    const float* x       = (const float*)d_in[0];
    const float* W_in    = (const float*)d_in[1];
    const float* b_in    = (const float*)d_in[2];
    const float* in_proj = (const float*)d_in[3];
    const float* conv_w  = (const float*)d_in[4];
    const float* conv_b  = (const float*)d_in[5];
    const float* x_proj  = (const float*)d_in[6];
    const float* dt_w    = (const float*)d_in[7];
    const float* dt_b    = (const float*)d_in[8];
    const float* A_log   = (const float*)d_in[9];
    const float* D_skip  = (const float*)d_in[10];
    const float* Wout    = (const float*)d_in[11];
    const float* gamma   = (const float*)d_in[12];
    const float* beta    = (const float*)d_in[13];
    float* out = (float*)d_out;

    const long long NT = (long long)B_SZ * L_SZ;  // 131072 tokens
    char* ws = (char*)d_ws;
    float*  xin_g = (float*)ws;   ws += NT * 64 * 4;
    u32*    dtu_g = (u32*)ws;     ws += NT * 128 * 4;   // (dt fp16 | u bf16)
    float*  B_g   = (float*)ws;   ws += NT * 16 * 4;
    float*  C_g   = (float*)ws;   ws += NT * 16 * 4;
    u16*    sz_g  = (u16*)ws;     ws += NT * 128 * 2;
    float*  hl_ws  = (float*)ws;  ws += (long long)B_SZ * NCH * 2048 * 4;  // hl -> hin (in place)
    float*  sdt_ws = (float*)ws;  ws += (long long)B_SZ * NCH * 128 * 4;
    u16* Wf1 = (u16*)ws; ws += 4096 * 2;
    u16* Wf2 = (u16*)ws; ws += 16384 * 2;
    u16* Wf3 = (u16*)ws; ws += 6144 * 2;
    u16* Wf4 = (u16*)ws; ws += 8192 * 2;

    k_prep<<<1, 256, 0, stream>>>(W_in, in_proj, x_proj, Wout, Wf1, Wf2, Wf3, Wf4);

    k_frontend<<<dim3(L_SZ / CH, B_SZ), 256, 0, stream>>>(
        x, b_in, conv_w, conv_b, dt_w, dt_b, Wf1, Wf2, Wf3, A_log,
        xin_g, dtu_g, B_g, C_g, sz_g, hl_ws, sdt_ws);

    k_combine<<<256, 128, 0, stream>>>(A_log, hl_ws, sdt_ws);

    k_backend<<<dim3(L_SZ / 64, B_SZ), 256, 0, stream>>>(
        dtu_g, B_g, C_g, sz_g, A_log, D_skip, hl_ws, xin_g,
        Wf4, gamma, beta, out);
}

// Round 8
// 295.171 us; speedup vs baseline: 1.2429x; 1.0027x over previous
//
#include <hip/hip_runtime.h>
#include <hip/hip_bf16.h>
#include <hip/hip_fp16.h>

#define B_SZ   16
#define L_SZ   8192
#define DM     64
#define DI     128
#define NCH    256      // scan sub-chunks (32 tokens each)
#define CLEN   32       // L_SZ / NCH
#define CH     64       // frontend tokens per block (= 2 sub-chunks)
#define RT     80       // padded rows (5 mtiles of 16; 67 used)
#define PA     72       // LDS pitch (u16) for 64-wide acts: 144B
#define PU     136      // LDS pitch (u16) for 128-wide acts: 272B
#define PC     132      // LDS pitch (u16) for conv input: 264B
#define LN_EPS 1e-3f

typedef float  f4 __attribute__((ext_vector_type(4)));
typedef short  s8 __attribute__((ext_vector_type(8)));
typedef unsigned short u16;
typedef unsigned int   u32;
#define MFMA16 __builtin_amdgcn_mfma_f32_16x16x32_bf16

__device__ __forceinline__ u16 f2bfu(float f) {
    u32 u = __float_as_uint(f);
    return (u16)((u + 0x7FFFu + ((u >> 16) & 1u)) >> 16);
}
__device__ __forceinline__ u32 pk2bf(float a, float b) {
    return (u32)f2bfu(a) | ((u32)f2bfu(b) << 16);
}
__device__ __forceinline__ float bflo(u32 u) { return __uint_as_float(u << 16); }
__device__ __forceinline__ float bfhi(u32 u) { return __uint_as_float(u & 0xFFFF0000u); }
__device__ __forceinline__ float bfu2f(u16 h) { return __uint_as_float((u32)h << 16); }
__device__ __forceinline__ float h2f(u32 lo16) {
    return __half2float(__ushort_as_half((u16)(lo16 & 0xFFFFu)));
}
__device__ __forceinline__ float fsig(float v) {
    return __builtin_amdgcn_rcpf(1.f + __expf(-v));
}
__device__ __forceinline__ float fsp(float v) {   // softplus
    return fmaxf(v, 0.f) + __logf(1.f + __expf(-fabsf(v)));
}

// ---------------- Weight prep: fragment-linear bf16 granules ----------------
__global__ __launch_bounds__(256) void k_prep(
    const float* __restrict__ W_in, const float* __restrict__ in_proj,
    const float* __restrict__ x_proj, const float* __restrict__ Wout,
    u16* __restrict__ Wf1, u16* __restrict__ Wf2,
    u16* __restrict__ Wf3, u16* __restrict__ Wf4)
{
    const int tid = threadIdx.x;
    for (int g = tid; g < 512; g += 256) {          // W_in: 4 nt x 2 ks
        int lane = g & 63, ks = (g >> 6) & 1, nt = g >> 7;
        int n = nt * 16 + (lane & 15), kb = ks * 32 + (lane >> 4) * 8;
        for (int j = 0; j < 8; j++) Wf1[g * 8 + j] = f2bfu(W_in[(kb + j) * 64 + n]);
    }
    for (int g = tid; g < 2048; g += 256) {         // in_proj: 16 nt x 2 ks
        int lane = g & 63, ks = (g >> 6) & 1, nt = g >> 7;
        int n = nt * 16 + (lane & 15), kb = ks * 32 + (lane >> 4) * 8;
        for (int j = 0; j < 8; j++) Wf2[g * 8 + j] = f2bfu(in_proj[(kb + j) * 256 + n]);
    }
    for (int g = tid; g < 768; g += 256) {          // x_proj (pad N 36->48): 3 nt x 4 ks
        int lane = g & 63, ks = (g >> 6) & 3, nt = g >> 8;
        int n = nt * 16 + (lane & 15), kb = ks * 32 + (lane >> 4) * 8;
        for (int j = 0; j < 8; j++)
            Wf3[g * 8 + j] = f2bfu(n < 36 ? x_proj[(kb + j) * 36 + n] : 0.f);
    }
    for (int g = tid; g < 1024; g += 256) {         // out_proj: 4 nt x 4 ks
        int lane = g & 63, ks = (g >> 6) & 3, nt = g >> 8;
        int n = nt * 16 + (lane & 15), kb = ks * 32 + (lane >> 4) * 8;
        for (int j = 0; j < 8; j++) Wf4[g * 8 + j] = f2bfu(Wout[(kb + j) * 64 + n]);
    }
}

// ---------------- Frontend + fused sub-chunk scan (scan1) ----------------
__global__ __launch_bounds__(256, 4) void k_frontend(
    const float* __restrict__ x, const float* __restrict__ b_in,
    const float* __restrict__ conv_w, const float* __restrict__ conv_b,
    const float* __restrict__ dt_w, const float* __restrict__ dt_b,
    const u16* __restrict__ Wf1, const u16* __restrict__ Wf2, const u16* __restrict__ Wf3,
    const float* __restrict__ A_log,
    float* __restrict__ xin_g, u32* __restrict__ dtu_g,
    float* __restrict__ B_g, float* __restrict__ C_g, u16* __restrict__ sz_g,
    float* __restrict__ hl_ws, float* __restrict__ sdt_ws)
{
    __shared__ __align__(16) char sm[40736];
    u16*   smA   = (u16*)sm;              // [80][72] x (bf16)
    u16*   smB   = (u16*)(sm + 11520);    // [80][72] xin
    u16*   smU   = (u16*)sm;              // [64][136] u (reuses smA/smB)
    float* smDtr = (float*)(sm + 17408);  // [64][4]
    float* smBf  = (float*)(sm + 18432);  // [64][16] B for scan
    u16*   smC   = (u16*)(sm + 23040);    // [67][132] xc
    u32*   smDt  = (u32*)(sm + 23040);    // [64][64] fp16 dt pairs, overlays dead smC

    const int tid = threadIdx.x;
    const int w = tid >> 6, lane = tid & 63;
    const int n16 = lane & 15, quad = lane >> 4;
    const int b = blockIdx.y, c0 = blockIdx.x * CH;
    const long long tokbase = (long long)b * L_SZ + c0;

    // P0: stage x rows (bf16), float4-vectorized
    for (int idx = tid; idx < RT * 16; idx += 256) {
        int r = idx >> 4, c4 = idx & 15;
        int l = c0 - 3 + r;
        float4 v = make_float4(0.f, 0.f, 0.f, 0.f);
        if (r < 67 && l >= 0)
            v = *(const float4*)(x + ((long long)b * L_SZ + l) * 64 + c4 * 4);
        *(uint2*)((char*)smA + r * 144 + c4 * 8) = make_uint2(pk2bf(v.x, v.y), pk2bf(v.z, v.w));
    }
    __syncthreads();

    // GEMM1: xin = x @ W_in + b_in
    {
        s8 b0 = *(const s8*)(Wf1 + ((w * 2 + 0) * 64 + lane) * 8);
        s8 b1 = *(const s8*)(Wf1 + ((w * 2 + 1) * 64 + lane) * 8);
        float bias = b_in[w * 16 + n16];
        for (int m = 0; m < 5; m++) {
            int ar = m * 16 + n16;
            s8 a0 = *(const s8*)(smA + ar * PA + quad * 8);
            s8 a1 = *(const s8*)(smA + ar * PA + 32 + quad * 8);
            f4 acc = {0.f, 0.f, 0.f, 0.f};
            acc = MFMA16(a0, b0, acc, 0, 0, 0);
            acc = MFMA16(a1, b1, acc, 0, 0, 0);
#pragma unroll
            for (int reg = 0; reg < 4; reg++) {
                int rr = m * 16 + quad * 4 + reg;
                float v = acc[reg] + bias;
                smB[rr * PA + w * 16 + n16] = f2bfu(v);
                if (rr >= 3 && rr < 67)
                    xin_g[(tokbase + rr - 3) * 64 + w * 16 + n16] = v;
            }
        }
    }
    __syncthreads();

    // GEMM2: xz = xin @ in_proj (waves 0-1 -> xc, waves 2-3 -> silu(z))
    {
        s8 bf[4][2];
#pragma unroll
        for (int i = 0; i < 4; i++)
#pragma unroll
            for (int ks = 0; ks < 2; ks++)
                bf[i][ks] = *(const s8*)(Wf2 + (((w * 4 + i) * 2 + ks) * 64 + lane) * 8);
        for (int m = 0; m < 5; m++) {
            int ar = m * 16 + n16;
            s8 a0 = *(const s8*)(smB + ar * PA + quad * 8);
            s8 a1 = *(const s8*)(smB + ar * PA + 32 + quad * 8);
#pragma unroll
            for (int i = 0; i < 4; i++) {
                f4 acc = {0.f, 0.f, 0.f, 0.f};
                acc = MFMA16(a0, bf[i][0], acc, 0, 0, 0);
                acc = MFMA16(a1, bf[i][1], acc, 0, 0, 0);
                int cg = (w * 4 + i) * 16 + n16;
#pragma unroll
                for (int reg = 0; reg < 4; reg++) {
                    int rr = m * 16 + quad * 4 + reg;
                    float v = acc[reg];
                    if (cg < 128) {                     // wave-uniform branch
                        if (rr < 67) {
                            int l = c0 - 3 + rr;
                            smC[rr * PC + cg] = f2bfu(l >= 0 ? v : 0.f);
                        }
                    } else if (rr >= 3 && rr < 67) {
                        sz_g[(tokbase + rr - 3) * 128 + (cg - 128)] = f2bfu(v * fsig(v));
                    }
                }
            }
        }
    }
    __syncthreads();

    // conv(4) + silu -> u (LDS only)
    {
        const int d2 = lane * 2, ctb = w * 16;
        float4 cw0 = ((const float4*)conv_w)[d2];
        float4 cw1 = ((const float4*)conv_w)[d2 + 1];
        float cb0 = conv_b[d2], cb1 = conv_b[d2 + 1];
        u32 r0 = *(const u32*)((char*)smC + (ctb + 0) * 264 + lane * 4);
        u32 r1 = *(const u32*)((char*)smC + (ctb + 1) * 264 + lane * 4);
        u32 r2 = *(const u32*)((char*)smC + (ctb + 2) * 264 + lane * 4);
#pragma unroll 4
        for (int j = 0; j < 16; j++) {
            int ct = ctb + j;
            u32 r3 = *(const u32*)((char*)smC + (ct + 3) * 264 + lane * 4);
            float v0 = cb0 + bflo(r0) * cw0.x + bflo(r1) * cw0.y + bflo(r2) * cw0.z + bflo(r3) * cw0.w;
            float v1 = cb1 + bfhi(r0) * cw1.x + bfhi(r1) * cw1.y + bfhi(r2) * cw1.z + bfhi(r3) * cw1.w;
            u32 pk = pk2bf(v0 * fsig(v0), v1 * fsig(v1));
            *(u32*)(smU + ct * PU + d2) = pk;
            r0 = r1; r1 = r2; r2 = r3;
        }
    }
    __syncthreads();

    // GEMM3: dbc = u @ x_proj  (M=64, N=48(36), K=128); wave w -> mtile w
    {
        s8 bf3[3][4];
#pragma unroll
        for (int nt = 0; nt < 3; nt++)
#pragma unroll
            for (int ks = 0; ks < 4; ks++)
                bf3[nt][ks] = *(const s8*)(Wf3 + ((nt * 4 + ks) * 64 + lane) * 8);
        f4 acc[3] = {{0.f,0.f,0.f,0.f},{0.f,0.f,0.f,0.f},{0.f,0.f,0.f,0.f}};
        int ar = w * 16 + n16;
#pragma unroll
        for (int ks = 0; ks < 4; ks++) {
            s8 a = *(const s8*)(smU + ar * PU + ks * 32 + quad * 8);
#pragma unroll
            for (int nt = 0; nt < 3; nt++) acc[nt] = MFMA16(a, bf3[nt][ks], acc[nt], 0, 0, 0);
        }
#pragma unroll
        for (int nt = 0; nt < 3; nt++) {
            int c = nt * 16 + n16;
#pragma unroll
            for (int reg = 0; reg < 4; reg++) {
                int rr = w * 16 + quad * 4 + reg;
                float v = acc[nt][reg];
                long long t = tokbase + rr;
                if (c < 4)       smDtr[rr * 4 + c] = v;
                else if (c < 20) { B_g[t * 16 + (c - 4)] = v; smBf[rr * 16 + (c - 4)] = v; }
                else if (c < 36) C_g[t * 16 + (c - 20)] = v;
            }
        }
    }
    __syncthreads();   // smC dead; smDt region now writable

    // dt = softplus(dtr @ dt_proj_w + dt_proj_b); fp16 pair -> smDt; packed (dt|u) -> global
    {
        const int o2 = lane * 2, grp = w;
        float w00 = dt_w[o2],       w01 = dt_w[o2 + 1];
        float w10 = dt_w[128 + o2], w11 = dt_w[128 + o2 + 1];
        float w20 = dt_w[256 + o2], w21 = dt_w[256 + o2 + 1];
        float w30 = dt_w[384 + o2], w31 = dt_w[384 + o2 + 1];
        float b0 = dt_b[o2], b1 = dt_b[o2 + 1];
#pragma unroll 4
        for (int j = 0; j < 16; j++) {
            int ct = grp * 16 + j;
            float4 q = *(const float4*)(smDtr + ct * 4);
            float v0 = b0 + q.x * w00 + q.y * w10 + q.z * w20 + q.w * w30;
            float v1 = b1 + q.x * w01 + q.y * w11 + q.z * w21 + q.w * w31;
            u32 hpk = (u32)__half_as_ushort(__float2half_rn(fsp(v0))) |
                      ((u32)__half_as_ushort(__float2half_rn(fsp(v1))) << 16);
            smDt[ct * 64 + lane] = hpk;
            u32 upk = *(const u32*)(smU + ct * PU + o2);
            u32 pk0 = (hpk & 0xFFFFu) | (upk << 16);
            u32 pk1 = (hpk >> 16) | (upk & 0xFFFF0000u);
            *(uint2*)(dtu_g + (tokbase + ct) * 128 + o2) = make_uint2(pk0, pk1);
        }
    }
    __syncthreads();

    // Fused sub-chunk scan: 1 thread per (sub-chunk, channel), 16 states, 32 tokens.
    {
        const int d = tid & 127, cs = tid >> 7;
        const int j2 = d >> 1, hi = d & 1;
        float A[16];
#pragma unroll
        for (int s = 0; s < 16; s++) A[s] = -__expf(A_log[d * 16 + s]);
        const float A0 = A[0];
        bool chain = true;
#pragma unroll
        for (int s = 1; s < 16; s++)
            chain = chain && (fabsf(A[s] - (float)(s + 1) * A0) <= 1e-4f * fabsf(A[s]));

        float h[16];
#pragma unroll
        for (int s = 0; s < 16; s++) h[s] = 0.f;
        float sdt = 0.f;

        if (chain) {
            for (int i = 0; i < CLEN; i++) {
                int t = cs * CLEN + i;
                u32 q = smDt[t * 64 + j2];
                float dtv = __half2float(__ushort_as_half((u16)(hi ? (q >> 16) : (q & 0xFFFFu))));
                float uv  = bfu2f(smU[t * PU + d]);
                float du  = dtv * uv;  sdt += dtv;
                float4 b0 = *(const float4*)(smBf + t * 16);
                float4 b1 = *(const float4*)(smBf + t * 16 + 4);
                float4 b2 = *(const float4*)(smBf + t * 16 + 8);
                float4 b3 = *(const float4*)(smBf + t * 16 + 12);
                // depth-4 power tree: p^1..p^16
                float p  = __expf(dtv * A0);
                float p2 = p * p,  p3 = p2 * p,  p4 = p2 * p2;
                float p8 = p4 * p4;
                h[0]  = p        * h[0]  + du * b0.x;
                h[1]  = p2       * h[1]  + du * b0.y;
                h[2]  = p3       * h[2]  + du * b0.z;
                h[3]  = p4       * h[3]  + du * b0.w;
                h[4]  = (p4*p)   * h[4]  + du * b1.x;
                h[5]  = (p4*p2)  * h[5]  + du * b1.y;
                h[6]  = (p4*p3)  * h[6]  + du * b1.z;
                h[7]  = p8       * h[7]  + du * b1.w;
                h[8]  = (p8*p)   * h[8]  + du * b2.x;
                h[9]  = (p8*p2)  * h[9]  + du * b2.y;
                h[10] = (p8*p3)  * h[10] + du * b2.z;
                h[11] = (p8*p4)  * h[11] + du * b2.w;
                h[12] = (p8*p4*p)  * h[12] + du * b3.x;
                h[13] = (p8*p4*p2) * h[13] + du * b3.y;
                h[14] = (p8*p4*p3) * h[14] + du * b3.z;
                h[15] = (p8*p8)    * h[15] + du * b3.w;
            }
        } else {
            for (int i = 0; i < CLEN; i++) {
                int t = cs * CLEN + i;
                u32 q = smDt[t * 64 + j2];
                float dtv = __half2float(__ushort_as_half((u16)(hi ? (q >> 16) : (q & 0xFFFFu))));
                float uv  = bfu2f(smU[t * PU + d]);
                float du  = dtv * uv;  sdt += dtv;
                const float* Bp = smBf + t * 16;
#pragma unroll
                for (int s = 0; s < 16; s++) h[s] = __expf(dtv * A[s]) * h[s] + du * Bp[s];
            }
        }

        const int ch = blockIdx.x * 2 + cs;
        float4* hp4 = (float4*)(hl_ws + (((long long)b * NCH + ch) * 128 + d) * 16);
        hp4[0] = make_float4(h[0], h[1], h[2], h[3]);
        hp4[1] = make_float4(h[4], h[5], h[6], h[7]);
        hp4[2] = make_float4(h[8], h[9], h[10], h[11]);
        hp4[3] = make_float4(h[12], h[13], h[14], h[15]);
        sdt_ws[((long long)b * NCH + ch) * 128 + d] = sdt;
    }
}

// ---------------- Hierarchical chunk-boundary combine (in-place: hl -> hin) ----------------
// One block per (b, d): 256 threads = 16 states x 16 segments of 16 chunks.
// Serial depth 16+15+16 instead of 256; 8192 waves total (32/CU).
__global__ __launch_bounds__(256) void k_combine(
    const float* __restrict__ A_log, float* __restrict__ hl_ws,
    const float* __restrict__ sdt_ws)
{
    __shared__ float sH[16 * 16];   // [seg][s] segment-end h
    __shared__ float sCT[16];       // segment total sum(dt)
    const int tid = threadIdx.x;
    const int s = tid & 15, seg = tid >> 4;
    const int bd = blockIdx.x;      // b*128 + d
    const int b = bd >> 7, d = bd & 127;
    const float A = -__expf(A_log[d * 16 + s]);

    const long long base  = ((long long)b * NCH + seg * 16) * 2048 + d * 16 + s;
    const long long sbase = ((long long)b * NCH + seg * 16) * 128 + d;

    // phase 1: local scan over this segment's 16 chunks (regs, static idx)
    float hinL[16], cum[16];
    float h = 0.f, csum = 0.f;
#pragma unroll
    for (int j = 0; j < 16; j++) {
        float v   = hl_ws[base + (long long)j * 2048];
        float sdt = sdt_ws[sbase + j * 128];
        hinL[j] = h;  cum[j] = csum;
        h = __expf(A * sdt) * h + v;
        csum += sdt;
    }
    sH[seg * 16 + s] = h;
    if (s == 0) sCT[seg] = csum;
    __syncthreads();

    // phase 2: scan over preceding segments (LDS broadcast reads)
    float hseg = 0.f;
    for (int k = 0; k < seg; k++)
        hseg = __expf(A * sCT[k]) * hseg + sH[k * 16 + s];

    // phase 3: fixup + in-place write (each address owned by exactly one thread)
#pragma unroll
    for (int j = 0; j < 16; j++)
        hl_ws[base + (long long)j * 2048] = hinL[j] + __expf(A * cum[j]) * hseg;
}

// ---------------- Backend: scan (direct loads) + epilogue, smR overlays sy ----------------
__global__ __launch_bounds__(256, 6) void k_backend(
    const u32* __restrict__ dtu_g, const float* __restrict__ B_g,
    const float* __restrict__ C_g, const u16* __restrict__ sz_g,
    const float* __restrict__ A_log, const float* __restrict__ D_skip,
    const float* __restrict__ hin_ws, const float* __restrict__ xin_g,
    const u16* __restrict__ Wf4, const float* __restrict__ gamma,
    const float* __restrict__ beta, float* __restrict__ out)
{
    __shared__ __align__(16) char sm[17408];
    u16*   sy   = (u16*)sm;               // [64][136] bf16 y
    float* smR  = (float*)sm;             // [64][65] f32, overlays sy after MFMA reads

    const int tid = threadIdx.x;
    const int cb = blockIdx.x, b = blockIdx.y;   // 64-token tile
    const long long tok0 = (long long)b * L_SZ + (long long)cb * 64;

    // ---- scan: 1 thread per (half, channel), 16 states, 32 tokens, direct loads ----
    {
        const int d = tid & 127, half = tid >> 7;
        float A[16];
#pragma unroll
        for (int s = 0; s < 16; s++) A[s] = -__expf(A_log[d * 16 + s]);
        const float A0 = A[0];
        bool chain = true;
#pragma unroll
        for (int s = 1; s < 16; s++)
            chain = chain && (fabsf(A[s] - (float)(s + 1) * A0) <= 1e-4f * fabsf(A[s]));

        float h[16];
        {
            const float4* hp = (const float4*)(hin_ws +
                (((long long)b * NCH + 2 * cb + half) * 128 + d) * 16);
            float4 h0 = hp[0], h1 = hp[1], h2 = hp[2], h3 = hp[3];
            h[0]=h0.x; h[1]=h0.y; h[2]=h0.z; h[3]=h0.w;
            h[4]=h1.x; h[5]=h1.y; h[6]=h1.z; h[7]=h1.w;
            h[8]=h2.x; h[9]=h2.y; h[10]=h2.z; h[11]=h2.w;
            h[12]=h3.x; h[13]=h3.y; h[14]=h3.z; h[15]=h3.w;
        }
        const float Dv = D_skip[d];

        if (chain) {
            for (int i = 0; i < CLEN; i++) {
                int t = half * CLEN + i;
                u32 pk = dtu_g[(tok0 + t) * 128 + d];
                float dtv = h2f(pk);
                float uv  = bfhi(pk);
                float du  = dtv * uv;
                const float4* Bp = (const float4*)(B_g + (tok0 + t) * 16);
                float4 b0 = Bp[0], b1 = Bp[1], b2 = Bp[2], b3 = Bp[3];
                const float4* Cp = (const float4*)(C_g + (tok0 + t) * 16);
                float4 c0 = Cp[0], c1 = Cp[1], c2 = Cp[2], c3 = Cp[3];
                // depth-4 power tree: p^1..p^16
                float p  = __expf(dtv * A0);
                float p2 = p * p,  p3 = p2 * p,  p4 = p2 * p2;
                float p8 = p4 * p4;
                h[0]  = p        * h[0]  + du * b0.x; float ys = h[0] * c0.x;
                h[1]  = p2       * h[1]  + du * b0.y; ys += h[1]  * c0.y;
                h[2]  = p3       * h[2]  + du * b0.z; ys += h[2]  * c0.z;
                h[3]  = p4       * h[3]  + du * b0.w; ys += h[3]  * c0.w;
                h[4]  = (p4*p)   * h[4]  + du * b1.x; ys += h[4]  * c1.x;
                h[5]  = (p4*p2)  * h[5]  + du * b1.y; ys += h[5]  * c1.y;
                h[6]  = (p4*p3)  * h[6]  + du * b1.z; ys += h[6]  * c1.z;
                h[7]  = p8       * h[7]  + du * b1.w; ys += h[7]  * c1.w;
                h[8]  = (p8*p)   * h[8]  + du * b2.x; ys += h[8]  * c2.x;
                h[9]  = (p8*p2)  * h[9]  + du * b2.y; ys += h[9]  * c2.y;
                h[10] = (p8*p3)  * h[10] + du * b2.z; ys += h[10] * c2.z;
                h[11] = (p8*p4)  * h[11] + du * b2.w; ys += h[11] * c2.w;
                h[12] = (p8*p4*p)  * h[12] + du * b3.x; ys += h[12] * c3.x;
                h[13] = (p8*p4*p2) * h[13] + du * b3.y; ys += h[13] * c3.y;
                h[14] = (p8*p4*p3) * h[14] + du * b3.z; ys += h[14] * c3.z;
                h[15] = (p8*p8)    * h[15] + du * b3.w; ys += h[15] * c3.w;
                float szv = bfu2f(sz_g[(tok0 + t) * 128 + d]);
                sy[t * PU + d] = f2bfu((ys + uv * Dv) * szv);
            }
        } else {
            for (int i = 0; i < CLEN; i++) {
                int t = half * CLEN + i;
                u32 pk = dtu_g[(tok0 + t) * 128 + d];
                float dtv = h2f(pk);
                float uv  = bfhi(pk);
                float du  = dtv * uv;
                const float4* Bp = (const float4*)(B_g + (tok0 + t) * 16);
                float4 b0 = Bp[0], b1 = Bp[1], b2 = Bp[2], b3 = Bp[3];
                float Bv[16] = { b0.x, b0.y, b0.z, b0.w, b1.x, b1.y, b1.z, b1.w,
                                 b2.x, b2.y, b2.z, b2.w, b3.x, b3.y, b3.z, b3.w };
                const float4* Cp = (const float4*)(C_g + (tok0 + t) * 16);
                float4 c0 = Cp[0], c1 = Cp[1], c2 = Cp[2], c3 = Cp[3];
                float Cv[16] = { c0.x, c0.y, c0.z, c0.w, c1.x, c1.y, c1.z, c1.w,
                                 c2.x, c2.y, c2.z, c2.w, c3.x, c3.y, c3.z, c3.w };
                float ys = 0.f;
#pragma unroll
                for (int s = 0; s < 16; s++) {
                    h[s] = __expf(dtv * A[s]) * h[s] + du * Bv[s];
                    ys += h[s] * Cv[s];
                }
                float szv = bfu2f(sz_g[(tok0 + t) * 128 + d]);
                sy[t * PU + d] = f2bfu((ys + uv * Dv) * szv);
            }
        }
    }
    __syncthreads();   // sy complete

    // ---- epilogue: out = LN(y @ out_proj + xin); accs in regs, then smR overlays sy ----
    const int w = tid >> 6, lane = tid & 63;
    const int n16 = lane & 15, quad = lane >> 4;
    f4 accm[4];
    {
        s8 bf[4];
#pragma unroll
        for (int ks = 0; ks < 4; ks++)
            bf[ks] = *(const s8*)(Wf4 + ((w * 4 + ks) * 64 + lane) * 8);
#pragma unroll
        for (int m = 0; m < 4; m++) {
            int ar = m * 16 + n16;
            f4 acc = {0.f, 0.f, 0.f, 0.f};
#pragma unroll
            for (int ks = 0; ks < 4; ks++) {
                s8 a = *(const s8*)(sy + ar * PU + ks * 32 + quad * 8);
                acc = MFMA16(a, bf[ks], acc, 0, 0, 0);
            }
            accm[m] = acc;
        }
    }
    __syncthreads();   // all sy reads done; region now writable as smR

    {
#pragma unroll
        for (int m = 0; m < 4; m++)
#pragma unroll
            for (int reg = 0; reg < 4; reg++) {
                int rr = m * 16 + quad * 4 + reg;
                smR[rr * 65 + w * 16 + n16] = accm[m][reg];
            }
    }
    __syncthreads();

    {
        int o = tid & 63, wv = tid >> 6;
        float g = gamma[o], bb = beta[o];
        for (int j = 0; j < 16; j++) {
            int rr = wv * 16 + j;
            float r = smR[rr * 65 + o] + xin_g[(tok0 + rr) * 64 + o];
            float s = r;
#pragma unroll
            for (int mS = 0; mS < 6; mS++) s += __shfl_xor(s, 1 << mS, 64);
            float mu = s * (1.f / 64.f);
            float dv = r - mu;
            float vs = dv * dv;
#pragma unroll
            for (int mS = 0; mS < 6; mS++) vs += __shfl_xor(vs, 1 << mS, 64);
            out[(tok0 + rr) * 64 + o] = g * dv * rsqrtf(vs * (1.f / 64.f) + LN_EPS) + bb;
        }
    }
}

extern "C" void kernel_launch(void* const* d_in, const int* in_sizes, int n_in,
                              void* d_out, int out_size, void* d_ws, size_t ws_size,
                              hipStream_t stream)
{
    const float* x       = (const float*)d_in[0];
    const float* W_in    = (const float*)d_in[1];
    const float* b_in    = (const float*)d_in[2];
    const float* in_proj = (const float*)d_in[3];
    const float* conv_w  = (const float*)d_in[4];
    const float* conv_b  = (const float*)d_in[5];
    const float* x_proj  = (const float*)d_in[6];
    const float* dt_w    = (const float*)d_in[7];
    const float* dt_b    = (const float*)d_in[8];
    const float* A_log   = (const float*)d_in[9];
    const float* D_skip  = (const float*)d_in[10];
    const float* Wout    = (const float*)d_in[11];
    const float* gamma   = (const float*)d_in[12];
    const float* beta    = (const float*)d_in[13];
    float* out = (float*)d_out;

    const long long NT = (long long)B_SZ * L_SZ;  // 131072 tokens
    char* ws = (char*)d_ws;
    float*  xin_g = (float*)ws;   ws += NT * 64 * 4;
    u32*    dtu_g = (u32*)ws;     ws += NT * 128 * 4;   // (dt fp16 | u bf16)
    float*  B_g   = (float*)ws;   ws += NT * 16 * 4;
    float*  C_g   = (float*)ws;   ws += NT * 16 * 4;
    u16*    sz_g  = (u16*)ws;     ws += NT * 128 * 2;
    float*  hl_ws  = (float*)ws;  ws += (long long)B_SZ * NCH * 2048 * 4;  // hl -> hin (in place)
    float*  sdt_ws = (float*)ws;  ws += (long long)B_SZ * NCH * 128 * 4;
    u16* Wf1 = (u16*)ws; ws += 4096 * 2;
    u16* Wf2 = (u16*)ws; ws += 16384 * 2;
    u16* Wf3 = (u16*)ws; ws += 6144 * 2;
    u16* Wf4 = (u16*)ws; ws += 8192 * 2;

    k_prep<<<1, 256, 0, stream>>>(W_in, in_proj, x_proj, Wout, Wf1, Wf2, Wf3, Wf4);

    k_frontend<<<dim3(L_SZ / CH, B_SZ), 256, 0, stream>>>(
        x, b_in, conv_w, conv_b, dt_w, dt_b, Wf1, Wf2, Wf3, A_log,
        xin_g, dtu_g, B_g, C_g, sz_g, hl_ws, sdt_ws);

    k_combine<<<B_SZ * 128, 256, 0, stream>>>(A_log, hl_ws, sdt_ws);

    k_backend<<<dim3(L_SZ / 64, B_SZ), 256, 0, stream>>>(
        dtu_g, B_g, C_g, sz_g, A_log, D_skip, hl_ws, xin_g,
        Wf4, gamma, beta, out);
}

// Round 9
// 292.655 us; speedup vs baseline: 1.2535x; 1.0086x over previous
//
#include <hip/hip_runtime.h>
#include <hip/hip_bf16.h>
#include <hip/hip_fp16.h>

#define B_SZ   16
#define L_SZ   8192
#define DM     64
#define DI     128
#define NCH    256      // scan sub-chunks (32 tokens each)
#define CLEN   32       // L_SZ / NCH
#define CH     64       // frontend tokens per block (= 2 sub-chunks)
#define RT     80       // padded rows (5 mtiles of 16; 67 used)
#define PA     72       // LDS pitch (u16) for 64-wide acts: 144B
#define PU     136      // LDS pitch (u16) for 128-wide acts: 272B
#define PC     132      // LDS pitch (u16) for conv input: 264B
#define LN_EPS 1e-3f

typedef float  f4 __attribute__((ext_vector_type(4)));
typedef float  f2 __attribute__((ext_vector_type(2)));
typedef short  s8 __attribute__((ext_vector_type(8)));
typedef unsigned short u16;
typedef unsigned int   u32;
#define MFMA16 __builtin_amdgcn_mfma_f32_16x16x32_bf16

__device__ __forceinline__ u16 f2bfu(float f) {
    u32 u = __float_as_uint(f);
    return (u16)((u + 0x7FFFu + ((u >> 16) & 1u)) >> 16);
}
__device__ __forceinline__ u32 pk2bf(float a, float b) {
    return (u32)f2bfu(a) | ((u32)f2bfu(b) << 16);
}
__device__ __forceinline__ float bflo(u32 u) { return __uint_as_float(u << 16); }
__device__ __forceinline__ float bfhi(u32 u) { return __uint_as_float(u & 0xFFFF0000u); }
__device__ __forceinline__ float bfu2f(u16 h) { return __uint_as_float((u32)h << 16); }
__device__ __forceinline__ float h2f(u32 lo16) {
    return __half2float(__ushort_as_half((u16)(lo16 & 0xFFFFu)));
}
__device__ __forceinline__ float fsig(float v) {
    return __builtin_amdgcn_rcpf(1.f + __expf(-v));
}
__device__ __forceinline__ float fsp(float v) {   // softplus
    return fmaxf(v, 0.f) + __logf(1.f + __expf(-fabsf(v)));
}

// ---------------- Weight prep: fragment-linear bf16 granules ----------------
__global__ __launch_bounds__(256) void k_prep(
    const float* __restrict__ W_in, const float* __restrict__ in_proj,
    const float* __restrict__ x_proj, const float* __restrict__ Wout,
    u16* __restrict__ Wf1, u16* __restrict__ Wf2,
    u16* __restrict__ Wf3, u16* __restrict__ Wf4)
{
    const int tid = threadIdx.x;
    for (int g = tid; g < 512; g += 256) {          // W_in: 4 nt x 2 ks
        int lane = g & 63, ks = (g >> 6) & 1, nt = g >> 7;
        int n = nt * 16 + (lane & 15), kb = ks * 32 + (lane >> 4) * 8;
        for (int j = 0; j < 8; j++) Wf1[g * 8 + j] = f2bfu(W_in[(kb + j) * 64 + n]);
    }
    for (int g = tid; g < 2048; g += 256) {         // in_proj: 16 nt x 2 ks
        int lane = g & 63, ks = (g >> 6) & 1, nt = g >> 7;
        int n = nt * 16 + (lane & 15), kb = ks * 32 + (lane >> 4) * 8;
        for (int j = 0; j < 8; j++) Wf2[g * 8 + j] = f2bfu(in_proj[(kb + j) * 256 + n]);
    }
    for (int g = tid; g < 768; g += 256) {          // x_proj (pad N 36->48): 3 nt x 4 ks
        int lane = g & 63, ks = (g >> 6) & 3, nt = g >> 8;
        int n = nt * 16 + (lane & 15), kb = ks * 32 + (lane >> 4) * 8;
        for (int j = 0; j < 8; j++)
            Wf3[g * 8 + j] = f2bfu(n < 36 ? x_proj[(kb + j) * 36 + n] : 0.f);
    }
    for (int g = tid; g < 1024; g += 256) {         // out_proj: 4 nt x 4 ks
        int lane = g & 63, ks = (g >> 6) & 3, nt = g >> 8;
        int n = nt * 16 + (lane & 15), kb = ks * 32 + (lane >> 4) * 8;
        for (int j = 0; j < 8; j++) Wf4[g * 8 + j] = f2bfu(Wout[(kb + j) * 64 + n]);
    }
}

// ---------------- Frontend + fused sub-chunk scan (scan1) ----------------
__global__ __launch_bounds__(256, 4) void k_frontend(
    const float* __restrict__ x, const float* __restrict__ b_in,
    const float* __restrict__ conv_w, const float* __restrict__ conv_b,
    const float* __restrict__ dt_w, const float* __restrict__ dt_b,
    const u16* __restrict__ Wf1, const u16* __restrict__ Wf2, const u16* __restrict__ Wf3,
    const float* __restrict__ A_log,
    float* __restrict__ xin_g, u32* __restrict__ dtu_g,
    float* __restrict__ B_g, float* __restrict__ C_g, u16* __restrict__ sz_g,
    float* __restrict__ hl_ws, float* __restrict__ sdt_ws)
{
    __shared__ __align__(16) char sm[40736];
    u16*   smA   = (u16*)sm;              // [80][72] x (bf16)
    u16*   smB   = (u16*)(sm + 11520);    // [80][72] xin
    u16*   smU   = (u16*)sm;              // [64][136] u (reuses smA/smB)
    float* smDtr = (float*)(sm + 17408);  // [64][4]
    float* smBf  = (float*)(sm + 18432);  // [64][16] B for scan
    u16*   smC   = (u16*)(sm + 23040);    // [67][132] xc
    u32*   smDt  = (u32*)(sm + 23040);    // [64][64] fp16 dt pairs, overlays dead smC

    const int tid = threadIdx.x;
    const int w = tid >> 6, lane = tid & 63;
    const int n16 = lane & 15, quad = lane >> 4;
    const int b = blockIdx.y, c0 = blockIdx.x * CH;
    const long long tokbase = (long long)b * L_SZ + c0;

    // P0: stage x rows (bf16), float4-vectorized
    for (int idx = tid; idx < RT * 16; idx += 256) {
        int r = idx >> 4, c4 = idx & 15;
        int l = c0 - 3 + r;
        float4 v = make_float4(0.f, 0.f, 0.f, 0.f);
        if (r < 67 && l >= 0)
            v = *(const float4*)(x + ((long long)b * L_SZ + l) * 64 + c4 * 4);
        *(uint2*)((char*)smA + r * 144 + c4 * 8) = make_uint2(pk2bf(v.x, v.y), pk2bf(v.z, v.w));
    }
    __syncthreads();

    // GEMM1: xin = x @ W_in + b_in
    {
        s8 b0 = *(const s8*)(Wf1 + ((w * 2 + 0) * 64 + lane) * 8);
        s8 b1 = *(const s8*)(Wf1 + ((w * 2 + 1) * 64 + lane) * 8);
        float bias = b_in[w * 16 + n16];
        for (int m = 0; m < 5; m++) {
            int ar = m * 16 + n16;
            s8 a0 = *(const s8*)(smA + ar * PA + quad * 8);
            s8 a1 = *(const s8*)(smA + ar * PA + 32 + quad * 8);
            f4 acc = {0.f, 0.f, 0.f, 0.f};
            acc = MFMA16(a0, b0, acc, 0, 0, 0);
            acc = MFMA16(a1, b1, acc, 0, 0, 0);
#pragma unroll
            for (int reg = 0; reg < 4; reg++) {
                int rr = m * 16 + quad * 4 + reg;
                float v = acc[reg] + bias;
                smB[rr * PA + w * 16 + n16] = f2bfu(v);
                if (rr >= 3 && rr < 67)
                    xin_g[(tokbase + rr - 3) * 64 + w * 16 + n16] = v;
            }
        }
    }
    __syncthreads();

    // GEMM2: xz = xin @ in_proj (waves 0-1 -> xc, waves 2-3 -> silu(z))
    {
        s8 bf[4][2];
#pragma unroll
        for (int i = 0; i < 4; i++)
#pragma unroll
            for (int ks = 0; ks < 2; ks++)
                bf[i][ks] = *(const s8*)(Wf2 + (((w * 4 + i) * 2 + ks) * 64 + lane) * 8);
        for (int m = 0; m < 5; m++) {
            int ar = m * 16 + n16;
            s8 a0 = *(const s8*)(smB + ar * PA + quad * 8);
            s8 a1 = *(const s8*)(smB + ar * PA + 32 + quad * 8);
#pragma unroll
            for (int i = 0; i < 4; i++) {
                f4 acc = {0.f, 0.f, 0.f, 0.f};
                acc = MFMA16(a0, bf[i][0], acc, 0, 0, 0);
                acc = MFMA16(a1, bf[i][1], acc, 0, 0, 0);
                int cg = (w * 4 + i) * 16 + n16;
#pragma unroll
                for (int reg = 0; reg < 4; reg++) {
                    int rr = m * 16 + quad * 4 + reg;
                    float v = acc[reg];
                    if (cg < 128) {                     // wave-uniform branch
                        if (rr < 67) {
                            int l = c0 - 3 + rr;
                            smC[rr * PC + cg] = f2bfu(l >= 0 ? v : 0.f);
                        }
                    } else if (rr >= 3 && rr < 67) {
                        sz_g[(tokbase + rr - 3) * 128 + (cg - 128)] = f2bfu(v * fsig(v));
                    }
                }
            }
        }
    }
    __syncthreads();

    // conv(4) + silu -> u (LDS only)
    {
        const int d2 = lane * 2, ctb = w * 16;
        float4 cw0 = ((const float4*)conv_w)[d2];
        float4 cw1 = ((const float4*)conv_w)[d2 + 1];
        float cb0 = conv_b[d2], cb1 = conv_b[d2 + 1];
        u32 r0 = *(const u32*)((char*)smC + (ctb + 0) * 264 + lane * 4);
        u32 r1 = *(const u32*)((char*)smC + (ctb + 1) * 264 + lane * 4);
        u32 r2 = *(const u32*)((char*)smC + (ctb + 2) * 264 + lane * 4);
#pragma unroll 4
        for (int j = 0; j < 16; j++) {
            int ct = ctb + j;
            u32 r3 = *(const u32*)((char*)smC + (ct + 3) * 264 + lane * 4);
            float v0 = cb0 + bflo(r0) * cw0.x + bflo(r1) * cw0.y + bflo(r2) * cw0.z + bflo(r3) * cw0.w;
            float v1 = cb1 + bfhi(r0) * cw1.x + bfhi(r1) * cw1.y + bfhi(r2) * cw1.z + bfhi(r3) * cw1.w;
            u32 pk = pk2bf(v0 * fsig(v0), v1 * fsig(v1));
            *(u32*)(smU + ct * PU + d2) = pk;
            r0 = r1; r1 = r2; r2 = r3;
        }
    }
    __syncthreads();

    // GEMM3: dbc = u @ x_proj  (M=64, N=48(36), K=128); wave w -> mtile w
    {
        s8 bf3[3][4];
#pragma unroll
        for (int nt = 0; nt < 3; nt++)
#pragma unroll
            for (int ks = 0; ks < 4; ks++)
                bf3[nt][ks] = *(const s8*)(Wf3 + ((nt * 4 + ks) * 64 + lane) * 8);
        f4 acc[3] = {{0.f,0.f,0.f,0.f},{0.f,0.f,0.f,0.f},{0.f,0.f,0.f,0.f}};
        int ar = w * 16 + n16;
#pragma unroll
        for (int ks = 0; ks < 4; ks++) {
            s8 a = *(const s8*)(smU + ar * PU + ks * 32 + quad * 8);
#pragma unroll
            for (int nt = 0; nt < 3; nt++) acc[nt] = MFMA16(a, bf3[nt][ks], acc[nt], 0, 0, 0);
        }
#pragma unroll
        for (int nt = 0; nt < 3; nt++) {
            int c = nt * 16 + n16;
#pragma unroll
            for (int reg = 0; reg < 4; reg++) {
                int rr = w * 16 + quad * 4 + reg;
                float v = acc[nt][reg];
                long long t = tokbase + rr;
                if (c < 4)       smDtr[rr * 4 + c] = v;
                else if (c < 20) { B_g[t * 16 + (c - 4)] = v; smBf[rr * 16 + (c - 4)] = v; }
                else if (c < 36) C_g[t * 16 + (c - 20)] = v;
            }
        }
    }
    __syncthreads();   // smC dead; smDt region now writable

    // dt = softplus(dtr @ dt_proj_w + dt_proj_b); fp16 pair -> smDt; packed (dt|u) -> global
    {
        const int o2 = lane * 2, grp = w;
        float w00 = dt_w[o2],       w01 = dt_w[o2 + 1];
        float w10 = dt_w[128 + o2], w11 = dt_w[128 + o2 + 1];
        float w20 = dt_w[256 + o2], w21 = dt_w[256 + o2 + 1];
        float w30 = dt_w[384 + o2], w31 = dt_w[384 + o2 + 1];
        float b0 = dt_b[o2], b1 = dt_b[o2 + 1];
#pragma unroll 4
        for (int j = 0; j < 16; j++) {
            int ct = grp * 16 + j;
            float4 q = *(const float4*)(smDtr + ct * 4);
            float v0 = b0 + q.x * w00 + q.y * w10 + q.z * w20 + q.w * w30;
            float v1 = b1 + q.x * w01 + q.y * w11 + q.z * w21 + q.w * w31;
            u32 hpk = (u32)__half_as_ushort(__float2half_rn(fsp(v0))) |
                      ((u32)__half_as_ushort(__float2half_rn(fsp(v1))) << 16);
            smDt[ct * 64 + lane] = hpk;
            u32 upk = *(const u32*)(smU + ct * PU + o2);
            u32 pk0 = (hpk & 0xFFFFu) | (upk << 16);
            u32 pk1 = (hpk >> 16) | (upk & 0xFFFF0000u);
            *(uint2*)(dtu_g + (tokbase + ct) * 128 + o2) = make_uint2(pk0, pk1);
        }
    }
    __syncthreads();

    // Fused sub-chunk scan: 1 thread per (sub-chunk, channel), 16 states, 32 tokens.
    // Packed dual-FP32 (v_pk_fma_f32) state update.
    {
        const int d = tid & 127, cs = tid >> 7;
        const int j2 = d >> 1, hi = d & 1;
        float A[16];
#pragma unroll
        for (int s = 0; s < 16; s++) A[s] = -__expf(A_log[d * 16 + s]);
        const float A0 = A[0];
        bool chain = true;
#pragma unroll
        for (int s = 1; s < 16; s++)
            chain = chain && (fabsf(A[s] - (float)(s + 1) * A0) <= 1e-4f * fabsf(A[s]));

        float sdt = 0.f;
        f2 hh[8];
#pragma unroll
        for (int k = 0; k < 8; k++) hh[k] = f2{0.f, 0.f};

        if (chain) {
            for (int i = 0; i < CLEN; i++) {
                int t = cs * CLEN + i;
                u32 qq = smDt[t * 64 + j2];
                float dtv = __half2float(__ushort_as_half((u16)(hi ? (qq >> 16) : (qq & 0xFFFFu))));
                float uv  = bfu2f(smU[t * PU + d]);
                float duv = dtv * uv;  sdt += dtv;
                f2 du2 = {duv, duv};
                float4 B0 = *(const float4*)(smBf + t * 16);
                float4 B1 = *(const float4*)(smBf + t * 16 + 4);
                float4 B2 = *(const float4*)(smBf + t * 16 + 8);
                float4 B3 = *(const float4*)(smBf + t * 16 + 12);
                f2 bb[8] = {{B0.x,B0.y},{B0.z,B0.w},{B1.x,B1.y},{B1.z,B1.w},
                            {B2.x,B2.y},{B2.z,B2.w},{B3.x,B3.y},{B3.z,B3.w}};
                float p = __expf(dtv * A0);
                float q = p * p, q2v = q * q, q4v = q2v * q2v;
                f2 vq = {q,q}, vq2 = {q2v,q2v}, vq4 = {q4v,q4v};
                f2 m[8];
                m[0] = f2{p, q};
                m[1] = m[0] * vq;  m[2] = m[0] * vq2; m[3] = m[1] * vq2;
                m[4] = m[0] * vq4; m[5] = m[1] * vq4; m[6] = m[2] * vq4; m[7] = m[3] * vq4;
#pragma unroll
                for (int k = 0; k < 8; k++)
                    hh[k] = m[k] * hh[k] + du2 * bb[k];
            }
        } else {
            for (int i = 0; i < CLEN; i++) {
                int t = cs * CLEN + i;
                u32 qq = smDt[t * 64 + j2];
                float dtv = __half2float(__ushort_as_half((u16)(hi ? (qq >> 16) : (qq & 0xFFFFu))));
                float uv  = bfu2f(smU[t * PU + d]);
                float duv = dtv * uv;  sdt += dtv;
                const float* Bp = smBf + t * 16;
#pragma unroll
                for (int k = 0; k < 8; k++) {
                    hh[k].x = __expf(dtv * A[2*k])   * hh[k].x + duv * Bp[2*k];
                    hh[k].y = __expf(dtv * A[2*k+1]) * hh[k].y + duv * Bp[2*k+1];
                }
            }
        }

        const int ch = blockIdx.x * 2 + cs;
        float4* hp4 = (float4*)(hl_ws + (((long long)b * NCH + ch) * 128 + d) * 16);
        hp4[0] = make_float4(hh[0].x, hh[0].y, hh[1].x, hh[1].y);
        hp4[1] = make_float4(hh[2].x, hh[2].y, hh[3].x, hh[3].y);
        hp4[2] = make_float4(hh[4].x, hh[4].y, hh[5].x, hh[5].y);
        hp4[3] = make_float4(hh[6].x, hh[6].y, hh[7].x, hh[7].y);
        sdt_ws[((long long)b * NCH + ch) * 128 + d] = sdt;
    }
}

// ---------------- Hierarchical chunk-boundary combine (in-place: hl -> hin) ----------------
__global__ __launch_bounds__(256) void k_combine(
    const float* __restrict__ A_log, float* __restrict__ hl_ws,
    const float* __restrict__ sdt_ws)
{
    __shared__ float sH[16 * 16];   // [seg][s] segment-end h
    __shared__ float sCT[16];       // segment total sum(dt)
    const int tid = threadIdx.x;
    const int s = tid & 15, seg = tid >> 4;
    const int bd = blockIdx.x;      // b*128 + d
    const int b = bd >> 7, d = bd & 127;
    const float A = -__expf(A_log[d * 16 + s]);

    const long long base  = ((long long)b * NCH + seg * 16) * 2048 + d * 16 + s;
    const long long sbase = ((long long)b * NCH + seg * 16) * 128 + d;

    // phase 1: local scan over this segment's 16 chunks (regs, static idx)
    float hinL[16], cum[16];
    float h = 0.f, csum = 0.f;
#pragma unroll
    for (int j = 0; j < 16; j++) {
        float v   = hl_ws[base + (long long)j * 2048];
        float sdt = sdt_ws[sbase + j * 128];
        hinL[j] = h;  cum[j] = csum;
        h = __expf(A * sdt) * h + v;
        csum += sdt;
    }
    sH[seg * 16 + s] = h;
    if (s == 0) sCT[seg] = csum;
    __syncthreads();

    // phase 2: scan over preceding segments (LDS broadcast reads)
    float hseg = 0.f;
    for (int k = 0; k < seg; k++)
        hseg = __expf(A * sCT[k]) * hseg + sH[k * 16 + s];

    // phase 3: fixup + in-place write (each address owned by exactly one thread)
#pragma unroll
    for (int j = 0; j < 16; j++)
        hl_ws[base + (long long)j * 2048] = hinL[j] + __expf(A * cum[j]) * hseg;
}

// ---------------- Backend: packed-FP32 scan + epilogue, smR overlays sy ----------------
__global__ __launch_bounds__(256, 8) void k_backend(
    const u32* __restrict__ dtu_g, const float* __restrict__ B_g,
    const float* __restrict__ C_g, const u16* __restrict__ sz_g,
    const float* __restrict__ A_log, const float* __restrict__ D_skip,
    const float* __restrict__ hin_ws, const float* __restrict__ xin_g,
    const u16* __restrict__ Wf4, const float* __restrict__ gamma,
    const float* __restrict__ beta, float* __restrict__ out)
{
    __shared__ __align__(16) char sm[17408];
    u16*   sy   = (u16*)sm;               // [64][136] bf16 y
    float* smR  = (float*)sm;             // [64][65] f32, overlays sy after MFMA reads

    const int tid = threadIdx.x;
    const int cb = blockIdx.x, b = blockIdx.y;   // 64-token tile
    const long long tok0 = (long long)b * L_SZ + (long long)cb * 64;

    // ---- scan: 1 thread per (half, channel), 16 states (f2 x8), 32 tokens ----
    {
        const int d = tid & 127, half = tid >> 7;
        float A[16];
#pragma unroll
        for (int s = 0; s < 16; s++) A[s] = -__expf(A_log[d * 16 + s]);
        const float A0 = A[0];
        bool chain = true;
#pragma unroll
        for (int s = 1; s < 16; s++)
            chain = chain && (fabsf(A[s] - (float)(s + 1) * A0) <= 1e-4f * fabsf(A[s]));

        f2 hh[8];
        {
            const float4* hp = (const float4*)(hin_ws +
                (((long long)b * NCH + 2 * cb + half) * 128 + d) * 16);
            float4 ha = hp[0], hb = hp[1], hc = hp[2], hd = hp[3];
            hh[0] = f2{ha.x, ha.y}; hh[1] = f2{ha.z, ha.w};
            hh[2] = f2{hb.x, hb.y}; hh[3] = f2{hb.z, hb.w};
            hh[4] = f2{hc.x, hc.y}; hh[5] = f2{hc.z, hc.w};
            hh[6] = f2{hd.x, hd.y}; hh[7] = f2{hd.z, hd.w};
        }
        const float Dv = D_skip[d];

        if (chain) {
            for (int i = 0; i < CLEN; i++) {
                int t = half * CLEN + i;
                u32 pk = dtu_g[(tok0 + t) * 128 + d];
                float dtv = h2f(pk);
                float uv  = bfhi(pk);
                float duv = dtv * uv;
                f2 du2 = {duv, duv};
                const float4* Bp = (const float4*)(B_g + (tok0 + t) * 16);
                float4 B0 = Bp[0], B1 = Bp[1], B2 = Bp[2], B3 = Bp[3];
                const float4* Cp = (const float4*)(C_g + (tok0 + t) * 16);
                float4 C0 = Cp[0], C1 = Cp[1], C2 = Cp[2], C3 = Cp[3];
                f2 bb[8] = {{B0.x,B0.y},{B0.z,B0.w},{B1.x,B1.y},{B1.z,B1.w},
                            {B2.x,B2.y},{B2.z,B2.w},{B3.x,B3.y},{B3.z,B3.w}};
                f2 cc[8] = {{C0.x,C0.y},{C0.z,C0.w},{C1.x,C1.y},{C1.z,C1.w},
                            {C2.x,C2.y},{C2.z,C2.w},{C3.x,C3.y},{C3.z,C3.w}};
                float p = __expf(dtv * A0);
                float q = p * p, q2v = q * q, q4v = q2v * q2v;
                f2 vq = {q,q}, vq2 = {q2v,q2v}, vq4 = {q4v,q4v};
                f2 m[8];
                m[0] = f2{p, q};
                m[1] = m[0] * vq;  m[2] = m[0] * vq2; m[3] = m[1] * vq2;
                m[4] = m[0] * vq4; m[5] = m[1] * vq4; m[6] = m[2] * vq4; m[7] = m[3] * vq4;
                f2 ys2 = {0.f, 0.f};
#pragma unroll
                for (int k = 0; k < 8; k++) {
                    hh[k] = m[k] * hh[k] + du2 * bb[k];
                    ys2 = hh[k] * cc[k] + ys2;
                }
                float ys = ys2.x + ys2.y;
                float szv = bfu2f(sz_g[(tok0 + t) * 128 + d]);
                sy[t * PU + d] = f2bfu((ys + uv * Dv) * szv);
            }
        } else {
            for (int i = 0; i < CLEN; i++) {
                int t = half * CLEN + i;
                u32 pk = dtu_g[(tok0 + t) * 128 + d];
                float dtv = h2f(pk);
                float uv  = bfhi(pk);
                float duv = dtv * uv;
                const float* Bp = (const float*)(B_g + (tok0 + t) * 16);
                const float* Cp = (const float*)(C_g + (tok0 + t) * 16);
                float ys = 0.f;
#pragma unroll
                for (int k = 0; k < 8; k++) {
                    hh[k].x = __expf(dtv * A[2*k])   * hh[k].x + duv * Bp[2*k];
                    hh[k].y = __expf(dtv * A[2*k+1]) * hh[k].y + duv * Bp[2*k+1];
                    ys += hh[k].x * Cp[2*k] + hh[k].y * Cp[2*k+1];
                }
                float szv = bfu2f(sz_g[(tok0 + t) * 128 + d]);
                sy[t * PU + d] = f2bfu((ys + uv * Dv) * szv);
            }
        }
    }
    __syncthreads();   // sy complete

    // ---- epilogue: out = LN(y @ out_proj + xin); accs in regs, then smR overlays sy ----
    const int w = tid >> 6, lane = tid & 63;
    const int n16 = lane & 15, quad = lane >> 4;
    f4 accm[4];
    {
        s8 bf[4];
#pragma unroll
        for (int ks = 0; ks < 4; ks++)
            bf[ks] = *(const s8*)(Wf4 + ((w * 4 + ks) * 64 + lane) * 8);
#pragma unroll
        for (int m = 0; m < 4; m++) {
            int ar = m * 16 + n16;
            f4 acc = {0.f, 0.f, 0.f, 0.f};
#pragma unroll
            for (int ks = 0; ks < 4; ks++) {
                s8 a = *(const s8*)(sy + ar * PU + ks * 32 + quad * 8);
                acc = MFMA16(a, bf[ks], acc, 0, 0, 0);
            }
            accm[m] = acc;
        }
    }
    __syncthreads();   // all sy reads done; region now writable as smR

    {
#pragma unroll
        for (int m = 0; m < 4; m++)
#pragma unroll
            for (int reg = 0; reg < 4; reg++) {
                int rr = m * 16 + quad * 4 + reg;
                smR[rr * 65 + w * 16 + n16] = accm[m][reg];
            }
    }
    __syncthreads();

    {
        int o = tid & 63, wv = tid >> 6;
        float g = gamma[o], bb = beta[o];
        for (int j = 0; j < 16; j++) {
            int rr = wv * 16 + j;
            float r = smR[rr * 65 + o] + xin_g[(tok0 + rr) * 64 + o];
            float s = r;
#pragma unroll
            for (int mS = 0; mS < 6; mS++) s += __shfl_xor(s, 1 << mS, 64);
            float mu = s * (1.f / 64.f);
            float dv = r - mu;
            float vs = dv * dv;
#pragma unroll
            for (int mS = 0; mS < 6; mS++) vs += __shfl_xor(vs, 1 << mS, 64);
            out[(tok0 + rr) * 64 + o] = g * dv * rsqrtf(vs * (1.f / 64.f) + LN_EPS) + bb;
        }
    }
}

extern "C" void kernel_launch(void* const* d_in, const int* in_sizes, int n_in,
                              void* d_out, int out_size, void* d_ws, size_t ws_size,
                              hipStream_t stream)
{
    const float* x       = (const float*)d_in[0];
    const float* W_in    = (const float*)d_in[1];
    const float* b_in    = (const float*)d_in[2];
    const float* in_proj = (const float*)d_in[3];
    const float* conv_w  = (const float*)d_in[4];
    const float* conv_b  = (const float*)d_in[5];
    const float* x_proj  = (const float*)d_in[6];
    const float* dt_w    = (const float*)d_in[7];
    const float* dt_b    = (const float*)d_in[8];
    const float* A_log   = (const float*)d_in[9];
    const float* D_skip  = (const float*)d_in[10];
    const float* Wout    = (const float*)d_in[11];
    const float* gamma   = (const float*)d_in[12];
    const float* beta    = (const float*)d_in[13];
    float* out = (float*)d_out;

    const long long NT = (long long)B_SZ * L_SZ;  // 131072 tokens
    char* ws = (char*)d_ws;
    float*  xin_g = (float*)ws;   ws += NT * 64 * 4;
    u32*    dtu_g = (u32*)ws;     ws += NT * 128 * 4;   // (dt fp16 | u bf16)
    float*  B_g   = (float*)ws;   ws += NT * 16 * 4;
    float*  C_g   = (float*)ws;   ws += NT * 16 * 4;
    u16*    sz_g  = (u16*)ws;     ws += NT * 128 * 2;
    float*  hl_ws  = (float*)ws;  ws += (long long)B_SZ * NCH * 2048 * 4;  // hl -> hin (in place)
    float*  sdt_ws = (float*)ws;  ws += (long long)B_SZ * NCH * 128 * 4;
    u16* Wf1 = (u16*)ws; ws += 4096 * 2;
    u16* Wf2 = (u16*)ws; ws += 16384 * 2;
    u16* Wf3 = (u16*)ws; ws += 6144 * 2;
    u16* Wf4 = (u16*)ws; ws += 8192 * 2;

    k_prep<<<1, 256, 0, stream>>>(W_in, in_proj, x_proj, Wout, Wf1, Wf2, Wf3, Wf4);

    k_frontend<<<dim3(L_SZ / CH, B_SZ), 256, 0, stream>>>(
        x, b_in, conv_w, conv_b, dt_w, dt_b, Wf1, Wf2, Wf3, A_log,
        xin_g, dtu_g, B_g, C_g, sz_g, hl_ws, sdt_ws);

    k_combine<<<B_SZ * 128, 256, 0, stream>>>(A_log, hl_ws, sdt_ws);

    k_backend<<<dim3(L_SZ / 64, B_SZ), 256, 0, stream>>>(
        dtu_g, B_g, C_g, sz_g, A_log, D_skip, hl_ws, xin_g,
        Wf4, gamma, beta, out);
}

// Round 10
// 253.909 us; speedup vs baseline: 1.4448x; 1.1526x over previous
//
#include <hip/hip_runtime.h>
#include <hip/hip_bf16.h>
#include <hip/hip_fp16.h>

#define B_SZ   16
#define L_SZ   8192
#define DM     64
#define DI     128
#define NCH    256      // scan sub-chunks (32 tokens each)
#define CLEN   32       // L_SZ / NCH
#define CH     64       // frontend tokens per block (= 2 sub-chunks)
#define RT     80       // padded rows (5 mtiles of 16; 67 used)
#define PA     72       // LDS pitch (u16) for 64-wide acts: 144B
#define PU     136      // LDS pitch (u16) for 128-wide acts: 272B
#define PC     132      // LDS pitch (u16) for conv input: 264B
#define LN_EPS 1e-3f

typedef float  f4 __attribute__((ext_vector_type(4)));
typedef float  f2 __attribute__((ext_vector_type(2)));
typedef short  s8 __attribute__((ext_vector_type(8)));
typedef unsigned short u16;
typedef unsigned int   u32;
#define MFMA16 __builtin_amdgcn_mfma_f32_16x16x32_bf16

__device__ __forceinline__ u16 f2bfu(float f) {
    u32 u = __float_as_uint(f);
    return (u16)((u + 0x7FFFu + ((u >> 16) & 1u)) >> 16);
}
__device__ __forceinline__ u32 pk2bf(float a, float b) {
    return (u32)f2bfu(a) | ((u32)f2bfu(b) << 16);
}
__device__ __forceinline__ float bflo(u32 u) { return __uint_as_float(u << 16); }
__device__ __forceinline__ float bfhi(u32 u) { return __uint_as_float(u & 0xFFFF0000u); }
__device__ __forceinline__ float bfu2f(u16 h) { return __uint_as_float((u32)h << 16); }
__device__ __forceinline__ float h2f(u32 lo16) {
    return __half2float(__ushort_as_half((u16)(lo16 & 0xFFFFu)));
}
__device__ __forceinline__ float fsig(float v) {
    return __builtin_amdgcn_rcpf(1.f + __expf(-v));
}
__device__ __forceinline__ float fsp(float v) {   // softplus
    return fmaxf(v, 0.f) + __logf(1.f + __expf(-fabsf(v)));
}

// ---------------- Weight prep: fragment-linear bf16 granules ----------------
__global__ __launch_bounds__(256) void k_prep(
    const float* __restrict__ W_in, const float* __restrict__ in_proj,
    const float* __restrict__ x_proj, const float* __restrict__ Wout,
    u16* __restrict__ Wf1, u16* __restrict__ Wf2,
    u16* __restrict__ Wf3, u16* __restrict__ Wf4)
{
    const int tid = threadIdx.x;
    for (int g = tid; g < 512; g += 256) {          // W_in: 4 nt x 2 ks
        int lane = g & 63, ks = (g >> 6) & 1, nt = g >> 7;
        int n = nt * 16 + (lane & 15), kb = ks * 32 + (lane >> 4) * 8;
        for (int j = 0; j < 8; j++) Wf1[g * 8 + j] = f2bfu(W_in[(kb + j) * 64 + n]);
    }
    for (int g = tid; g < 2048; g += 256) {         // in_proj: 16 nt x 2 ks
        int lane = g & 63, ks = (g >> 6) & 1, nt = g >> 7;
        int n = nt * 16 + (lane & 15), kb = ks * 32 + (lane >> 4) * 8;
        for (int j = 0; j < 8; j++) Wf2[g * 8 + j] = f2bfu(in_proj[(kb + j) * 256 + n]);
    }
    for (int g = tid; g < 768; g += 256) {          // x_proj (pad N 36->48): 3 nt x 4 ks
        int lane = g & 63, ks = (g >> 6) & 3, nt = g >> 8;
        int n = nt * 16 + (lane & 15), kb = ks * 32 + (lane >> 4) * 8;
        for (int j = 0; j < 8; j++)
            Wf3[g * 8 + j] = f2bfu(n < 36 ? x_proj[(kb + j) * 36 + n] : 0.f);
    }
    for (int g = tid; g < 1024; g += 256) {         // out_proj: 4 nt x 4 ks
        int lane = g & 63, ks = (g >> 6) & 3, nt = g >> 8;
        int n = nt * 16 + (lane & 15), kb = ks * 32 + (lane >> 4) * 8;
        for (int j = 0; j < 8; j++) Wf4[g * 8 + j] = f2bfu(Wout[(kb + j) * 64 + n]);
    }
}

// ---------------- Frontend + fused sub-chunk scan (scan1) ----------------
__global__ __launch_bounds__(256, 4) void k_frontend(
    const float* __restrict__ x, const float* __restrict__ b_in,
    const float* __restrict__ conv_w, const float* __restrict__ conv_b,
    const float* __restrict__ dt_w, const float* __restrict__ dt_b,
    const u16* __restrict__ Wf1, const u16* __restrict__ Wf2, const u16* __restrict__ Wf3,
    const float* __restrict__ A_log,
    float* __restrict__ xin_g, u32* __restrict__ dtu_g,
    float* __restrict__ B_g, float* __restrict__ C_g, u16* __restrict__ sz_g,
    float* __restrict__ hl_ws, float* __restrict__ sdt_ws)
{
    __shared__ __align__(16) char sm[40736];
    u16*   smA   = (u16*)sm;              // [80][72] x (bf16)
    u16*   smB   = (u16*)(sm + 11520);    // [80][72] xin
    u16*   smU   = (u16*)sm;              // [64][136] u (reuses smA/smB)
    float* smDtr = (float*)(sm + 17408);  // [64][4]
    float* smBf  = (float*)(sm + 18432);  // [64][16] B for scan
    u16*   smC   = (u16*)(sm + 23040);    // [67][132] xc
    u32*   smDt  = (u32*)(sm + 23040);    // [64][64] fp16 dt pairs, overlays dead smC

    const int tid = threadIdx.x;
    const int w = tid >> 6, lane = tid & 63;
    const int n16 = lane & 15, quad = lane >> 4;
    const int b = blockIdx.y, c0 = blockIdx.x * CH;
    const long long tokbase = (long long)b * L_SZ + c0;

    // P0: stage x rows (bf16), float4-vectorized
    for (int idx = tid; idx < RT * 16; idx += 256) {
        int r = idx >> 4, c4 = idx & 15;
        int l = c0 - 3 + r;
        float4 v = make_float4(0.f, 0.f, 0.f, 0.f);
        if (r < 67 && l >= 0)
            v = *(const float4*)(x + ((long long)b * L_SZ + l) * 64 + c4 * 4);
        *(uint2*)((char*)smA + r * 144 + c4 * 8) = make_uint2(pk2bf(v.x, v.y), pk2bf(v.z, v.w));
    }
    __syncthreads();

    // GEMM1: xin = x @ W_in + b_in
    {
        s8 b0 = *(const s8*)(Wf1 + ((w * 2 + 0) * 64 + lane) * 8);
        s8 b1 = *(const s8*)(Wf1 + ((w * 2 + 1) * 64 + lane) * 8);
        float bias = b_in[w * 16 + n16];
        for (int m = 0; m < 5; m++) {
            int ar = m * 16 + n16;
            s8 a0 = *(const s8*)(smA + ar * PA + quad * 8);
            s8 a1 = *(const s8*)(smA + ar * PA + 32 + quad * 8);
            f4 acc = {0.f, 0.f, 0.f, 0.f};
            acc = MFMA16(a0, b0, acc, 0, 0, 0);
            acc = MFMA16(a1, b1, acc, 0, 0, 0);
#pragma unroll
            for (int reg = 0; reg < 4; reg++) {
                int rr = m * 16 + quad * 4 + reg;
                float v = acc[reg] + bias;
                smB[rr * PA + w * 16 + n16] = f2bfu(v);
                if (rr >= 3 && rr < 67)
                    xin_g[(tokbase + rr - 3) * 64 + w * 16 + n16] = v;
            }
        }
    }
    __syncthreads();

    // GEMM2: xz = xin @ in_proj (waves 0-1 -> xc, waves 2-3 -> silu(z))
    {
        s8 bf[4][2];
#pragma unroll
        for (int i = 0; i < 4; i++)
#pragma unroll
            for (int ks = 0; ks < 2; ks++)
                bf[i][ks] = *(const s8*)(Wf2 + (((w * 4 + i) * 2 + ks) * 64 + lane) * 8);
        for (int m = 0; m < 5; m++) {
            int ar = m * 16 + n16;
            s8 a0 = *(const s8*)(smB + ar * PA + quad * 8);
            s8 a1 = *(const s8*)(smB + ar * PA + 32 + quad * 8);
#pragma unroll
            for (int i = 0; i < 4; i++) {
                f4 acc = {0.f, 0.f, 0.f, 0.f};
                acc = MFMA16(a0, bf[i][0], acc, 0, 0, 0);
                acc = MFMA16(a1, bf[i][1], acc, 0, 0, 0);
                int cg = (w * 4 + i) * 16 + n16;
#pragma unroll
                for (int reg = 0; reg < 4; reg++) {
                    int rr = m * 16 + quad * 4 + reg;
                    float v = acc[reg];
                    if (cg < 128) {                     // wave-uniform branch
                        if (rr < 67) {
                            int l = c0 - 3 + rr;
                            smC[rr * PC + cg] = f2bfu(l >= 0 ? v : 0.f);
                        }
                    } else if (rr >= 3 && rr < 67) {
                        sz_g[(tokbase + rr - 3) * 128 + (cg - 128)] = f2bfu(v * fsig(v));
                    }
                }
            }
        }
    }
    __syncthreads();

    // conv(4) + silu -> u (LDS only)
    {
        const int d2 = lane * 2, ctb = w * 16;
        float4 cw0 = ((const float4*)conv_w)[d2];
        float4 cw1 = ((const float4*)conv_w)[d2 + 1];
        float cb0 = conv_b[d2], cb1 = conv_b[d2 + 1];
        u32 r0 = *(const u32*)((char*)smC + (ctb + 0) * 264 + lane * 4);
        u32 r1 = *(const u32*)((char*)smC + (ctb + 1) * 264 + lane * 4);
        u32 r2 = *(const u32*)((char*)smC + (ctb + 2) * 264 + lane * 4);
#pragma unroll 4
        for (int j = 0; j < 16; j++) {
            int ct = ctb + j;
            u32 r3 = *(const u32*)((char*)smC + (ct + 3) * 264 + lane * 4);
            float v0 = cb0 + bflo(r0) * cw0.x + bflo(r1) * cw0.y + bflo(r2) * cw0.z + bflo(r3) * cw0.w;
            float v1 = cb1 + bfhi(r0) * cw1.x + bfhi(r1) * cw1.y + bfhi(r2) * cw1.z + bfhi(r3) * cw1.w;
            u32 pk = pk2bf(v0 * fsig(v0), v1 * fsig(v1));
            *(u32*)(smU + ct * PU + d2) = pk;
            r0 = r1; r1 = r2; r2 = r3;
        }
    }
    __syncthreads();

    // GEMM3: dbc = u @ x_proj  (M=64, N=48(36), K=128); wave w -> mtile w
    {
        s8 bf3[3][4];
#pragma unroll
        for (int nt = 0; nt < 3; nt++)
#pragma unroll
            for (int ks = 0; ks < 4; ks++)
                bf3[nt][ks] = *(const s8*)(Wf3 + ((nt * 4 + ks) * 64 + lane) * 8);
        f4 acc[3] = {{0.f,0.f,0.f,0.f},{0.f,0.f,0.f,0.f},{0.f,0.f,0.f,0.f}};
        int ar = w * 16 + n16;
#pragma unroll
        for (int ks = 0; ks < 4; ks++) {
            s8 a = *(const s8*)(smU + ar * PU + ks * 32 + quad * 8);
#pragma unroll
            for (int nt = 0; nt < 3; nt++) acc[nt] = MFMA16(a, bf3[nt][ks], acc[nt], 0, 0, 0);
        }
#pragma unroll
        for (int nt = 0; nt < 3; nt++) {
            int c = nt * 16 + n16;
#pragma unroll
            for (int reg = 0; reg < 4; reg++) {
                int rr = w * 16 + quad * 4 + reg;
                float v = acc[nt][reg];
                long long t = tokbase + rr;
                if (c < 4)       smDtr[rr * 4 + c] = v;
                else if (c < 20) { B_g[t * 16 + (c - 4)] = v; smBf[rr * 16 + (c - 4)] = v; }
                else if (c < 36) C_g[t * 16 + (c - 20)] = v;
            }
        }
    }
    __syncthreads();   // smC dead; smDt region now writable

    // dt = softplus(dtr @ dt_proj_w + dt_proj_b); fp16 pair -> smDt; packed (dt|u) -> global
    {
        const int o2 = lane * 2, grp = w;
        float w00 = dt_w[o2],       w01 = dt_w[o2 + 1];
        float w10 = dt_w[128 + o2], w11 = dt_w[128 + o2 + 1];
        float w20 = dt_w[256 + o2], w21 = dt_w[256 + o2 + 1];
        float w30 = dt_w[384 + o2], w31 = dt_w[384 + o2 + 1];
        float b0 = dt_b[o2], b1 = dt_b[o2 + 1];
#pragma unroll 4
        for (int j = 0; j < 16; j++) {
            int ct = grp * 16 + j;
            float4 q = *(const float4*)(smDtr + ct * 4);
            float v0 = b0 + q.x * w00 + q.y * w10 + q.z * w20 + q.w * w30;
            float v1 = b1 + q.x * w01 + q.y * w11 + q.z * w21 + q.w * w31;
            u32 hpk = (u32)__half_as_ushort(__float2half_rn(fsp(v0))) |
                      ((u32)__half_as_ushort(__float2half_rn(fsp(v1))) << 16);
            smDt[ct * 64 + lane] = hpk;
            u32 upk = *(const u32*)(smU + ct * PU + o2);
            u32 pk0 = (hpk & 0xFFFFu) | (upk << 16);
            u32 pk1 = (hpk >> 16) | (upk & 0xFFFF0000u);
            *(uint2*)(dtu_g + (tokbase + ct) * 128 + o2) = make_uint2(pk0, pk1);
        }
    }
    __syncthreads();

    // Fused sub-chunk scan: 1 thread per (sub-chunk, channel), 16 states, 32 tokens.
    // Packed dual-FP32 (v_pk_fma_f32) state update.
    {
        const int d = tid & 127, cs = tid >> 7;
        const int j2 = d >> 1, hi = d & 1;
        float A[16];
#pragma unroll
        for (int s = 0; s < 16; s++) A[s] = -__expf(A_log[d * 16 + s]);
        const float A0 = A[0];
        bool chain = true;
#pragma unroll
        for (int s = 1; s < 16; s++)
            chain = chain && (fabsf(A[s] - (float)(s + 1) * A0) <= 1e-4f * fabsf(A[s]));

        float sdt = 0.f;
        f2 hh[8];
#pragma unroll
        for (int k = 0; k < 8; k++) hh[k] = f2{0.f, 0.f};

        if (chain) {
            for (int i = 0; i < CLEN; i++) {
                int t = cs * CLEN + i;
                u32 qq = smDt[t * 64 + j2];
                float dtv = __half2float(__ushort_as_half((u16)(hi ? (qq >> 16) : (qq & 0xFFFFu))));
                float uv  = bfu2f(smU[t * PU + d]);
                float duv = dtv * uv;  sdt += dtv;
                f2 du2 = {duv, duv};
                float4 B0 = *(const float4*)(smBf + t * 16);
                float4 B1 = *(const float4*)(smBf + t * 16 + 4);
                float4 B2 = *(const float4*)(smBf + t * 16 + 8);
                float4 B3 = *(const float4*)(smBf + t * 16 + 12);
                f2 bb[8] = {{B0.x,B0.y},{B0.z,B0.w},{B1.x,B1.y},{B1.z,B1.w},
                            {B2.x,B2.y},{B2.z,B2.w},{B3.x,B3.y},{B3.z,B3.w}};
                float p = __expf(dtv * A0);
                float q = p * p, q2v = q * q, q4v = q2v * q2v;
                f2 vq = {q,q}, vq2 = {q2v,q2v}, vq4 = {q4v,q4v};
                f2 m[8];
                m[0] = f2{p, q};
                m[1] = m[0] * vq;  m[2] = m[0] * vq2; m[3] = m[1] * vq2;
                m[4] = m[0] * vq4; m[5] = m[1] * vq4; m[6] = m[2] * vq4; m[7] = m[3] * vq4;
#pragma unroll
                for (int k = 0; k < 8; k++)
                    hh[k] = m[k] * hh[k] + du2 * bb[k];
            }
        } else {
            for (int i = 0; i < CLEN; i++) {
                int t = cs * CLEN + i;
                u32 qq = smDt[t * 64 + j2];
                float dtv = __half2float(__ushort_as_half((u16)(hi ? (qq >> 16) : (qq & 0xFFFFu))));
                float uv  = bfu2f(smU[t * PU + d]);
                float duv = dtv * uv;  sdt += dtv;
                const float* Bp = smBf + t * 16;
#pragma unroll
                for (int k = 0; k < 8; k++) {
                    hh[k].x = __expf(dtv * A[2*k])   * hh[k].x + duv * Bp[2*k];
                    hh[k].y = __expf(dtv * A[2*k+1]) * hh[k].y + duv * Bp[2*k+1];
                }
            }
        }

        const int ch = blockIdx.x * 2 + cs;
        float4* hp4 = (float4*)(hl_ws + (((long long)b * NCH + ch) * 128 + d) * 16);
        hp4[0] = make_float4(hh[0].x, hh[0].y, hh[1].x, hh[1].y);
        hp4[1] = make_float4(hh[2].x, hh[2].y, hh[3].x, hh[3].y);
        hp4[2] = make_float4(hh[4].x, hh[4].y, hh[5].x, hh[5].y);
        hp4[3] = make_float4(hh[6].x, hh[6].y, hh[7].x, hh[7].y);
        sdt_ws[((long long)b * NCH + ch) * 128 + d] = sdt;
    }
}

// ---------------- Hierarchical chunk-boundary combine (in-place: hl -> hin) ----------------
__global__ __launch_bounds__(256) void k_combine(
    const float* __restrict__ A_log, float* __restrict__ hl_ws,
    const float* __restrict__ sdt_ws)
{
    __shared__ float sH[16 * 16];   // [seg][s] segment-end h
    __shared__ float sCT[16];       // segment total sum(dt)
    const int tid = threadIdx.x;
    const int s = tid & 15, seg = tid >> 4;
    const int bd = blockIdx.x;      // b*128 + d
    const int b = bd >> 7, d = bd & 127;
    const float A = -__expf(A_log[d * 16 + s]);

    const long long base  = ((long long)b * NCH + seg * 16) * 2048 + d * 16 + s;
    const long long sbase = ((long long)b * NCH + seg * 16) * 128 + d;

    // phase 1: local scan over this segment's 16 chunks (regs, static idx)
    float hinL[16], cum[16];
    float h = 0.f, csum = 0.f;
#pragma unroll
    for (int j = 0; j < 16; j++) {
        float v   = hl_ws[base + (long long)j * 2048];
        float sdt = sdt_ws[sbase + j * 128];
        hinL[j] = h;  cum[j] = csum;
        h = __expf(A * sdt) * h + v;
        csum += sdt;
    }
    sH[seg * 16 + s] = h;
    if (s == 0) sCT[seg] = csum;
    __syncthreads();

    // phase 2: scan over preceding segments (LDS broadcast reads)
    float hseg = 0.f;
    for (int k = 0; k < seg; k++)
        hseg = __expf(A * sCT[k]) * hseg + sH[k * 16 + s];

    // phase 3: fixup + in-place write (each address owned by exactly one thread)
#pragma unroll
    for (int j = 0; j < 16; j++)
        hl_ws[base + (long long)j * 2048] = hinL[j] + __expf(A * cum[j]) * hseg;
}

// ---------------- Backend: packed-FP32 scan (B/C LDS-staged) + epilogue ----------------
// LDS 25600 B -> 6 blocks/CU: sy [64][136] @0, sB [64][16]f32 @17408, sC @21504.
// smR [64][65]f32 overlays sy after MFMA reads.
__global__ __launch_bounds__(256, 6) void k_backend(
    const u32* __restrict__ dtu_g, const float* __restrict__ B_g,
    const float* __restrict__ C_g, const u16* __restrict__ sz_g,
    const float* __restrict__ A_log, const float* __restrict__ D_skip,
    const float* __restrict__ hin_ws, const float* __restrict__ xin_g,
    const u16* __restrict__ Wf4, const float* __restrict__ gamma,
    const float* __restrict__ beta, float* __restrict__ out)
{
    __shared__ __align__(16) char sm[25600];
    u16*   sy   = (u16*)sm;               // [64][136] bf16 y
    float* smR  = (float*)sm;             // [64][65] f32, overlays sy after MFMA reads
    float* sB   = (float*)(sm + 17408);   // [64][16]
    float* sC   = (float*)(sm + 21504);   // [64][16]

    const int tid = threadIdx.x;
    const int cb = blockIdx.x, b = blockIdx.y;   // 64-token tile
    const long long tok0 = (long long)b * L_SZ + (long long)cb * 64;

    // stage B/C tiles (4 KB each) via per-lane coalesced vector loads (vmcnt path)
    {
        ((float4*)sB)[tid] = ((const float4*)(B_g + tok0 * 16))[tid];
        ((float4*)sC)[tid] = ((const float4*)(C_g + tok0 * 16))[tid];
    }

    // ---- scan: 1 thread per (half, channel), 16 states (f2 x8), 32 tokens ----
    {
        const int d = tid & 127, half = tid >> 7;
        float A[16];
#pragma unroll
        for (int s = 0; s < 16; s++) A[s] = -__expf(A_log[d * 16 + s]);
        const float A0 = A[0];
        bool chain = true;
#pragma unroll
        for (int s = 1; s < 16; s++)
            chain = chain && (fabsf(A[s] - (float)(s + 1) * A0) <= 1e-4f * fabsf(A[s]));

        f2 hh[8];
        {
            const float4* hp = (const float4*)(hin_ws +
                (((long long)b * NCH + 2 * cb + half) * 128 + d) * 16);
            float4 ha = hp[0], hb = hp[1], hc = hp[2], hd = hp[3];
            hh[0] = f2{ha.x, ha.y}; hh[1] = f2{ha.z, ha.w};
            hh[2] = f2{hb.x, hb.y}; hh[3] = f2{hb.z, hb.w};
            hh[4] = f2{hc.x, hc.y}; hh[5] = f2{hc.z, hc.w};
            hh[6] = f2{hd.x, hd.y}; hh[7] = f2{hd.z, hd.w};
        }
        const float Dv = D_skip[d];
        __syncthreads();   // sB/sC staged

        if (chain) {
            for (int i = 0; i < CLEN; i++) {
                int t = half * CLEN + i;
                u32 pk = dtu_g[(tok0 + t) * 128 + d];
                float dtv = h2f(pk);
                float uv  = bfhi(pk);
                float duv = dtv * uv;
                f2 du2 = {duv, duv};
                const float4* Bp = (const float4*)(sB + t * 16);
                float4 B0 = Bp[0], B1 = Bp[1], B2 = Bp[2], B3 = Bp[3];
                const float4* Cp = (const float4*)(sC + t * 16);
                float4 C0 = Cp[0], C1 = Cp[1], C2 = Cp[2], C3 = Cp[3];
                f2 bb[8] = {{B0.x,B0.y},{B0.z,B0.w},{B1.x,B1.y},{B1.z,B1.w},
                            {B2.x,B2.y},{B2.z,B2.w},{B3.x,B3.y},{B3.z,B3.w}};
                f2 cc[8] = {{C0.x,C0.y},{C0.z,C0.w},{C1.x,C1.y},{C1.z,C1.w},
                            {C2.x,C2.y},{C2.z,C2.w},{C3.x,C3.y},{C3.z,C3.w}};
                float p = __expf(dtv * A0);
                float q = p * p, q2v = q * q, q4v = q2v * q2v;
                f2 vq = {q,q}, vq2 = {q2v,q2v}, vq4 = {q4v,q4v};
                f2 m[8];
                m[0] = f2{p, q};
                m[1] = m[0] * vq;  m[2] = m[0] * vq2; m[3] = m[1] * vq2;
                m[4] = m[0] * vq4; m[5] = m[1] * vq4; m[6] = m[2] * vq4; m[7] = m[3] * vq4;
                f2 ys2 = {0.f, 0.f};
#pragma unroll
                for (int k = 0; k < 8; k++) {
                    hh[k] = m[k] * hh[k] + du2 * bb[k];
                    ys2 = hh[k] * cc[k] + ys2;
                }
                float ys = ys2.x + ys2.y;
                float szv = bfu2f(sz_g[(tok0 + t) * 128 + d]);
                sy[t * PU + d] = f2bfu((ys + uv * Dv) * szv);
            }
        } else {
            for (int i = 0; i < CLEN; i++) {
                int t = half * CLEN + i;
                u32 pk = dtu_g[(tok0 + t) * 128 + d];
                float dtv = h2f(pk);
                float uv  = bfhi(pk);
                float duv = dtv * uv;
                const float* Bp = sB + t * 16;
                const float* Cp = sC + t * 16;
                float ys = 0.f;
#pragma unroll
                for (int k = 0; k < 8; k++) {
                    hh[k].x = __expf(dtv * A[2*k])   * hh[k].x + duv * Bp[2*k];
                    hh[k].y = __expf(dtv * A[2*k+1]) * hh[k].y + duv * Bp[2*k+1];
                    ys += hh[k].x * Cp[2*k] + hh[k].y * Cp[2*k+1];
                }
                float szv = bfu2f(sz_g[(tok0 + t) * 128 + d]);
                sy[t * PU + d] = f2bfu((ys + uv * Dv) * szv);
            }
        }
    }
    __syncthreads();   // sy complete

    // ---- epilogue: out = LN(y @ out_proj + xin); accs in regs, then smR overlays sy ----
    const int w = tid >> 6, lane = tid & 63;
    const int n16 = lane & 15, quad = lane >> 4;
    f4 accm[4];
    {
        s8 bf[4];
#pragma unroll
        for (int ks = 0; ks < 4; ks++)
            bf[ks] = *(const s8*)(Wf4 + ((w * 4 + ks) * 64 + lane) * 8);
#pragma unroll
        for (int m = 0; m < 4; m++) {
            int ar = m * 16 + n16;
            f4 acc = {0.f, 0.f, 0.f, 0.f};
#pragma unroll
            for (int ks = 0; ks < 4; ks++) {
                s8 a = *(const s8*)(sy + ar * PU + ks * 32 + quad * 8);
                acc = MFMA16(a, bf[ks], acc, 0, 0, 0);
            }
            accm[m] = acc;
        }
    }
    __syncthreads();   // all sy reads done; region now writable as smR

    {
#pragma unroll
        for (int m = 0; m < 4; m++)
#pragma unroll
            for (int reg = 0; reg < 4; reg++) {
                int rr = m * 16 + quad * 4 + reg;
                smR[rr * 65 + w * 16 + n16] = accm[m][reg];
            }
    }
    __syncthreads();

    // LN: 4 threads per row, 16 elements each; 2 shfl_xor to combine partials
    {
        const int row = tid >> 2, part = tid & 3;
        float r[16];
        float s = 0.f, ss = 0.f;
        const float* xr = xin_g + (tok0 + row) * 64 + part * 16;
#pragma unroll
        for (int k = 0; k < 16; k++) {
            float v = smR[row * 65 + part * 16 + k] + xr[k];
            r[k] = v; s += v; ss += v * v;
        }
        s  += __shfl_xor(s, 1, 64);   s  += __shfl_xor(s, 2, 64);
        ss += __shfl_xor(ss, 1, 64);  ss += __shfl_xor(ss, 2, 64);
        float mu  = s * (1.f / 64.f);
        float var = ss * (1.f / 64.f) - mu * mu;
        float rs  = rsqrtf(var + LN_EPS);
        float* orow = out + (tok0 + row) * 64 + part * 16;
        const float* gp = gamma + part * 16;
        const float* bp = beta + part * 16;
#pragma unroll
        for (int k = 0; k < 16; k++)
            orow[k] = gp[k] * (r[k] - mu) * rs + bp[k];
    }
}

extern "C" void kernel_launch(void* const* d_in, const int* in_sizes, int n_in,
                              void* d_out, int out_size, void* d_ws, size_t ws_size,
                              hipStream_t stream)
{
    const float* x       = (const float*)d_in[0];
    const float* W_in    = (const float*)d_in[1];
    const float* b_in    = (const float*)d_in[2];
    const float* in_proj = (const float*)d_in[3];
    const float* conv_w  = (const float*)d_in[4];
    const float* conv_b  = (const float*)d_in[5];
    const float* x_proj  = (const float*)d_in[6];
    const float* dt_w    = (const float*)d_in[7];
    const float* dt_b    = (const float*)d_in[8];
    const float* A_log   = (const float*)d_in[9];
    const float* D_skip  = (const float*)d_in[10];
    const float* Wout    = (const float*)d_in[11];
    const float* gamma   = (const float*)d_in[12];
    const float* beta    = (const float*)d_in[13];
    float* out = (float*)d_out;

    const long long NT = (long long)B_SZ * L_SZ;  // 131072 tokens
    char* ws = (char*)d_ws;
    float*  xin_g = (float*)ws;   ws += NT * 64 * 4;
    u32*    dtu_g = (u32*)ws;     ws += NT * 128 * 4;   // (dt fp16 | u bf16)
    float*  B_g   = (float*)ws;   ws += NT * 16 * 4;
    float*  C_g   = (float*)ws;   ws += NT * 16 * 4;
    u16*    sz_g  = (u16*)ws;     ws += NT * 128 * 2;
    float*  hl_ws  = (float*)ws;  ws += (long long)B_SZ * NCH * 2048 * 4;  // hl -> hin (in place)
    float*  sdt_ws = (float*)ws;  ws += (long long)B_SZ * NCH * 128 * 4;
    u16* Wf1 = (u16*)ws; ws += 4096 * 2;
    u16* Wf2 = (u16*)ws; ws += 16384 * 2;
    u16* Wf3 = (u16*)ws; ws += 6144 * 2;
    u16* Wf4 = (u16*)ws; ws += 8192 * 2;

    k_prep<<<1, 256, 0, stream>>>(W_in, in_proj, x_proj, Wout, Wf1, Wf2, Wf3, Wf4);

    k_frontend<<<dim3(L_SZ / CH, B_SZ), 256, 0, stream>>>(
        x, b_in, conv_w, conv_b, dt_w, dt_b, Wf1, Wf2, Wf3, A_log,
        xin_g, dtu_g, B_g, C_g, sz_g, hl_ws, sdt_ws);

    k_combine<<<B_SZ * 128, 256, 0, stream>>>(A_log, hl_ws, sdt_ws);

    k_backend<<<dim3(L_SZ / 64, B_SZ), 256, 0, stream>>>(
        dtu_g, B_g, C_g, sz_g, A_log, D_skip, hl_ws, xin_g,
        Wf4, gamma, beta, out);
}